// Round 1
// baseline (993.005 us; speedup 1.0000x reference)
//
#include <hip/hip_runtime.h>

#define HD 128
#define MAXM 256
#define ECH 512

// ---------- reduction helpers (block = 128 threads = 2 waves) ----------
__device__ inline float waveSum(float v){ for(int o=32;o;o>>=1) v += __shfl_down(v,o); return v; }
__device__ inline float waveMax(float v){ for(int o=32;o;o>>=1) v = fmaxf(v,__shfl_down(v,o)); return v; }

__device__ inline float blockSum128(float v, float* red){
  int j = threadIdx.x;
  float s = waveSum(v);
  __syncthreads();
  if ((j & 63) == 0) red[j >> 6] = s;
  __syncthreads();
  return red[0] + red[1];
}
__device__ inline float blockMax128(float v, float* red){
  int j = threadIdx.x;
  float s = waveMax(v);
  __syncthreads();
  if ((j & 63) == 0) red[j >> 6] = s;
  __syncthreads();
  return fmaxf(red[0], red[1]);
}

// ---------- region aggregation ----------
__global__ void k_count(const int* __restrict__ memb, int N, int* __restrict__ counts){
  __shared__ int h[64];
  int tid = threadIdx.x;
  if (tid < 64) h[tid] = 0;
  __syncthreads();
  for (int t = blockIdx.x*blockDim.x + tid; t < N; t += gridDim.x*blockDim.x)
    atomicAdd(&h[memb[t]], 1);
  __syncthreads();
  if (tid < 64){ int v = h[tid]; if (v) atomicAdd(&counts[tid], v); }
}

__global__ void k_regsum(const float* __restrict__ node, const int* __restrict__ memb,
                         int N, int R, float* __restrict__ sums){
  extern __shared__ float acc[];          // R*HD floats
  int b = blockIdx.y, j = threadIdx.x;
  for (int r = 0; r < R; ++r) acc[r*HD + j] = 0.f;
  int per = (N + gridDim.x - 1) / gridDim.x;
  int t0 = blockIdx.x * per;
  int t1 = t0 + per; if (t1 > N) t1 = N;
  for (int t = t0; t < t1; ++t){
    int r = memb[t];
    acc[r*HD + j] += node[((long)b*N + t)*HD + j];
  }
  for (int r = 0; r < R; ++r)
    atomicAdd(&sums[((long)b*R + r)*HD + j], acc[r*HD + j]);
}

__global__ void k_regfin(const float* __restrict__ sums, const int* __restrict__ counts,
                         const float* __restrict__ rinit, float* __restrict__ h_aug,
                         int N, int R, int T, int B){
  int i = blockIdx.x*blockDim.x + threadIdx.x;
  if (i >= B*R*HD) return;
  int j = i % HD; int r = (i/HD) % R; int b = i/(HD*R);
  int c = counts[r];
  float v = (c > 0) ? sums[i] / (float)c : 0.f;
  v += rinit[r*HD + j];
  h_aug[((long)b*T + N + r)*HD + j] = v;
}

__global__ void k_copyin(const float* __restrict__ node, float* __restrict__ h_aug, int N, int T, int B){
  long total = (long)B*N*(HD/4);
  for (long i = blockIdx.x*(long)blockDim.x + threadIdx.x; i < total; i += (long)gridDim.x*blockDim.x){
    long bt = i / (HD/4); int j4 = (int)(i % (HD/4));
    int b = (int)(bt / N); int t = (int)(bt % N);
    ((float4*)h_aug)[((long)b*T + t)*(HD/4) + j4] = ((const float4*)node)[i];
  }
}

// ---------- column CSR of H_inc (edge -> member nodes), built once per launch ----------
__global__ void k_colcnt(const float* __restrict__ Hinc, long TE, int E, int* __restrict__ cnt){
  for (long i = blockIdx.x*(long)blockDim.x + threadIdx.x; i < TE; i += (long)gridDim.x*blockDim.x)
    if (Hinc[i] != 0.f) atomicAdd(&cnt[(int)(i % E)], 1);
}

__global__ void k_scan(const int* __restrict__ cnt, int E, int* __restrict__ ptr, int* __restrict__ cur){
  __shared__ int s[1024];
  int tid = threadIdx.x;
  int v = (tid < E) ? cnt[tid] : 0;
  s[tid] = v; __syncthreads();
  for (int off = 1; off < 1024; off <<= 1){
    int t = (tid >= off) ? s[tid - off] : 0;
    __syncthreads();
    s[tid] += t;
    __syncthreads();
  }
  if (tid < E){ int excl = s[tid] - v; ptr[tid] = excl; cur[tid] = excl; }
  if (tid == E - 1) ptr[E] = s[tid];
}

__global__ void k_colfill(const float* __restrict__ Hinc, long TE, int E,
                          int* __restrict__ cur, int* __restrict__ idx, int cap){
  for (long i = blockIdx.x*(long)blockDim.x + threadIdx.x; i < TE; i += (long)gridDim.x*blockDim.x)
    if (Hinc[i] != 0.f){
      int e = (int)(i % E);
      int slot = atomicAdd(&cur[e], 1);
      if (slot < cap) idx[slot] = (int)(i / E);
    }
}

// ---------- v_l = ctx1[l] @ W1_hat[l]  (raw = h·v·scale trick) ----------
__global__ void k_ctxv(const float* __restrict__ ctx1, const float* __restrict__ W1h,
                       float* __restrict__ v){
  int l = blockIdx.x, k = threadIdx.x;
  float a = 0.f;
  for (int j = 0; j < HD; ++j) a += ctx1[l*HD + j] * W1h[((long)l*HD + j)*HD + k];
  v[l*HD + k] = a;
}

__global__ void k_raw(const float* __restrict__ h_aug, const float* __restrict__ v,
                      float* __restrict__ raw, int T, float scale){
  int t = blockIdx.x, b = blockIdx.y, j = threadIdx.x;
  __shared__ float red[2];
  float p = h_aug[((long)b*T + t)*HD + j] * v[j];
  float s = blockSum128(p, red);
  if (j == 0) raw[(long)b*T + t] = s * scale;
}

// ---------- C = A @ W^T ; A,C: (B, M, 128) row-major, W: 128x128 row-major ----------
__global__ __launch_bounds__(256) void k_gemm(const float* __restrict__ A, const float* __restrict__ W,
                                              float* __restrict__ C, int M){
  __shared__ float As[64][33];
  __shared__ float Ws[32][132];   // Ws[k][n]
  int b = blockIdx.y;
  const float* Ab = A + (long)b*M*HD;
  float* Cb = C + (long)b*M*HD;
  int row0 = blockIdx.x * 64;
  int tid = threadIdx.x;
  int tx = tid & 15, ty = tid >> 4;
  float acc[4][8];
  #pragma unroll
  for (int r = 0; r < 4; ++r)
    #pragma unroll
    for (int c = 0; c < 8; ++c) acc[r][c] = 0.f;

  for (int kk = 0; kk < HD; kk += 32){
    #pragma unroll
    for (int i = tid; i < 64*32; i += 256){
      int m = i >> 5, k = i & 31;
      int gr = row0 + m;
      As[m][k] = (gr < M) ? Ab[(long)gr*HD + kk + k] : 0.f;
    }
    #pragma unroll
    for (int i = tid; i < 128*32; i += 256){
      int n = i >> 5, k = i & 31;
      Ws[k][n] = W[(long)n*HD + kk + k];
    }
    __syncthreads();
    #pragma unroll
    for (int k = 0; k < 32; ++k){
      float a0 = As[ty*4+0][k], a1 = As[ty*4+1][k], a2 = As[ty*4+2][k], a3 = As[ty*4+3][k];
      float4 b0 = *(const float4*)&Ws[k][tx*8];
      float4 b1 = *(const float4*)&Ws[k][tx*8+4];
      float bb[8] = {b0.x,b0.y,b0.z,b0.w,b1.x,b1.y,b1.z,b1.w};
      #pragma unroll
      for (int c = 0; c < 8; ++c){
        acc[0][c] += a0*bb[c]; acc[1][c] += a1*bb[c];
        acc[2][c] += a2*bb[c]; acc[3][c] += a3*bb[c];
      }
    }
    __syncthreads();
  }
  #pragma unroll
  for (int r = 0; r < 4; ++r){
    int gr = row0 + ty*4 + r;
    if (gr < M){
      *(float4*)&Cb[(long)gr*HD + tx*8]   = make_float4(acc[r][0],acc[r][1],acc[r][2],acc[r][3]);
      *(float4*)&Cb[(long)gr*HD + tx*8+4] = make_float4(acc[r][4],acc[r][5],acc[r][6],acc[r][7]);
    }
  }
}

// ---------- stage 1: per-edge masked softmax over member nodes + weighted sum of proj1 ----------
__global__ __launch_bounds__(128) void k_edge(const float* __restrict__ raw, const float* __restrict__ proj1,
                      const int* __restrict__ colptr, const int* __restrict__ colidx,
                      float* __restrict__ hyper, int T, int E, int cap){
  int e = blockIdx.x, b = blockIdx.y, j = threadIdx.x;
  __shared__ float red[2];
  __shared__ float wls[ECH];
  __shared__ int   tls[ECH];
  int p0 = colptr[e], p1 = colptr[e+1];
  if (p1 > cap) p1 = cap;
  int c = p1 - p0;
  const float* rawb = raw + (long)b*T;
  if (c <= 0){ hyper[((long)b*E + e)*HD + j] = 0.f; return; }
  float lm = -1e30f;
  for (int i = j; i < c; i += 128) lm = fmaxf(lm, rawb[colidx[p0 + i]]);
  float m = blockMax128(lm, red);
  float lz = 0.f;
  for (int i = j; i < c; i += 128) lz += __expf(rawb[colidx[p0 + i]] - m);
  float Z = blockSum128(lz, red);
  float invZ = 1.f / Z;
  float accv = 0.f;
  for (int base = 0; base < c; base += ECH){
    int n = c - base; if (n > ECH) n = ECH;
    __syncthreads();
    for (int i = j; i < n; i += 128){
      int t = colidx[p0 + base + i];
      tls[i] = t;
      wls[i] = __expf(rawb[t] - m);
    }
    __syncthreads();
    #pragma unroll 4
    for (int i = 0; i < n; ++i)
      accv += wls[i] * proj1[((long)b*T + tls[i])*HD + j];
  }
  hyper[((long)b*E + e)*HD + j] = accv * invZ;
}

// ---------- stage 2: per-node masked softmax over member edges + weighted sum + residual + LN ----------
__global__ __launch_bounds__(128) void k_node(const float* __restrict__ Hinc,
      const float* __restrict__ proj3, const float* __restrict__ p2hat, const float* __restrict__ hw2,
      const float* __restrict__ lng, const float* __restrict__ lnb,
      float* __restrict__ h_aug, float* __restrict__ out,
      int T, int E, int N, int writeOut, float scale){
  int t = blockIdx.x, b = blockIdx.y, j = threadIdx.x;
  int lane = j & 63, wid = j >> 6;
  __shared__ __align__(16) float p3[HD];
  __shared__ int   mem[MAXM];
  __shared__ float sv[MAXM];
  __shared__ float red[2];
  __shared__ int   wsum[2];
  long rowb = (long)b*T + t;
  p3[j] = proj3[rowb*HD + j];
  const float* hrow = Hinc + (long)t*E;

  // ordered member discovery via ballot
  int c = 0;
  for (int base = 0; base < E; base += 128){
    bool f = (hrow[base + j] != 0.f);
    unsigned long long mk = __ballot(f);
    if (lane == 0) wsum[wid] = __popcll(mk);
    __syncthreads();
    int w0 = wsum[0], w1 = wsum[1];
    if (f){
      int pos = c + (wid ? w0 : 0) + (int)__popcll(mk & ((1ull << lane) - 1ull));
      if (pos < MAXM) mem[pos] = base + j;
    }
    c += w0 + w1;
    __syncthreads();
  }
  if (c > MAXM) c = MAXM;

  float o = 0.f;
  if (c > 0){
    const float* p2b  = p2hat + (long)b*E*HD;
    const float* hw2b = hw2   + (long)b*E*HD;
    // scores
    for (int i = j; i < c; i += 128){
      int e = mem[i];
      const float4* pr4 = (const float4*)(p2b + (long)e*HD);
      const float4* p34 = (const float4*)p3;
      float s = 0.f;
      #pragma unroll 8
      for (int k = 0; k < HD/4; ++k){
        float4 a = p34[k], q = pr4[k];
        s += a.x*q.x + a.y*q.y + a.z*q.z + a.w*q.w;
      }
      sv[i] = s * scale;
    }
    __syncthreads();
    float lm = -1e30f;
    for (int i = j; i < c; i += 128) lm = fmaxf(lm, sv[i]);
    float m = blockMax128(lm, red);
    float lz = 0.f;
    for (int i = j; i < c; i += 128){ float w = __expf(sv[i] - m); sv[i] = w; lz += w; }
    float Z = blockSum128(lz, red);     // syncs also publish sv[]
    float invZ = 1.f / Z;
    for (int i = 0; i < c; ++i)
      o += sv[i] * hw2b[(long)mem[i]*HD + j];
    o *= invZ;
  }
  // residual + layernorm
  float x = o + h_aug[rowb*HD + j];
  float mean = blockSum128(x, red) * (1.f/HD);
  float d = x - mean;
  float var = blockSum128(d*d, red) * (1.f/HD);
  float y = d * rsqrtf(var + 1e-5f) * lng[j] + lnb[j];
  h_aug[rowb*HD + j] = y;
  if (writeOut && t < N) out[((long)b*N + t)*HD + j] = y;
}

extern "C" void kernel_launch(void* const* d_in, const int* in_sizes, int n_in,
                              void* d_out, int out_size, void* d_ws, size_t ws_size,
                              hipStream_t stream) {
  const float* node_emb = (const float*)d_in[0];
  const float* Hinc     = (const float*)d_in[1];
  const int*   memb     = (const int*)d_in[2];
  const float* W1       = (const float*)d_in[3];
  const float* W1h      = (const float*)d_in[4];
  const float* ctx1     = (const float*)d_in[5];
  const float* W2       = (const float*)d_in[6];
  const float* W2h      = (const float*)d_in[7];
  const float* W3       = (const float*)d_in[8];
  const float* lng      = (const float*)d_in[9];
  const float* lnb      = (const float*)d_in[10];
  const float* rinit    = (const float*)d_in[11];
  float* out = (float*)d_out;

  const int N  = in_sizes[2];
  const int Hd = in_sizes[3] / in_sizes[5];   // (L*H*H)/(L*H) = 128
  const int L  = in_sizes[5] / Hd;            // 2
  const int R  = in_sizes[11] / Hd;           // 16
  const int B  = in_sizes[0] / (N * Hd);      // 4
  const int T  = N + R;
  const int E  = in_sizes[1] / T;             // 1024
  const float scale = 1.0f / sqrtf((float)Hd);

  char* p = (char*)d_ws;
  auto carve = [&](size_t bytes){ char* r = p; p += (bytes + 255) & ~(size_t)255; return (void*)r; };
  float* h_aug = (float*)carve((size_t)B*T*Hd*4);
  float* proj1 = (float*)carve((size_t)B*T*Hd*4);
  float* proj3 = (float*)carve((size_t)B*T*Hd*4);
  float* hyper = (float*)carve((size_t)B*E*Hd*4);
  float* p2hat = (float*)carve((size_t)B*E*Hd*4);
  float* hw2   = (float*)carve((size_t)B*E*Hd*4);
  float* rawb  = (float*)carve((size_t)B*T*4);
  float* vbuf  = (float*)carve((size_t)L*Hd*4);
  float* sums  = (float*)carve((size_t)B*R*Hd*4);
  int* counts  = (int*)carve((size_t)R*4);
  int* col_cnt = (int*)carve((size_t)E*4);
  int* col_ptr = (int*)carve((size_t)(E+1)*4);
  int* col_cur = (int*)carve((size_t)E*4);
  size_t used = (size_t)(p - (char*)d_ws);
  size_t rem  = (ws_size > used) ? (ws_size - used) : 0;
  long TE = (long)T*E;
  long capl = (long)(rem / 4); if (capl > TE) capl = TE;
  int cap = (int)capl;
  int* col_idx = (int*)p;

  hipMemsetAsync(counts, 0, (size_t)R*4, stream);
  hipMemsetAsync(sums, 0, (size_t)B*R*Hd*4, stream);
  hipMemsetAsync(col_cnt, 0, (size_t)E*4, stream);

  k_count<<<32, 256, 0, stream>>>(memb, N, counts);
  k_regsum<<<dim3(16, B), Hd, (size_t)R*Hd*4, stream>>>(node_emb, memb, N, R, sums);
  int tot = B*R*Hd;
  k_regfin<<<(tot+255)/256, 256, 0, stream>>>(sums, counts, rinit, h_aug, N, R, T, B);
  k_copyin<<<2048, 256, 0, stream>>>(node_emb, h_aug, N, T, B);
  k_colcnt<<<2048, 256, 0, stream>>>(Hinc, TE, E, col_cnt);
  k_scan<<<1, 1024, 0, stream>>>(col_cnt, E, col_ptr, col_cur);
  k_colfill<<<2048, 256, 0, stream>>>(Hinc, TE, E, col_cur, col_idx, cap);
  k_ctxv<<<L, Hd, 0, stream>>>(ctx1, W1h, vbuf);

  int gT = (T + 63)/64, gE = (E + 63)/64;
  for (int l = 0; l < L; ++l){
    size_t wo = (size_t)l*Hd*Hd;
    k_raw<<<dim3(T, B), Hd, 0, stream>>>(h_aug, vbuf + (size_t)l*Hd, rawb, T, scale);
    k_gemm<<<dim3(gT, B), 256, 0, stream>>>(h_aug, W1 + wo, proj1, T);
    k_gemm<<<dim3(gT, B), 256, 0, stream>>>(h_aug, W3 + wo, proj3, T);
    k_edge<<<dim3(E, B), 128, 0, stream>>>(rawb, proj1, col_ptr, col_idx, hyper, T, E, cap);
    k_gemm<<<dim3(gE, B), 256, 0, stream>>>(hyper, W2h + wo, p2hat, E);
    k_gemm<<<dim3(gE, B), 256, 0, stream>>>(hyper, W2 + wo, hw2, E);
    k_node<<<dim3(T, B), 128, 0, stream>>>(Hinc, proj3, p2hat, hw2, lng + (size_t)l*Hd, lnb + (size_t)l*Hd,
                                           h_aug, out, T, E, N, (l == L-1) ? 1 : 0, scale);
  }
}

// Round 2
// 918.115 us; speedup vs baseline: 1.0816x; 1.0816x over previous
//
#include <hip/hip_runtime.h>

#define HD 128
#define MAXM 256
#define ECH 512
#define MAXR 16
#define NB_RS 128

// ---------- reduction helpers (block = 128 threads = 2 waves) ----------
__device__ inline float waveSum(float v){ for(int o=32;o;o>>=1) v += __shfl_down(v,o); return v; }
__device__ inline float waveMax(float v){ for(int o=32;o;o>>=1) v = fmaxf(v,__shfl_down(v,o)); return v; }

__device__ inline float blockSum128(float v, float* red){
  int j = threadIdx.x;
  float s = waveSum(v);
  __syncthreads();
  if ((j & 63) == 0) red[j >> 6] = s;
  __syncthreads();
  return red[0] + red[1];
}
__device__ inline float blockMax128(float v, float* red){
  int j = threadIdx.x;
  float s = waveMax(v);
  __syncthreads();
  if ((j & 63) == 0) red[j >> 6] = s;
  __syncthreads();
  return fmaxf(red[0], red[1]);
}

// ---------- region aggregation ----------
__global__ void k_count(const int* __restrict__ memb, int N, int* __restrict__ counts){
  __shared__ int h[64];
  int tid = threadIdx.x;
  if (tid < 64) h[tid] = 0;
  __syncthreads();
  for (int t = blockIdx.x*blockDim.x + tid; t < N; t += gridDim.x*blockDim.x)
    atomicAdd(&h[memb[t]], 1);
  __syncthreads();
  if (tid < 64){ int v = h[tid]; if (v) atomicAdd(&counts[tid], v); }
}

// fast path (R <= 16): per-thread register accumulators, atomic-free partials
// partials layout: [b][blk][R][HD]
__global__ __launch_bounds__(128) void k_regsum_fast(const float* __restrict__ node,
                        const int* __restrict__ memb, int N, int R,
                        float* __restrict__ partials){
  int b = blockIdx.y, j = threadIdx.x, blk = blockIdx.x;
  int nb = gridDim.x;
  int per = (N + nb - 1) / nb;
  int t0 = blk * per;
  int t1 = t0 + per; if (t1 > N) t1 = N;
  float acc[MAXR];
  #pragma unroll
  for (int i = 0; i < MAXR; ++i) acc[i] = 0.f;
  const float* base = node + (long)b*N*HD + j;
  for (int t = t0; t < t1; ++t){
    float v = base[(long)t*HD];
    int r = memb[t];
    #pragma unroll
    for (int i = 0; i < MAXR; ++i) acc[i] += (i == r) ? v : 0.f;
  }
  float* dst = partials + ((long)(b*nb + blk)*R)*HD + j;
  #pragma unroll
  for (int i = 0; i < MAXR; ++i)
    if (i < R) dst[(long)i*HD] = acc[i];
}

// fallback (R > 16): LDS accumulate + atomics into partials slice 0 (memset first)
__global__ void k_regsum_lds(const float* __restrict__ node, const int* __restrict__ memb,
                             int N, int R, float* __restrict__ partials, int nb){
  extern __shared__ float acc[];          // R*HD floats
  int b = blockIdx.y, j = threadIdx.x;
  for (int r = 0; r < R; ++r) acc[r*HD + j] = 0.f;
  int per = (N + gridDim.x - 1) / gridDim.x;
  int t0 = blockIdx.x * per;
  int t1 = t0 + per; if (t1 > N) t1 = N;
  for (int t = t0; t < t1; ++t){
    int r = memb[t];
    acc[r*HD + j] += node[((long)b*N + t)*HD + j];
  }
  for (int r = 0; r < R; ++r)
    atomicAdd(&partials[((long)(b*nb)*R + r)*HD + j], acc[r*HD + j]);
}

// reduce partials over nb blocks, divide by count, add region_init, write into h_aug
__global__ void k_regfin(const float* __restrict__ partials, int nb, int redN,
                         const int* __restrict__ counts,
                         const float* __restrict__ rinit, float* __restrict__ h_aug,
                         int N, int R, int T, int B){
  int i = blockIdx.x*blockDim.x + threadIdx.x;
  if (i >= B*R*HD) return;
  int j = i % HD; int r = (i/HD) % R; int b = i/(HD*R);
  float s = 0.f;
  for (int blk = 0; blk < redN; ++blk)
    s += partials[((long)(b*nb + blk)*R + r)*HD + j];
  int c = counts[r];
  float v = (c > 0) ? s / (float)c : 0.f;
  v += rinit[r*HD + j];
  h_aug[((long)b*T + N + r)*HD + j] = v;
}

__global__ void k_copyin(const float* __restrict__ node, float* __restrict__ h_aug, int N, int T, int B){
  long total = (long)B*N*(HD/4);
  for (long i = blockIdx.x*(long)blockDim.x + threadIdx.x; i < total; i += (long)gridDim.x*blockDim.x){
    long bt = i / (HD/4); int j4 = (int)(i % (HD/4));
    int b = (int)(bt / N); int t = (int)(bt % N);
    ((float4*)h_aug)[((long)b*T + t)*(HD/4) + j4] = ((const float4*)node)[i];
  }
}

// ---------- column CSR of H_inc (edge -> member nodes), built once per launch ----------
__global__ void k_colcnt(const float* __restrict__ Hinc, long TE, int E, int* __restrict__ cnt){
  for (long i = blockIdx.x*(long)blockDim.x + threadIdx.x; i < TE; i += (long)gridDim.x*blockDim.x)
    if (Hinc[i] != 0.f) atomicAdd(&cnt[(int)(i % E)], 1);
}

__global__ void k_scan(const int* __restrict__ cnt, int E, int* __restrict__ ptr, int* __restrict__ cur){
  __shared__ int s[1024];
  int tid = threadIdx.x;
  int v = (tid < E) ? cnt[tid] : 0;
  s[tid] = v; __syncthreads();
  for (int off = 1; off < 1024; off <<= 1){
    int t = (tid >= off) ? s[tid - off] : 0;
    __syncthreads();
    s[tid] += t;
    __syncthreads();
  }
  if (tid < E){ int excl = s[tid] - v; ptr[tid] = excl; cur[tid] = excl; }
  if (tid == E - 1) ptr[E] = s[tid];
}

__global__ void k_colfill(const float* __restrict__ Hinc, long TE, int E,
                          int* __restrict__ cur, int* __restrict__ idx, int cap){
  for (long i = blockIdx.x*(long)blockDim.x + threadIdx.x; i < TE; i += (long)gridDim.x*blockDim.x)
    if (Hinc[i] != 0.f){
      int e = (int)(i % E);
      int slot = atomicAdd(&cur[e], 1);
      if (slot < cap) idx[slot] = (int)(i / E);
    }
}

// ---------- v_l = ctx1[l] @ W1_hat[l]  (raw = h·v·scale trick) ----------
__global__ void k_ctxv(const float* __restrict__ ctx1, const float* __restrict__ W1h,
                       float* __restrict__ v){
  int l = blockIdx.x, k = threadIdx.x;
  float a = 0.f;
  for (int j = 0; j < HD; ++j) a += ctx1[l*HD + j] * W1h[((long)l*HD + j)*HD + k];
  v[l*HD + k] = a;
}

__global__ void k_raw(const float* __restrict__ h_aug, const float* __restrict__ v,
                      float* __restrict__ raw, int T, float scale){
  int t = blockIdx.x, b = blockIdx.y, j = threadIdx.x;
  __shared__ float red[2];
  float p = h_aug[((long)b*T + t)*HD + j] * v[j];
  float s = blockSum128(p, red);
  if (j == 0) raw[(long)b*T + t] = s * scale;
}

// ---------- C = A @ W^T ; A,C: (B, M, 128) row-major, W: 128x128 row-major ----------
__global__ __launch_bounds__(256) void k_gemm(const float* __restrict__ A, const float* __restrict__ W,
                                              float* __restrict__ C, int M){
  __shared__ float As[64][33];
  __shared__ float Ws[32][132];   // Ws[k][n]
  int b = blockIdx.y;
  const float* Ab = A + (long)b*M*HD;
  float* Cb = C + (long)b*M*HD;
  int row0 = blockIdx.x * 64;
  int tid = threadIdx.x;
  int tx = tid & 15, ty = tid >> 4;
  float acc[4][8];
  #pragma unroll
  for (int r = 0; r < 4; ++r)
    #pragma unroll
    for (int c = 0; c < 8; ++c) acc[r][c] = 0.f;

  for (int kk = 0; kk < HD; kk += 32){
    #pragma unroll
    for (int i = tid; i < 64*32; i += 256){
      int m = i >> 5, k = i & 31;
      int gr = row0 + m;
      As[m][k] = (gr < M) ? Ab[(long)gr*HD + kk + k] : 0.f;
    }
    #pragma unroll
    for (int i = tid; i < 128*32; i += 256){
      int n = i >> 5, k = i & 31;
      Ws[k][n] = W[(long)n*HD + kk + k];
    }
    __syncthreads();
    #pragma unroll
    for (int k = 0; k < 32; ++k){
      float a0 = As[ty*4+0][k], a1 = As[ty*4+1][k], a2 = As[ty*4+2][k], a3 = As[ty*4+3][k];
      float4 b0 = *(const float4*)&Ws[k][tx*8];
      float4 b1 = *(const float4*)&Ws[k][tx*8+4];
      float bb[8] = {b0.x,b0.y,b0.z,b0.w,b1.x,b1.y,b1.z,b1.w};
      #pragma unroll
      for (int c = 0; c < 8; ++c){
        acc[0][c] += a0*bb[c]; acc[1][c] += a1*bb[c];
        acc[2][c] += a2*bb[c]; acc[3][c] += a3*bb[c];
      }
    }
    __syncthreads();
  }
  #pragma unroll
  for (int r = 0; r < 4; ++r){
    int gr = row0 + ty*4 + r;
    if (gr < M){
      *(float4*)&Cb[(long)gr*HD + tx*8]   = make_float4(acc[r][0],acc[r][1],acc[r][2],acc[r][3]);
      *(float4*)&Cb[(long)gr*HD + tx*8+4] = make_float4(acc[r][4],acc[r][5],acc[r][6],acc[r][7]);
    }
  }
}

// ---------- stage 1: per-edge masked softmax over member nodes + weighted sum of proj1 ----------
__global__ __launch_bounds__(128) void k_edge(const float* __restrict__ raw, const float* __restrict__ proj1,
                      const int* __restrict__ colptr, const int* __restrict__ colidx,
                      float* __restrict__ hyper, int T, int E, int cap){
  int e = blockIdx.x, b = blockIdx.y, j = threadIdx.x;
  __shared__ float red[2];
  __shared__ float wls[ECH];
  __shared__ int   tls[ECH];
  int p0 = colptr[e], p1 = colptr[e+1];
  if (p1 > cap) p1 = cap;
  int c = p1 - p0;
  const float* rawb = raw + (long)b*T;
  if (c <= 0){ hyper[((long)b*E + e)*HD + j] = 0.f; return; }
  float lm = -1e30f;
  for (int i = j; i < c; i += 128) lm = fmaxf(lm, rawb[colidx[p0 + i]]);
  float m = blockMax128(lm, red);
  float lz = 0.f;
  for (int i = j; i < c; i += 128) lz += __expf(rawb[colidx[p0 + i]] - m);
  float Z = blockSum128(lz, red);
  float invZ = 1.f / Z;
  float accv = 0.f;
  for (int base = 0; base < c; base += ECH){
    int n = c - base; if (n > ECH) n = ECH;
    __syncthreads();
    for (int i = j; i < n; i += 128){
      int t = colidx[p0 + base + i];
      tls[i] = t;
      wls[i] = __expf(rawb[t] - m);
    }
    __syncthreads();
    #pragma unroll 4
    for (int i = 0; i < n; ++i)
      accv += wls[i] * proj1[((long)b*T + tls[i])*HD + j];
  }
  hyper[((long)b*E + e)*HD + j] = accv * invZ;
}

// ---------- stage 2: per-node masked softmax over member edges + weighted sum + residual + LN ----------
__global__ __launch_bounds__(128) void k_node(const float* __restrict__ Hinc,
      const float* __restrict__ proj3, const float* __restrict__ p2hat, const float* __restrict__ hw2,
      const float* __restrict__ lng, const float* __restrict__ lnb,
      float* __restrict__ h_aug, float* __restrict__ out,
      int T, int E, int N, int writeOut, float scale){
  int t = blockIdx.x, b = blockIdx.y, j = threadIdx.x;
  int lane = j & 63, wid = j >> 6;
  __shared__ __align__(16) float p3[HD];
  __shared__ int   mem[MAXM];
  __shared__ float sv[MAXM];
  __shared__ float red[2];
  __shared__ int   wsum[2];
  long rowb = (long)b*T + t;
  p3[j] = proj3[rowb*HD + j];
  const float* hrow = Hinc + (long)t*E;

  // ordered member discovery via ballot
  int c = 0;
  for (int base = 0; base < E; base += 128){
    bool f = (hrow[base + j] != 0.f);
    unsigned long long mk = __ballot(f);
    if (lane == 0) wsum[wid] = __popcll(mk);
    __syncthreads();
    int w0 = wsum[0], w1 = wsum[1];
    if (f){
      int pos = c + (wid ? w0 : 0) + (int)__popcll(mk & ((1ull << lane) - 1ull));
      if (pos < MAXM) mem[pos] = base + j;
    }
    c += w0 + w1;
    __syncthreads();
  }
  if (c > MAXM) c = MAXM;

  float o = 0.f;
  if (c > 0){
    const float* p2b  = p2hat + (long)b*E*HD;
    const float* hw2b = hw2   + (long)b*E*HD;
    // scores
    for (int i = j; i < c; i += 128){
      int e = mem[i];
      const float4* pr4 = (const float4*)(p2b + (long)e*HD);
      const float4* p34 = (const float4*)p3;
      float s = 0.f;
      #pragma unroll 8
      for (int k = 0; k < HD/4; ++k){
        float4 a = p34[k], q = pr4[k];
        s += a.x*q.x + a.y*q.y + a.z*q.z + a.w*q.w;
      }
      sv[i] = s * scale;
    }
    __syncthreads();
    float lm = -1e30f;
    for (int i = j; i < c; i += 128) lm = fmaxf(lm, sv[i]);
    float m = blockMax128(lm, red);
    float lz = 0.f;
    for (int i = j; i < c; i += 128){ float w = __expf(sv[i] - m); sv[i] = w; lz += w; }
    float Z = blockSum128(lz, red);     // syncs also publish sv[]
    float invZ = 1.f / Z;
    for (int i = 0; i < c; ++i)
      o += sv[i] * hw2b[(long)mem[i]*HD + j];
    o *= invZ;
  }
  // residual + layernorm
  float x = o + h_aug[rowb*HD + j];
  float mean = blockSum128(x, red) * (1.f/HD);
  float d = x - mean;
  float var = blockSum128(d*d, red) * (1.f/HD);
  float y = d * rsqrtf(var + 1e-5f) * lng[j] + lnb[j];
  h_aug[rowb*HD + j] = y;
  if (writeOut && t < N) out[((long)b*N + t)*HD + j] = y;
}

extern "C" void kernel_launch(void* const* d_in, const int* in_sizes, int n_in,
                              void* d_out, int out_size, void* d_ws, size_t ws_size,
                              hipStream_t stream) {
  const float* node_emb = (const float*)d_in[0];
  const float* Hinc     = (const float*)d_in[1];
  const int*   memb     = (const int*)d_in[2];
  const float* W1       = (const float*)d_in[3];
  const float* W1h      = (const float*)d_in[4];
  const float* ctx1     = (const float*)d_in[5];
  const float* W2       = (const float*)d_in[6];
  const float* W2h      = (const float*)d_in[7];
  const float* W3       = (const float*)d_in[8];
  const float* lng      = (const float*)d_in[9];
  const float* lnb      = (const float*)d_in[10];
  const float* rinit    = (const float*)d_in[11];
  float* out = (float*)d_out;

  const int N  = in_sizes[2];
  const int Hd = in_sizes[3] / in_sizes[5];   // (L*H*H)/(L*H) = 128
  const int L  = in_sizes[5] / Hd;            // 2
  const int R  = in_sizes[11] / Hd;           // 16
  const int B  = in_sizes[0] / (N * Hd);      // 4
  const int T  = N + R;
  const int E  = in_sizes[1] / T;             // 1024
  const float scale = 1.0f / sqrtf((float)Hd);

  char* p = (char*)d_ws;
  auto carve = [&](size_t bytes){ char* r = p; p += (bytes + 255) & ~(size_t)255; return (void*)r; };
  float* h_aug = (float*)carve((size_t)B*T*Hd*4);
  float* proj1 = (float*)carve((size_t)B*T*Hd*4);
  float* proj3 = (float*)carve((size_t)B*T*Hd*4);
  float* hyper = (float*)carve((size_t)B*E*Hd*4);
  float* p2hat = (float*)carve((size_t)B*E*Hd*4);
  float* hw2   = (float*)carve((size_t)B*E*Hd*4);
  float* rawb  = (float*)carve((size_t)B*T*4);
  float* vbuf  = (float*)carve((size_t)L*Hd*4);
  int* counts  = (int*)carve((size_t)R*4);
  int* col_cnt = (int*)carve((size_t)E*4);
  int* col_ptr = (int*)carve((size_t)(E+1)*4);
  int* col_cur = (int*)carve((size_t)E*4);
  size_t used = (size_t)(p - (char*)d_ws);
  size_t rem  = (ws_size > used) ? (ws_size - used) : 0;
  long TE = (long)T*E;
  long capl = (long)(rem / 4); if (capl > TE) capl = TE;
  int cap = (int)capl;
  int* col_idx = (int*)p;

  // partials alias proj1 (dead until k_gemm writes it, well after k_regfin)
  float* partials = proj1;

  hipMemsetAsync(counts, 0, (size_t)R*4, stream);
  hipMemsetAsync(col_cnt, 0, (size_t)E*4, stream);

  k_count<<<32, 256, 0, stream>>>(memb, N, counts);

  int redN;
  if (R <= MAXR){
    k_regsum_fast<<<dim3(NB_RS, B), 128, 0, stream>>>(node_emb, memb, N, R, partials);
    redN = NB_RS;
  } else {
    hipMemsetAsync(partials, 0, (size_t)B*R*Hd*4, stream);
    k_regsum_lds<<<dim3(16, B), Hd, (size_t)R*Hd*4, stream>>>(node_emb, memb, N, R, partials, NB_RS);
    redN = 1;
  }
  int tot = B*R*Hd;
  k_regfin<<<(tot+255)/256, 256, 0, stream>>>(partials, NB_RS, redN, counts, rinit, h_aug, N, R, T, B);
  k_copyin<<<2048, 256, 0, stream>>>(node_emb, h_aug, N, T, B);
  k_colcnt<<<2048, 256, 0, stream>>>(Hinc, TE, E, col_cnt);
  k_scan<<<1, 1024, 0, stream>>>(col_cnt, E, col_ptr, col_cur);
  k_colfill<<<2048, 256, 0, stream>>>(Hinc, TE, E, col_cur, col_idx, cap);
  k_ctxv<<<L, Hd, 0, stream>>>(ctx1, W1h, vbuf);

  int gT = (T + 63)/64, gE = (E + 63)/64;
  for (int l = 0; l < L; ++l){
    size_t wo = (size_t)l*Hd*Hd;
    k_raw<<<dim3(T, B), Hd, 0, stream>>>(h_aug, vbuf + (size_t)l*Hd, rawb, T, scale);
    k_gemm<<<dim3(gT, B), 256, 0, stream>>>(h_aug, W1 + wo, proj1, T);
    k_gemm<<<dim3(gT, B), 256, 0, stream>>>(h_aug, W3 + wo, proj3, T);
    k_edge<<<dim3(E, B), 128, 0, stream>>>(rawb, proj1, col_ptr, col_idx, hyper, T, E, cap);
    k_gemm<<<dim3(gE, B), 256, 0, stream>>>(hyper, W2h + wo, p2hat, E);
    k_gemm<<<dim3(gE, B), 256, 0, stream>>>(hyper, W2 + wo, hw2, E);
    k_node<<<dim3(T, B), 128, 0, stream>>>(Hinc, proj3, p2hat, hw2, lng + (size_t)l*Hd, lnb + (size_t)l*Hd,
                                           h_aug, out, T, E, N, (l == L-1) ? 1 : 0, scale);
  }
}

// Round 3
// 862.533 us; speedup vs baseline: 1.1513x; 1.0644x over previous
//
#include <hip/hip_runtime.h>

#define HD 128
#define MAXM 256
#define ECH 512
#define MAXR 16
#define NB_RS 128

// ---------- reduction helpers (block = 128 threads = 2 waves) ----------
__device__ inline float waveSum(float v){ for(int o=32;o;o>>=1) v += __shfl_down(v,o); return v; }
__device__ inline float waveMax(float v){ for(int o=32;o;o>>=1) v = fmaxf(v,__shfl_down(v,o)); return v; }

__device__ inline float blockSum128(float v, float* red){
  int j = threadIdx.x;
  float s = waveSum(v);
  __syncthreads();
  if ((j & 63) == 0) red[j >> 6] = s;
  __syncthreads();
  return red[0] + red[1];
}
__device__ inline float blockMax128(float v, float* red){
  int j = threadIdx.x;
  float s = waveMax(v);
  __syncthreads();
  if ((j & 63) == 0) red[j >> 6] = s;
  __syncthreads();
  return fmaxf(red[0], red[1]);
}

// ---------- region aggregation ----------
__global__ void k_count(const int* __restrict__ memb, int N, int* __restrict__ counts){
  __shared__ int h[64];
  int tid = threadIdx.x;
  if (tid < 64) h[tid] = 0;
  __syncthreads();
  for (int t = blockIdx.x*blockDim.x + tid; t < N; t += gridDim.x*blockDim.x)
    atomicAdd(&h[memb[t]], 1);
  __syncthreads();
  if (tid < 64){ int v = h[tid]; if (v) atomicAdd(&counts[tid], v); }
}

// fast path (R <= 16): per-thread register accumulators, atomic-free partials
__global__ __launch_bounds__(128) void k_regsum_fast(const float* __restrict__ node,
                        const int* __restrict__ memb, int N, int R,
                        float* __restrict__ partials){
  int b = blockIdx.y, j = threadIdx.x, blk = blockIdx.x;
  int nb = gridDim.x;
  int per = (N + nb - 1) / nb;
  int t0 = blk * per;
  int t1 = t0 + per; if (t1 > N) t1 = N;
  float acc[MAXR];
  #pragma unroll
  for (int i = 0; i < MAXR; ++i) acc[i] = 0.f;
  const float* base = node + (long)b*N*HD + j;
  for (int t = t0; t < t1; ++t){
    float v = base[(long)t*HD];
    int r = memb[t];
    #pragma unroll
    for (int i = 0; i < MAXR; ++i) acc[i] += (i == r) ? v : 0.f;
  }
  float* dst = partials + ((long)(b*nb + blk)*R)*HD + j;
  #pragma unroll
  for (int i = 0; i < MAXR; ++i)
    if (i < R) dst[(long)i*HD] = acc[i];
}

__global__ void k_regsum_lds(const float* __restrict__ node, const int* __restrict__ memb,
                             int N, int R, float* __restrict__ partials, int nb){
  extern __shared__ float acc[];
  int b = blockIdx.y, j = threadIdx.x;
  for (int r = 0; r < R; ++r) acc[r*HD + j] = 0.f;
  int per = (N + gridDim.x - 1) / gridDim.x;
  int t0 = blockIdx.x * per;
  int t1 = t0 + per; if (t1 > N) t1 = N;
  for (int t = t0; t < t1; ++t){
    int r = memb[t];
    acc[r*HD + j] += node[((long)b*N + t)*HD + j];
  }
  for (int r = 0; r < R; ++r)
    atomicAdd(&partials[((long)(b*nb)*R + r)*HD + j], acc[r*HD + j]);
}

__global__ void k_regfin(const float* __restrict__ partials, int nb, int redN,
                         const int* __restrict__ counts,
                         const float* __restrict__ rinit, float* __restrict__ h_aug,
                         int N, int R, int T, int B){
  int i = blockIdx.x*blockDim.x + threadIdx.x;
  if (i >= B*R*HD) return;
  int j = i % HD; int r = (i/HD) % R; int b = i/(HD*R);
  float s = 0.f;
  for (int blk = 0; blk < redN; ++blk)
    s += partials[((long)(b*nb + blk)*R + r)*HD + j];
  int c = counts[r];
  float v = (c > 0) ? s / (float)c : 0.f;
  v += rinit[r*HD + j];
  h_aug[((long)b*T + N + r)*HD + j] = v;
}

__global__ void k_copyin(const float* __restrict__ node, float* __restrict__ h_aug, int N, int T, int B){
  long total = (long)B*N*(HD/4);
  for (long i = blockIdx.x*(long)blockDim.x + threadIdx.x; i < total; i += (long)gridDim.x*blockDim.x){
    long bt = i / (HD/4); int j4 = (int)(i % (HD/4));
    int b = (int)(bt / N); int t = (int)(bt % N);
    ((float4*)h_aug)[((long)b*T + t)*(HD/4) + j4] = ((const float4*)node)[i];
  }
}

// ---------- CSR builders (H_inc is static across batch & layers: build once) ----------
__global__ void k_colcnt(const float* __restrict__ Hinc, long TE, int E, int* __restrict__ cnt){
  for (long i = blockIdx.x*(long)blockDim.x + threadIdx.x; i < TE; i += (long)gridDim.x*blockDim.x)
    if (Hinc[i] != 0.f) atomicAdd(&cnt[(int)(i % E)], 1);
}

__global__ void k_scan(const int* __restrict__ cnt, int E, int* __restrict__ ptr, int* __restrict__ cur){
  __shared__ int s[1024];
  int tid = threadIdx.x;
  int v = (tid < E) ? cnt[tid] : 0;
  s[tid] = v; __syncthreads();
  for (int off = 1; off < 1024; off <<= 1){
    int t = (tid >= off) ? s[tid - off] : 0;
    __syncthreads();
    s[tid] += t;
    __syncthreads();
  }
  if (tid < E){ int excl = s[tid] - v; ptr[tid] = excl; cur[tid] = excl; }
  if (tid == E - 1) ptr[E] = s[tid];
}

__global__ void k_colfill(const float* __restrict__ Hinc, long TE, int E,
                          int* __restrict__ cur, int* __restrict__ idx, int cap){
  for (long i = blockIdx.x*(long)blockDim.x + threadIdx.x; i < TE; i += (long)gridDim.x*blockDim.x)
    if (Hinc[i] != 0.f){
      int e = (int)(i % E);
      int slot = atomicAdd(&cur[e], 1);
      if (slot < cap) idx[slot] = (int)(i / E);
    }
}

// per-row nonzero count (one 128-thread block per row)
__global__ __launch_bounds__(128) void k_rowcnt(const float* __restrict__ Hinc, int E, int* __restrict__ rowcnt){
  int t = blockIdx.x, j = threadIdx.x;
  const float* hrow = Hinc + (long)t*E;
  int cnt = 0;
  for (int i = j; i < E; i += 128) cnt += (hrow[i] != 0.f) ? 1 : 0;
  int s = cnt;
  for (int o = 32; o; o >>= 1) s += __shfl_down(s, o);
  __shared__ int w[2];
  if ((j & 63) == 0) w[j >> 6] = s;
  __syncthreads();
  if (j == 0) rowcnt[t] = w[0] + w[1];
}

// chunked exclusive scan with carry (n up to ~32K)
__global__ void k_scanT(const int* __restrict__ cnt, int n, int* __restrict__ ptr){
  __shared__ int s[1024];
  __shared__ int carry;
  int tid = threadIdx.x;
  if (tid == 0) carry = 0;
  __syncthreads();
  for (int base = 0; base < n; base += 1024){
    int v = (base + tid < n) ? cnt[base + tid] : 0;
    s[tid] = v; __syncthreads();
    for (int off = 1; off < 1024; off <<= 1){
      int t = (tid >= off) ? s[tid - off] : 0;
      __syncthreads();
      s[tid] += t;
      __syncthreads();
    }
    if (base + tid < n) ptr[base + tid] = carry + s[tid] - v;
    __syncthreads();
    if (tid == 0) carry += s[1023];
    __syncthreads();
  }
  if (tid == 0) ptr[n] = carry;
}

// ordered (deterministic) row fill via ballot compaction
__global__ __launch_bounds__(128) void k_rowfill(const float* __restrict__ Hinc, int E,
                          const int* __restrict__ rowptr, int* __restrict__ rowidx, int capR){
  int t = blockIdx.x, j = threadIdx.x;
  int lane = j & 63, wid = j >> 6;
  __shared__ int wsum[2];
  const float* hrow = Hinc + (long)t*E;
  int base0 = rowptr[t];
  int c = 0;
  for (int base = 0; base < E; base += 128){
    bool f = (hrow[base + j] != 0.f);
    unsigned long long mk = __ballot(f);
    if (lane == 0) wsum[wid] = __popcll(mk);
    __syncthreads();
    int w0 = wsum[0], w1 = wsum[1];
    if (f){
      int pos = base0 + c + (wid ? w0 : 0) + (int)__popcll(mk & ((1ull << lane) - 1ull));
      if (pos < capR) rowidx[pos] = base + j;
    }
    c += w0 + w1;
    __syncthreads();
  }
}

// ---------- v_l = ctx1[l] @ W1_hat[l] ----------
__global__ void k_ctxv(const float* __restrict__ ctx1, const float* __restrict__ W1h,
                       float* __restrict__ v){
  int l = blockIdx.x, k = threadIdx.x;
  float a = 0.f;
  for (int j = 0; j < HD; ++j) a += ctx1[l*HD + j] * W1h[((long)l*HD + j)*HD + k];
  v[l*HD + k] = a;
}

__global__ void k_raw(const float* __restrict__ h_aug, const float* __restrict__ v,
                      float* __restrict__ raw, int T, float scale){
  int t = blockIdx.x, b = blockIdx.y, j = threadIdx.x;
  __shared__ float red[2];
  float p = h_aug[((long)b*T + t)*HD + j] * v[j];
  float s = blockSum128(p, red);
  if (j == 0) raw[(long)b*T + t] = s * scale;
}

// ---------- dual GEMM: Ca = A@Wa^T, Cb = A@Wb^T (z picks) ----------
__global__ __launch_bounds__(256) void k_gemm2(const float* __restrict__ A,
                       const float* __restrict__ Wa, const float* __restrict__ Wb,
                       float* __restrict__ Ca, float* __restrict__ Cb, int M){
  const float* W = blockIdx.z ? Wb : Wa;
  float* C = blockIdx.z ? Cb : Ca;
  __shared__ float As[64][33];
  __shared__ float Ws[32][132];
  int b = blockIdx.y;
  const float* Ab = A + (long)b*M*HD;
  float* Cbp = C + (long)b*M*HD;
  int row0 = blockIdx.x * 64;
  int tid = threadIdx.x;
  int tx = tid & 15, ty = tid >> 4;
  float acc[4][8];
  #pragma unroll
  for (int r = 0; r < 4; ++r)
    #pragma unroll
    for (int c = 0; c < 8; ++c) acc[r][c] = 0.f;

  for (int kk = 0; kk < HD; kk += 32){
    #pragma unroll
    for (int i = tid; i < 64*32; i += 256){
      int m = i >> 5, k = i & 31;
      int gr = row0 + m;
      As[m][k] = (gr < M) ? Ab[(long)gr*HD + kk + k] : 0.f;
    }
    #pragma unroll
    for (int i = tid; i < 128*32; i += 256){
      int n = i >> 5, k = i & 31;
      Ws[k][n] = W[(long)n*HD + kk + k];
    }
    __syncthreads();
    #pragma unroll
    for (int k = 0; k < 32; ++k){
      float a0 = As[ty*4+0][k], a1 = As[ty*4+1][k], a2 = As[ty*4+2][k], a3 = As[ty*4+3][k];
      float4 b0 = *(const float4*)&Ws[k][tx*8];
      float4 b1 = *(const float4*)&Ws[k][tx*8+4];
      float bb[8] = {b0.x,b0.y,b0.z,b0.w,b1.x,b1.y,b1.z,b1.w};
      #pragma unroll
      for (int c = 0; c < 8; ++c){
        acc[0][c] += a0*bb[c]; acc[1][c] += a1*bb[c];
        acc[2][c] += a2*bb[c]; acc[3][c] += a3*bb[c];
      }
    }
    __syncthreads();
  }
  #pragma unroll
  for (int r = 0; r < 4; ++r){
    int gr = row0 + ty*4 + r;
    if (gr < M){
      *(float4*)&Cbp[(long)gr*HD + tx*8]   = make_float4(acc[r][0],acc[r][1],acc[r][2],acc[r][3]);
      *(float4*)&Cbp[(long)gr*HD + tx*8+4] = make_float4(acc[r][4],acc[r][5],acc[r][6],acc[r][7]);
    }
  }
}

// ---------- stage 1: per-edge masked softmax + weighted sum of proj1 ----------
__global__ __launch_bounds__(128) void k_edge(const float* __restrict__ raw, const float* __restrict__ proj1,
                      const int* __restrict__ colptr, const int* __restrict__ colidx,
                      float* __restrict__ hyper, int T, int E, int cap){
  int e = blockIdx.x, b = blockIdx.y, j = threadIdx.x;
  __shared__ float red[2];
  __shared__ float wls[ECH];
  __shared__ int   tls[ECH];
  int p0 = colptr[e], p1 = colptr[e+1];
  if (p1 > cap) p1 = cap;
  int c = p1 - p0;
  const float* rawb = raw + (long)b*T;
  if (c <= 0){ hyper[((long)b*E + e)*HD + j] = 0.f; return; }
  float lm = -1e30f;
  for (int i = j; i < c; i += 128) lm = fmaxf(lm, rawb[colidx[p0 + i]]);
  float m = blockMax128(lm, red);
  float lz = 0.f;
  for (int i = j; i < c; i += 128) lz += __expf(rawb[colidx[p0 + i]] - m);
  float Z = blockSum128(lz, red);
  float invZ = 1.f / Z;
  const float* pb = proj1 + (long)b*T*HD + j;
  float accv = 0.f;
  for (int base = 0; base < c; base += ECH){
    int n = c - base; if (n > ECH) n = ECH;
    __syncthreads();
    for (int i = j; i < n; i += 128){
      int t = colidx[p0 + base + i];
      tls[i] = t;
      wls[i] = __expf(rawb[t] - m);
    }
    __syncthreads();
    float a0=0.f,a1=0.f,a2=0.f,a3=0.f;
    int i = 0;
    for (; i + 4 <= n; i += 4){
      a0 += wls[i]   * pb[(long)tls[i]  *HD];
      a1 += wls[i+1] * pb[(long)tls[i+1]*HD];
      a2 += wls[i+2] * pb[(long)tls[i+2]*HD];
      a3 += wls[i+3] * pb[(long)tls[i+3]*HD];
    }
    for (; i < n; ++i) a0 += wls[i] * pb[(long)tls[i]*HD];
    accv += (a0+a1)+(a2+a3);
  }
  hyper[((long)b*E + e)*HD + j] = accv * invZ;
}

// ---------- stage 2: CSR-driven per-node softmax + weighted sum + residual + LN (+ fused next raw) ----------
__global__ __launch_bounds__(128) void k_node(
      const int* __restrict__ rowptr, const int* __restrict__ rowidx, int capR,
      const float* __restrict__ proj3, const float* __restrict__ p2hat, const float* __restrict__ hw2,
      const float* __restrict__ lng, const float* __restrict__ lnb,
      const float* __restrict__ vnext, float* __restrict__ rawnext, int writeRaw,
      float* __restrict__ h_aug, float* __restrict__ out,
      int T, int E, int N, int writeOut, float scale){
  int t = blockIdx.x, b = blockIdx.y, j = threadIdx.x;
  __shared__ __align__(16) float p3[HD];
  __shared__ int   mem[MAXM];
  __shared__ float sv[MAXM];
  __shared__ float red[2];
  long rowb = (long)b*T + t;
  p3[j] = proj3[rowb*HD + j];
  int p0 = rowptr[t], p1 = rowptr[t+1];
  if (p1 > capR) p1 = capR;
  int c = p1 - p0;
  if (c > MAXM) c = MAXM;
  for (int i = j; i < c; i += 128) mem[i] = rowidx[p0 + i];
  __syncthreads();

  float o = 0.f;
  if (c > 0){
    const float* p2b  = p2hat + (long)b*E*HD;
    const float* hw2b = hw2   + (long)b*E*HD;
    int sub = j & 3, grp = j >> 2;
    // scores: 4 lanes per edge, 32-float slices, shfl reduce
    for (int i0 = 0; i0 < c; i0 += 32){
      int i = i0 + grp;
      float s = 0.f;
      if (i < c){
        const float4* pr4 = (const float4*)(p2b + (long)mem[i]*HD) + sub*8;
        const float4* p34 = (const float4*)p3 + sub*8;
        #pragma unroll
        for (int k = 0; k < 8; ++k){
          float4 a = p34[k], q = pr4[k];
          s += a.x*q.x + a.y*q.y + a.z*q.z + a.w*q.w;
        }
      }
      s += __shfl_xor(s, 1);
      s += __shfl_xor(s, 2);
      if (sub == 0 && i < c) sv[i] = s * scale;
    }
    __syncthreads();
    float lm = -1e30f;
    for (int i = j; i < c; i += 128) lm = fmaxf(lm, sv[i]);
    float m = blockMax128(lm, red);
    float lz = 0.f;
    for (int i = j; i < c; i += 128){ float w = __expf(sv[i] - m); sv[i] = w; lz += w; }
    float Z = blockSum128(lz, red);
    float invZ = 1.f / Z;
    const float* hb = hw2b + j;
    float o0=0.f,o1=0.f,o2=0.f,o3=0.f;
    int i = 0;
    for (; i + 4 <= c; i += 4){
      o0 += sv[i]   * hb[(long)mem[i]  *HD];
      o1 += sv[i+1] * hb[(long)mem[i+1]*HD];
      o2 += sv[i+2] * hb[(long)mem[i+2]*HD];
      o3 += sv[i+3] * hb[(long)mem[i+3]*HD];
    }
    for (; i < c; ++i) o0 += sv[i] * hb[(long)mem[i]*HD];
    o = ((o0+o1)+(o2+o3)) * invZ;
  }
  float x = o + h_aug[rowb*HD + j];
  float mean = blockSum128(x, red) * (1.f/HD);
  float d = x - mean;
  float var = blockSum128(d*d, red) * (1.f/HD);
  float y = d * rsqrtf(var + 1e-5f) * lng[j] + lnb[j];
  h_aug[rowb*HD + j] = y;
  if (writeOut && t < N) out[((long)b*N + t)*HD + j] = y;
  if (writeRaw){
    float s = blockSum128(y * vnext[j], red);
    if (j == 0) rawnext[rowb] = s * scale;
  }
}

extern "C" void kernel_launch(void* const* d_in, const int* in_sizes, int n_in,
                              void* d_out, int out_size, void* d_ws, size_t ws_size,
                              hipStream_t stream) {
  const float* node_emb = (const float*)d_in[0];
  const float* Hinc     = (const float*)d_in[1];
  const int*   memb     = (const int*)d_in[2];
  const float* W1       = (const float*)d_in[3];
  const float* W1h      = (const float*)d_in[4];
  const float* ctx1     = (const float*)d_in[5];
  const float* W2       = (const float*)d_in[6];
  const float* W2h      = (const float*)d_in[7];
  const float* W3       = (const float*)d_in[8];
  const float* lng      = (const float*)d_in[9];
  const float* lnb      = (const float*)d_in[10];
  const float* rinit    = (const float*)d_in[11];
  float* out = (float*)d_out;

  const int N  = in_sizes[2];
  const int Hd = in_sizes[3] / in_sizes[5];
  const int L  = in_sizes[5] / Hd;
  const int R  = in_sizes[11] / Hd;
  const int B  = in_sizes[0] / (N * Hd);
  const int T  = N + R;
  const int E  = in_sizes[1] / T;
  const float scale = 1.0f / sqrtf((float)Hd);

  char* p = (char*)d_ws;
  auto carve = [&](size_t bytes){ char* r = p; p += (bytes + 255) & ~(size_t)255; return (void*)r; };
  float* h_aug = (float*)carve((size_t)B*T*Hd*4);
  float* proj1 = (float*)carve((size_t)B*T*Hd*4);
  float* proj3 = (float*)carve((size_t)B*T*Hd*4);
  float* hyper = (float*)carve((size_t)B*E*Hd*4);
  float* rawb  = (float*)carve((size_t)B*T*4);
  float* vbuf  = (float*)carve((size_t)L*Hd*4);
  int* counts  = (int*)carve((size_t)R*4);
  int* col_cnt = (int*)carve((size_t)E*4);
  int* col_ptr = (int*)carve((size_t)(E+1)*4);
  int* col_cur = (int*)carve((size_t)E*4);
  int* row_cnt = (int*)carve((size_t)T*4);
  int* row_ptr = (int*)carve((size_t)(T+1)*4);
  size_t used = (size_t)(p - (char*)d_ws);
  size_t rem  = (ws_size > used) ? (ws_size - used) : 0;
  long TE = (long)T*E;
  long half = (long)(rem / 8);            // ints per idx array
  if (half > TE) half = TE;
  int capC = (int)half, capR = (int)half;
  int* col_idx = (int*)p;
  int* row_idx = col_idx + half;

  // p2hat/hw2 alias proj1 (dead after k_edge each layer); partials alias proj1 too (pre-GEMM)
  float* p2hat = proj1;
  float* hw2   = proj1 + (size_t)B*E*Hd;
  float* partials = proj1;

  hipMemsetAsync(counts, 0, (size_t)R*4, stream);
  hipMemsetAsync(col_cnt, 0, (size_t)E*4, stream);

  k_count<<<32, 256, 0, stream>>>(memb, N, counts);

  int redN;
  if (R <= MAXR){
    k_regsum_fast<<<dim3(NB_RS, B), 128, 0, stream>>>(node_emb, memb, N, R, partials);
    redN = NB_RS;
  } else {
    hipMemsetAsync(partials, 0, (size_t)B*R*Hd*4, stream);
    k_regsum_lds<<<dim3(16, B), Hd, (size_t)R*Hd*4, stream>>>(node_emb, memb, N, R, partials, NB_RS);
    redN = 1;
  }
  int tot = B*R*Hd;
  k_regfin<<<(tot+255)/256, 256, 0, stream>>>(partials, NB_RS, redN, counts, rinit, h_aug, N, R, T, B);
  k_copyin<<<2048, 256, 0, stream>>>(node_emb, h_aug, N, T, B);

  // CSR builds (once per launch)
  k_colcnt<<<2048, 256, 0, stream>>>(Hinc, TE, E, col_cnt);
  k_scan<<<1, 1024, 0, stream>>>(col_cnt, E, col_ptr, col_cur);
  k_colfill<<<2048, 256, 0, stream>>>(Hinc, TE, E, col_cur, col_idx, capC);
  k_rowcnt<<<T, 128, 0, stream>>>(Hinc, E, row_cnt);
  k_scanT<<<1, 1024, 0, stream>>>(row_cnt, T, row_ptr);
  k_rowfill<<<T, 128, 0, stream>>>(Hinc, E, row_ptr, row_idx, capR);

  k_ctxv<<<L, Hd, 0, stream>>>(ctx1, W1h, vbuf);
  k_raw<<<dim3(T, B), Hd, 0, stream>>>(h_aug, vbuf, rawb, T, scale);

  int gT = (T + 63)/64, gE = (E + 63)/64;
  for (int l = 0; l < L; ++l){
    size_t wo = (size_t)l*Hd*Hd;
    k_gemm2<<<dim3(gT, B, 2), 256, 0, stream>>>(h_aug, W1 + wo, W3 + wo, proj1, proj3, T);
    k_edge<<<dim3(E, B), 128, 0, stream>>>(rawb, proj1, col_ptr, col_idx, hyper, T, E, capC);
    k_gemm2<<<dim3(gE, B, 2), 256, 0, stream>>>(hyper, W2h + wo, W2 + wo, p2hat, hw2, E);
    int writeRaw = (l < L-1) ? 1 : 0;
    const float* vnext = vbuf + (size_t)((l+1 < L) ? (l+1) : l)*Hd;
    k_node<<<dim3(T, B), 128, 0, stream>>>(row_ptr, row_idx, capR, proj3, p2hat, hw2,
                                           lng + (size_t)l*Hd, lnb + (size_t)l*Hd,
                                           vnext, rawb, writeRaw,
                                           h_aug, out, T, E, N, (l == L-1) ? 1 : 0, scale);
  }
}

// Round 4
// 859.840 us; speedup vs baseline: 1.1549x; 1.0031x over previous
//
#include <hip/hip_runtime.h>

#define HD 128
#define MAXM 256
#define ECH 512
#define MAXR 16
#define NB_RS 128

typedef unsigned short u16;

__device__ inline float b2f(unsigned u){ return __uint_as_float(u << 16); }
__device__ inline u16 f2b(float x){
  unsigned u = __float_as_uint(x);
  return (u16)((u + 0x7fffu + ((u >> 16) & 1u)) >> 16);
}

// ---------- reduction helpers (block = 128 threads = 2 waves) ----------
__device__ inline float waveSum(float v){ for(int o=32;o;o>>=1) v += __shfl_down(v,o); return v; }
__device__ inline float waveMax(float v){ for(int o=32;o;o>>=1) v = fmaxf(v,__shfl_down(v,o)); return v; }

__device__ inline float blockSum128(float v, float* red){
  int j = threadIdx.x;
  float s = waveSum(v);
  __syncthreads();
  if ((j & 63) == 0) red[j >> 6] = s;
  __syncthreads();
  return red[0] + red[1];
}
__device__ inline float blockMax128(float v, float* red){
  int j = threadIdx.x;
  float s = waveMax(v);
  __syncthreads();
  if ((j & 63) == 0) red[j >> 6] = s;
  __syncthreads();
  return fmaxf(red[0], red[1]);
}

// ---------- region aggregation ----------
__global__ void k_count(const int* __restrict__ memb, int N, int* __restrict__ counts){
  __shared__ int h[64];
  int tid = threadIdx.x;
  if (tid < 64) h[tid] = 0;
  __syncthreads();
  for (int t = blockIdx.x*blockDim.x + tid; t < N; t += gridDim.x*blockDim.x)
    atomicAdd(&h[memb[t]], 1);
  __syncthreads();
  if (tid < 64){ int v = h[tid]; if (v) atomicAdd(&counts[tid], v); }
}

__global__ __launch_bounds__(128) void k_regsum_fast(const float* __restrict__ node,
                        const int* __restrict__ memb, int N, int R,
                        float* __restrict__ partials){
  int b = blockIdx.y, j = threadIdx.x, blk = blockIdx.x;
  int nb = gridDim.x;
  int per = (N + nb - 1) / nb;
  int t0 = blk * per;
  int t1 = t0 + per; if (t1 > N) t1 = N;
  float acc[MAXR];
  #pragma unroll
  for (int i = 0; i < MAXR; ++i) acc[i] = 0.f;
  const float* base = node + (long)b*N*HD + j;
  for (int t = t0; t < t1; ++t){
    float v = base[(long)t*HD];
    int r = memb[t];
    #pragma unroll
    for (int i = 0; i < MAXR; ++i) acc[i] += (i == r) ? v : 0.f;
  }
  float* dst = partials + ((long)(b*nb + blk)*R)*HD + j;
  #pragma unroll
  for (int i = 0; i < MAXR; ++i)
    if (i < R) dst[(long)i*HD] = acc[i];
}

__global__ void k_regsum_lds(const float* __restrict__ node, const int* __restrict__ memb,
                             int N, int R, float* __restrict__ partials, int nb){
  extern __shared__ float acc[];
  int b = blockIdx.y, j = threadIdx.x;
  for (int r = 0; r < R; ++r) acc[r*HD + j] = 0.f;
  int per = (N + gridDim.x - 1) / gridDim.x;
  int t0 = blockIdx.x * per;
  int t1 = t0 + per; if (t1 > N) t1 = N;
  for (int t = t0; t < t1; ++t){
    int r = memb[t];
    acc[r*HD + j] += node[((long)b*N + t)*HD + j];
  }
  for (int r = 0; r < R; ++r)
    atomicAdd(&partials[((long)(b*nb)*R + r)*HD + j], acc[r*HD + j]);
}

__global__ void k_regfin(const float* __restrict__ partials, int nb, int redN,
                         const int* __restrict__ counts,
                         const float* __restrict__ rinit, float* __restrict__ h_aug,
                         int N, int R, int T, int B){
  int i = blockIdx.x*blockDim.x + threadIdx.x;
  if (i >= B*R*HD) return;
  int j = i % HD; int r = (i/HD) % R; int b = i/(HD*R);
  float s = 0.f;
  for (int blk = 0; blk < redN; ++blk)
    s += partials[((long)(b*nb + blk)*R + r)*HD + j];
  int c = counts[r];
  float v = (c > 0) ? s / (float)c : 0.f;
  v += rinit[r*HD + j];
  h_aug[((long)b*T + N + r)*HD + j] = v;
}

__global__ void k_copyin(const float* __restrict__ node, float* __restrict__ h_aug, int N, int T, int B){
  long total = (long)B*N*(HD/4);
  for (long i = blockIdx.x*(long)blockDim.x + threadIdx.x; i < total; i += (long)gridDim.x*blockDim.x){
    long bt = i / (HD/4); int j4 = (int)(i % (HD/4));
    int b = (int)(bt / N); int t = (int)(bt % N);
    ((float4*)h_aug)[((long)b*T + t)*(HD/4) + j4] = ((const float4*)node)[i];
  }
}

// ---------- CSR builders (H_inc static: build once per launch) ----------
__global__ void k_colcnt(const float* __restrict__ Hinc, long TE, int E, int* __restrict__ cnt){
  for (long i = blockIdx.x*(long)blockDim.x + threadIdx.x; i < TE; i += (long)gridDim.x*blockDim.x)
    if (Hinc[i] != 0.f) atomicAdd(&cnt[(int)(i % E)], 1);
}

__global__ void k_scan(const int* __restrict__ cnt, int E, int* __restrict__ ptr, int* __restrict__ cur){
  __shared__ int s[1024];
  int tid = threadIdx.x;
  int v = (tid < E) ? cnt[tid] : 0;
  s[tid] = v; __syncthreads();
  for (int off = 1; off < 1024; off <<= 1){
    int t = (tid >= off) ? s[tid - off] : 0;
    __syncthreads();
    s[tid] += t;
    __syncthreads();
  }
  if (tid < E){ int excl = s[tid] - v; ptr[tid] = excl; cur[tid] = excl; }
  if (tid == E - 1) ptr[E] = s[tid];
}

__global__ void k_colfill(const float* __restrict__ Hinc, long TE, int E,
                          int* __restrict__ cur, int* __restrict__ idx, int cap){
  for (long i = blockIdx.x*(long)blockDim.x + threadIdx.x; i < TE; i += (long)gridDim.x*blockDim.x)
    if (Hinc[i] != 0.f){
      int e = (int)(i % E);
      int slot = atomicAdd(&cur[e], 1);
      if (slot < cap) idx[slot] = (int)(i / E);
    }
}

__global__ __launch_bounds__(128) void k_rowcnt(const float* __restrict__ Hinc, int E, int* __restrict__ rowcnt){
  int t = blockIdx.x, j = threadIdx.x;
  const float* hrow = Hinc + (long)t*E;
  int cnt = 0;
  for (int i = j; i < E; i += 128) cnt += (hrow[i] != 0.f) ? 1 : 0;
  int s = cnt;
  for (int o = 32; o; o >>= 1) s += __shfl_down(s, o);
  __shared__ int w[2];
  if ((j & 63) == 0) w[j >> 6] = s;
  __syncthreads();
  if (j == 0) rowcnt[t] = w[0] + w[1];
}

__global__ void k_scanT(const int* __restrict__ cnt, int n, int* __restrict__ ptr){
  __shared__ int s[1024];
  __shared__ int carry;
  int tid = threadIdx.x;
  if (tid == 0) carry = 0;
  __syncthreads();
  for (int base = 0; base < n; base += 1024){
    int v = (base + tid < n) ? cnt[base + tid] : 0;
    s[tid] = v; __syncthreads();
    for (int off = 1; off < 1024; off <<= 1){
      int t = (tid >= off) ? s[tid - off] : 0;
      __syncthreads();
      s[tid] += t;
      __syncthreads();
    }
    if (base + tid < n) ptr[base + tid] = carry + s[tid] - v;
    __syncthreads();
    if (tid == 0) carry += s[1023];
    __syncthreads();
  }
  if (tid == 0) ptr[n] = carry;
}

__global__ __launch_bounds__(128) void k_rowfill(const float* __restrict__ Hinc, int E,
                          const int* __restrict__ rowptr, int* __restrict__ rowidx, int capR){
  int t = blockIdx.x, j = threadIdx.x;
  int lane = j & 63, wid = j >> 6;
  __shared__ int wsum[2];
  const float* hrow = Hinc + (long)t*E;
  int base0 = rowptr[t];
  int c = 0;
  for (int base = 0; base < E; base += 128){
    bool f = (hrow[base + j] != 0.f);
    unsigned long long mk = __ballot(f);
    if (lane == 0) wsum[wid] = __popcll(mk);
    __syncthreads();
    int w0 = wsum[0], w1 = wsum[1];
    if (f){
      int pos = base0 + c + (wid ? w0 : 0) + (int)__popcll(mk & ((1ull << lane) - 1ull));
      if (pos < capR) rowidx[pos] = base + j;
    }
    c += w0 + w1;
    __syncthreads();
  }
}

// ---------- small precomputes ----------
__global__ void k_ctxv(const float* __restrict__ ctx1, const float* __restrict__ W1h,
                       float* __restrict__ v){
  int l = blockIdx.x, k = threadIdx.x;
  float a = 0.f;
  for (int j = 0; j < HD; ++j) a += ctx1[l*HD + j] * W1h[((long)l*HD + j)*HD + k];
  v[l*HD + k] = a;
}

// MqT[l][n][k] = sum_j W2h[l][j][n] * W3[l][j][k]   (so qt = h @ MqT^T gives h·(W3^T W2h))
__global__ void k_mm128(const float* __restrict__ W2h, const float* __restrict__ W3,
                        float* __restrict__ MqT){
  int n = blockIdx.x, l = blockIdx.y, k = threadIdx.x;
  const float* A = W2h + (long)l*HD*HD;
  const float* Bm = W3 + (long)l*HD*HD;
  float s = 0.f;
  for (int j = 0; j < HD; ++j) s += A[(long)j*HD + n] * Bm[(long)j*HD + k];
  MqT[((long)l*HD + n)*HD + k] = s;
}

__global__ void k_raw(const float* __restrict__ h_aug, const float* __restrict__ v,
                      float* __restrict__ raw, int T, float scale){
  int t = blockIdx.x, b = blockIdx.y, j = threadIdx.x;
  __shared__ float red[2];
  float p = h_aug[((long)b*T + t)*HD + j] * v[j];
  float s = blockSum128(p, red);
  if (j == 0) raw[(long)b*T + t] = s * scale;
}

// ---------- dual GEMM: z=0 -> bf16 out (Wa), z=1 -> f32 out (Wb) ----------
__global__ __launch_bounds__(256) void k_gemm2b(const float* __restrict__ A,
                       const float* __restrict__ Wa, const float* __restrict__ Wb,
                       u16* __restrict__ Cb16, float* __restrict__ Cf32, int M){
  int isB = (blockIdx.z == 0) ? 1 : 0;
  const float* W = isB ? Wa : Wb;
  __shared__ float As[64][33];
  __shared__ float Ws[32][132];
  int b = blockIdx.y;
  const float* Ab = A + (long)b*M*HD;
  int row0 = blockIdx.x * 64;
  int tid = threadIdx.x;
  int tx = tid & 15, ty = tid >> 4;
  float acc[4][8];
  #pragma unroll
  for (int r = 0; r < 4; ++r)
    #pragma unroll
    for (int c = 0; c < 8; ++c) acc[r][c] = 0.f;

  for (int kk = 0; kk < HD; kk += 32){
    #pragma unroll
    for (int i = tid; i < 64*32; i += 256){
      int m = i >> 5, k = i & 31;
      int gr = row0 + m;
      As[m][k] = (gr < M) ? Ab[(long)gr*HD + kk + k] : 0.f;
    }
    #pragma unroll
    for (int i = tid; i < 128*32; i += 256){
      int n = i >> 5, k = i & 31;
      Ws[k][n] = W[(long)n*HD + kk + k];
    }
    __syncthreads();
    #pragma unroll
    for (int k = 0; k < 32; ++k){
      float a0 = As[ty*4+0][k], a1 = As[ty*4+1][k], a2 = As[ty*4+2][k], a3 = As[ty*4+3][k];
      float4 b0 = *(const float4*)&Ws[k][tx*8];
      float4 b1 = *(const float4*)&Ws[k][tx*8+4];
      float bb[8] = {b0.x,b0.y,b0.z,b0.w,b1.x,b1.y,b1.z,b1.w};
      #pragma unroll
      for (int c = 0; c < 8; ++c){
        acc[0][c] += a0*bb[c]; acc[1][c] += a1*bb[c];
        acc[2][c] += a2*bb[c]; acc[3][c] += a3*bb[c];
      }
    }
    __syncthreads();
  }
  #pragma unroll
  for (int r = 0; r < 4; ++r){
    int gr = row0 + ty*4 + r;
    if (gr >= M) continue;
    if (isB){
      u16* Cb = Cb16 + (long)b*M*HD;
      uint4 pk;
      pk.x = (unsigned)f2b(acc[r][0]) | ((unsigned)f2b(acc[r][1]) << 16);
      pk.y = (unsigned)f2b(acc[r][2]) | ((unsigned)f2b(acc[r][3]) << 16);
      pk.z = (unsigned)f2b(acc[r][4]) | ((unsigned)f2b(acc[r][5]) << 16);
      pk.w = (unsigned)f2b(acc[r][6]) | ((unsigned)f2b(acc[r][7]) << 16);
      *(uint4*)&Cb[(long)gr*HD + tx*8] = pk;
    } else {
      float* Cb = Cf32 + (long)b*M*HD;
      *(float4*)&Cb[(long)gr*HD + tx*8]   = make_float4(acc[r][0],acc[r][1],acc[r][2],acc[r][3]);
      *(float4*)&Cb[(long)gr*HD + tx*8+4] = make_float4(acc[r][4],acc[r][5],acc[r][6],acc[r][7]);
    }
  }
}

// ---------- stage 1: per-edge masked softmax + weighted sum of proj1 (bf16 gather) ----------
__global__ __launch_bounds__(128) void k_edge(int swz, const float* __restrict__ raw,
                      const u16* __restrict__ proj1b,
                      const int* __restrict__ colptr, const int* __restrict__ colidx,
                      float* __restrict__ hyper, u16* __restrict__ hyb, int T, int E, int cap){
  int bi = blockIdx.x;
  int b, e;
  if (swz){ int x = bi & 7; b = x >> 1; e = ((bi >> 3) << 1) | (x & 1); }
  else    { b = bi / E; e = bi - b*E; }
  int j = threadIdx.x;
  __shared__ float red[2];
  __shared__ float wls[ECH];
  __shared__ int   tls[ECH];
  int p0 = colptr[e], p1 = colptr[e+1];
  if (p1 > cap) p1 = cap;
  int c = p1 - p0;
  const float* rawb = raw + (long)b*T;
  long orow = ((long)b*E + e)*HD + j;
  if (c <= 0){ hyper[orow] = 0.f; hyb[orow] = f2b(0.f); return; }
  float lm = -1e30f;
  for (int i = j; i < c; i += 128) lm = fmaxf(lm, rawb[colidx[p0 + i]]);
  float m = blockMax128(lm, red);
  float lz = 0.f;
  for (int i = j; i < c; i += 128) lz += __expf(rawb[colidx[p0 + i]] - m);
  float Z = blockSum128(lz, red);
  float invZ = 1.f / Z;
  const u16* pb = proj1b + (long)b*T*HD + j;
  float accv = 0.f;
  for (int base = 0; base < c; base += ECH){
    int n = c - base; if (n > ECH) n = ECH;
    __syncthreads();
    for (int i = j; i < n; i += 128){
      int t = colidx[p0 + base + i];
      tls[i] = t;
      wls[i] = __expf(rawb[t] - m);
    }
    __syncthreads();
    float a0=0.f,a1=0.f,a2=0.f,a3=0.f;
    int i = 0;
    for (; i + 4 <= n; i += 4){
      a0 += wls[i]   * b2f(pb[(long)tls[i]  *HD]);
      a1 += wls[i+1] * b2f(pb[(long)tls[i+1]*HD]);
      a2 += wls[i+2] * b2f(pb[(long)tls[i+2]*HD]);
      a3 += wls[i+3] * b2f(pb[(long)tls[i+3]*HD]);
    }
    for (; i < n; ++i) a0 += wls[i] * b2f(pb[(long)tls[i]*HD]);
    accv += (a0+a1)+(a2+a3);
  }
  float hv = accv * invZ;
  hyper[orow] = hv;
  hyb[orow] = f2b(hv);
}

// ---------- stage 2: scores vs hyper(bf16), PV vs hw2(bf16), residual + LN (+ fused next raw) ----------
__global__ __launch_bounds__(128) void k_node(int swz,
      const int* __restrict__ rowptr, const int* __restrict__ rowidx, int capR,
      const float* __restrict__ qt, const u16* __restrict__ hyb, const u16* __restrict__ hw2b,
      const float* __restrict__ lng, const float* __restrict__ lnb,
      const float* __restrict__ vnext, float* __restrict__ rawnext, int writeRaw,
      float* __restrict__ h_aug, float* __restrict__ out,
      int T, int E, int N, int writeOut, float scale){
  int bi = blockIdx.x;
  int b, t;
  if (swz){ int x = bi & 7; b = x >> 1; t = ((bi >> 3) << 1) | (x & 1); }
  else    { b = bi / T; t = bi - b*T; }
  int j = threadIdx.x;
  __shared__ __align__(16) float qs[HD];
  __shared__ int   mem[MAXM];
  __shared__ float sv[MAXM];
  __shared__ float red[2];
  long rowb = (long)b*T + t;
  qs[j] = qt[rowb*HD + j];
  int p0 = rowptr[t], p1 = rowptr[t+1];
  if (p1 > capR) p1 = capR;
  int c = p1 - p0;
  if (c > MAXM) c = MAXM;
  for (int i = j; i < c; i += 128) mem[i] = rowidx[p0 + i];
  __syncthreads();

  float o = 0.f;
  if (c > 0){
    const u16* hyE = hyb + (long)b*E*HD;
    int sub = j & 3, grp = j >> 2;
    const float4* qv = (const float4*)qs;
    // scores: 4 lanes per edge; lane sub reads contiguous 16B chunks hr[u*4+sub]
    for (int i0 = 0; i0 < c; i0 += 32){
      int e = i0 + grp;
      float s = 0.f;
      if (e < c){
        const uint4* hr = (const uint4*)(hyE + (long)mem[e]*HD);
        #pragma unroll
        for (int u = 0; u < 4; ++u){
          uint4 w = hr[u*4 + sub];
          float4 qa = qv[u*8 + sub*2], qb = qv[u*8 + sub*2 + 1];
          s += b2f(w.x & 0xffffu)*qa.x + b2f(w.x >> 16)*qa.y
             + b2f(w.y & 0xffffu)*qa.z + b2f(w.y >> 16)*qa.w
             + b2f(w.z & 0xffffu)*qb.x + b2f(w.z >> 16)*qb.y
             + b2f(w.w & 0xffffu)*qb.z + b2f(w.w >> 16)*qb.w;
        }
      }
      s += __shfl_xor(s, 1);
      s += __shfl_xor(s, 2);
      if (sub == 0 && e < c) sv[e] = s * scale;
    }
    __syncthreads();
    float lm = -1e30f;
    for (int i = j; i < c; i += 128) lm = fmaxf(lm, sv[i]);
    float m = blockMax128(lm, red);
    float lz = 0.f;
    for (int i = j; i < c; i += 128){ float w = __expf(sv[i] - m); sv[i] = w; lz += w; }
    float Z = blockSum128(lz, red);
    float invZ = 1.f / Z;
    const u16* hb = hw2b + (long)b*E*HD + j;
    float o0=0.f,o1=0.f,o2=0.f,o3=0.f;
    int i = 0;
    for (; i + 4 <= c; i += 4){
      o0 += sv[i]   * b2f(hb[(long)mem[i]  *HD]);
      o1 += sv[i+1] * b2f(hb[(long)mem[i+1]*HD]);
      o2 += sv[i+2] * b2f(hb[(long)mem[i+2]*HD]);
      o3 += sv[i+3] * b2f(hb[(long)mem[i+3]*HD]);
    }
    for (; i < c; ++i) o0 += sv[i] * b2f(hb[(long)mem[i]*HD]);
    o = ((o0+o1)+(o2+o3)) * invZ;
  }
  float x = o + h_aug[rowb*HD + j];
  float mean = blockSum128(x, red) * (1.f/HD);
  float d = x - mean;
  float var = blockSum128(d*d, red) * (1.f/HD);
  float y = d * rsqrtf(var + 1e-5f) * lng[j] + lnb[j];
  if (writeOut){
    if (t < N) out[((long)b*N + t)*HD + j] = y;
  } else {
    h_aug[rowb*HD + j] = y;
  }
  if (writeRaw){
    float s = blockSum128(y * vnext[j], red);
    if (j == 0) rawnext[rowb] = s * scale;
  }
}

extern "C" void kernel_launch(void* const* d_in, const int* in_sizes, int n_in,
                              void* d_out, int out_size, void* d_ws, size_t ws_size,
                              hipStream_t stream) {
  const float* node_emb = (const float*)d_in[0];
  const float* Hinc     = (const float*)d_in[1];
  const int*   memb     = (const int*)d_in[2];
  const float* W1       = (const float*)d_in[3];
  const float* W1h      = (const float*)d_in[4];
  const float* ctx1     = (const float*)d_in[5];
  const float* W2       = (const float*)d_in[6];
  const float* W2h      = (const float*)d_in[7];
  const float* W3       = (const float*)d_in[8];
  const float* lng      = (const float*)d_in[9];
  const float* lnb      = (const float*)d_in[10];
  const float* rinit    = (const float*)d_in[11];
  float* out = (float*)d_out;

  const int N  = in_sizes[2];
  const int Hd = in_sizes[3] / in_sizes[5];
  const int L  = in_sizes[5] / Hd;
  const int R  = in_sizes[11] / Hd;
  const int B  = in_sizes[0] / (N * Hd);
  const int T  = N + R;
  const int E  = in_sizes[1] / T;
  const float scale = 1.0f / sqrtf((float)Hd);

  char* p = (char*)d_ws;
  auto carve = [&](size_t bytes){ char* r = p; p += (bytes + 255) & ~(size_t)255; return (void*)r; };
  float* h_aug  = (float*)carve((size_t)B*T*Hd*4);
  u16*   proj1b = (u16*)  carve((size_t)B*T*Hd*2);
  float* qt     = (float*)carve((size_t)B*T*Hd*4);
  float* hyper  = (float*)carve((size_t)B*E*Hd*4);
  u16*   hyb    = (u16*)  carve((size_t)B*E*Hd*2);
  u16*   hw2b   = (u16*)  carve((size_t)B*E*Hd*2);
  float* MqT    = (float*)carve((size_t)L*Hd*Hd*4);
  float* rawb   = (float*)carve((size_t)B*T*4);
  float* vbuf   = (float*)carve((size_t)L*Hd*4);
  int* counts  = (int*)carve((size_t)R*4);
  int* col_cnt = (int*)carve((size_t)E*4);
  int* col_ptr = (int*)carve((size_t)(E+1)*4);
  int* col_cur = (int*)carve((size_t)E*4);
  int* row_cnt = (int*)carve((size_t)T*4);
  int* row_ptr = (int*)carve((size_t)(T+1)*4);
  size_t used = (size_t)(p - (char*)d_ws);
  size_t rem  = (ws_size > used) ? (ws_size - used) : 0;
  long TE = (long)T*E;
  long half = (long)(rem / 8);
  if (half > TE) half = TE;
  int capC = (int)half, capR = (int)half;
  int* col_idx = (int*)p;
  int* row_idx = col_idx + half;

  // partials alias qt (dead until first k_gemm2b, which runs after k_regfin)
  float* partials = qt;

  hipMemsetAsync(counts, 0, (size_t)R*4, stream);
  hipMemsetAsync(col_cnt, 0, (size_t)E*4, stream);

  k_count<<<32, 256, 0, stream>>>(memb, N, counts);

  int redN;
  if (R <= MAXR){
    k_regsum_fast<<<dim3(NB_RS, B), 128, 0, stream>>>(node_emb, memb, N, R, partials);
    redN = NB_RS;
  } else {
    hipMemsetAsync(partials, 0, (size_t)B*R*Hd*4, stream);
    k_regsum_lds<<<dim3(16, B), Hd, (size_t)R*Hd*4, stream>>>(node_emb, memb, N, R, partials, NB_RS);
    redN = 1;
  }
  int tot = B*R*Hd;
  k_regfin<<<(tot+255)/256, 256, 0, stream>>>(partials, NB_RS, redN, counts, rinit, h_aug, N, R, T, B);
  k_copyin<<<2048, 256, 0, stream>>>(node_emb, h_aug, N, T, B);

  // CSR builds (once per launch)
  k_colcnt<<<2048, 256, 0, stream>>>(Hinc, TE, E, col_cnt);
  k_scan<<<1, 1024, 0, stream>>>(col_cnt, E, col_ptr, col_cur);
  k_colfill<<<2048, 256, 0, stream>>>(Hinc, TE, E, col_cur, col_idx, capC);
  k_rowcnt<<<T, 128, 0, stream>>>(Hinc, E, row_cnt);
  k_scanT<<<1, 1024, 0, stream>>>(row_cnt, T, row_ptr);
  k_rowfill<<<T, 128, 0, stream>>>(Hinc, E, row_ptr, row_idx, capR);

  k_ctxv<<<L, Hd, 0, stream>>>(ctx1, W1h, vbuf);
  k_mm128<<<dim3(Hd, L), Hd, 0, stream>>>(W2h, W3, MqT);
  k_raw<<<dim3(T, B), Hd, 0, stream>>>(h_aug, vbuf, rawb, T, scale);

  int gT = (T + 63)/64, gE = (E + 63)/64;
  int swzE = (B == 4 && (E & 1) == 0) ? 1 : 0;
  int swzN = (B == 4 && (T & 1) == 0) ? 1 : 0;
  for (int l = 0; l < L; ++l){
    size_t wo = (size_t)l*Hd*Hd;
    // proj1 (bf16) = h@W1^T ; qt (f32) = h@MqT^T
    k_gemm2b<<<dim3(gT, B, 2), 256, 0, stream>>>(h_aug, W1 + wo, MqT + wo, proj1b, qt, T);
    k_edge<<<B*E, 128, 0, stream>>>(swzE, rawb, proj1b, col_ptr, col_idx, hyper, hyb, T, E, capC);
    // hw2 (bf16) = hyper@W2^T
    k_gemm2b<<<dim3(gE, B, 1), 256, 0, stream>>>(hyper, W2 + wo, nullptr, hw2b, nullptr, E);
    int writeRaw = (l < L-1) ? 1 : 0;
    const float* vnext = vbuf + (size_t)((l+1 < L) ? (l+1) : l)*Hd;
    k_node<<<B*T, 128, 0, stream>>>(swzN, row_ptr, row_idx, capR, qt, hyb, hw2b,
                                    lng + wo/Hd, lnb + wo/Hd,
                                    vnext, rawb, writeRaw,
                                    h_aug, out, T, E, N, (l == L-1) ? 1 : 0, scale);
  }
}

// Round 5
// 757.594 us; speedup vs baseline: 1.3107x; 1.1350x over previous
//
#include <hip/hip_runtime.h>

#define HD 128
#define MAXM 256
#define CAPE 768
#define ECH 512
#define MAXR 16
#define NB_RS 128

typedef unsigned short u16;

__device__ inline float b2f(unsigned u){ return __uint_as_float(u << 16); }
__device__ inline u16 f2b(float x){
  unsigned u = __float_as_uint(x);
  return (u16)((u + 0x7fffu + ((u >> 16) & 1u)) >> 16);
}

// ---------- reduction helpers (block = 128 threads = 2 waves) ----------
__device__ inline float waveSum(float v){ for(int o=32;o;o>>=1) v += __shfl_down(v,o); return v; }
__device__ inline float waveMax(float v){ for(int o=32;o;o>>=1) v = fmaxf(v,__shfl_down(v,o)); return v; }

__device__ inline float blockSum128(float v, float* red){
  int j = threadIdx.x;
  float s = waveSum(v);
  __syncthreads();
  if ((j & 63) == 0) red[j >> 6] = s;
  __syncthreads();
  return red[0] + red[1];
}
__device__ inline float blockMax128(float v, float* red){
  int j = threadIdx.x;
  float s = waveMax(v);
  __syncthreads();
  if ((j & 63) == 0) red[j >> 6] = s;
  __syncthreads();
  return fmaxf(red[0], red[1]);
}

// ---------- region aggregation ----------
__global__ void k_count(const int* __restrict__ memb, int N, int* __restrict__ counts){
  __shared__ int h[64];
  int tid = threadIdx.x;
  if (tid < 64) h[tid] = 0;
  __syncthreads();
  for (int t = blockIdx.x*blockDim.x + tid; t < N; t += gridDim.x*blockDim.x)
    atomicAdd(&h[memb[t]], 1);
  __syncthreads();
  if (tid < 64){ int v = h[tid]; if (v) atomicAdd(&counts[tid], v); }
}

__global__ __launch_bounds__(128) void k_regsum_fast(const float* __restrict__ node,
                        const int* __restrict__ memb, int N, int R,
                        float* __restrict__ partials){
  int b = blockIdx.y, j = threadIdx.x, blk = blockIdx.x;
  int nb = gridDim.x;
  int per = (N + nb - 1) / nb;
  int t0 = blk * per;
  int t1 = t0 + per; if (t1 > N) t1 = N;
  float acc[MAXR];
  #pragma unroll
  for (int i = 0; i < MAXR; ++i) acc[i] = 0.f;
  const float* base = node + (long)b*N*HD + j;
  for (int t = t0; t < t1; ++t){
    float v = base[(long)t*HD];
    int r = memb[t];
    #pragma unroll
    for (int i = 0; i < MAXR; ++i) acc[i] += (i == r) ? v : 0.f;
  }
  float* dst = partials + ((long)(b*nb + blk)*R)*HD + j;
  #pragma unroll
  for (int i = 0; i < MAXR; ++i)
    if (i < R) dst[(long)i*HD] = acc[i];
}

__global__ void k_regsum_lds(const float* __restrict__ node, const int* __restrict__ memb,
                             int N, int R, float* __restrict__ partials, int nb){
  extern __shared__ float acc[];
  int b = blockIdx.y, j = threadIdx.x;
  for (int r = 0; r < R; ++r) acc[r*HD + j] = 0.f;
  int per = (N + gridDim.x - 1) / gridDim.x;
  int t0 = blockIdx.x * per;
  int t1 = t0 + per; if (t1 > N) t1 = N;
  for (int t = t0; t < t1; ++t){
    int r = memb[t];
    acc[r*HD + j] += node[((long)b*N + t)*HD + j];
  }
  for (int r = 0; r < R; ++r)
    atomicAdd(&partials[((long)(b*nb)*R + r)*HD + j], acc[r*HD + j]);
}

__global__ void k_regfin(const float* __restrict__ partials, int nb, int redN,
                         const int* __restrict__ counts,
                         const float* __restrict__ rinit, float* __restrict__ h_aug,
                         int N, int R, int T, int B){
  int i = blockIdx.x*blockDim.x + threadIdx.x;
  if (i >= B*R*HD) return;
  int j = i % HD; int r = (i/HD) % R; int b = i/(HD*R);
  float s = 0.f;
  for (int blk = 0; blk < redN; ++blk)
    s += partials[((long)(b*nb + blk)*R + r)*HD + j];
  int c = counts[r];
  float v = (c > 0) ? s / (float)c : 0.f;
  v += rinit[r*HD + j];
  h_aug[((long)b*T + N + r)*HD + j] = v;
}

// copy node rows into h_aug AND compute raw = (h·v)*scale (fused)
__global__ __launch_bounds__(128) void k_copyraw(const float* __restrict__ node,
                      const float* __restrict__ v, float* __restrict__ h_aug,
                      float* __restrict__ raw, int N, int T, float scale){
  int t = blockIdx.x, b = blockIdx.y, j = threadIdx.x;
  __shared__ float red[2];
  long rowb = (long)b*T + t;
  float x;
  if (t < N){ x = node[((long)b*N + t)*HD + j]; h_aug[rowb*HD + j] = x; }
  else      { x = h_aug[rowb*HD + j]; }
  float s = blockSum128(x * v[j], red);
  if (j == 0) raw[rowb] = s * scale;
}

// ---------- padded index builders (H_inc static: build once per launch) ----------
// rows: ballot-ordered (deterministic), one block per row
__global__ __launch_bounds__(128) void k_rowbuild(const float* __restrict__ Hinc, int E,
                          u16* __restrict__ rowidx, int* __restrict__ rowcnt){
  int t = blockIdx.x, j = threadIdx.x;
  int lane = j & 63, wid = j >> 6;
  __shared__ int wsum[2];
  const float* hrow = Hinc + (long)t*E;
  int c = 0;
  for (int base = 0; base < E; base += 128){
    bool f = (base + j < E) && (hrow[base + j] != 0.f);
    unsigned long long mk = __ballot(f);
    if (lane == 0) wsum[wid] = __popcll(mk);
    __syncthreads();
    int w0 = wsum[0], w1 = wsum[1];
    if (f){
      int pos = c + (wid ? w0 : 0) + (int)__popcll(mk & ((1ull << lane) - 1ull));
      if (pos < MAXM) rowidx[(long)t*MAXM + pos] = (u16)(base + j);
    }
    c += w0 + w1;
    __syncthreads();
  }
  if (j == 0) rowcnt[t] = (c < MAXM) ? c : MAXM;
}

// cols: atomic slot fill (set deterministic; order not — summation tolerance ok)
__global__ void k_colbuild(const float* __restrict__ Hinc, long TE, int E,
                           int* __restrict__ colcnt, u16* __restrict__ colidx){
  for (long i = blockIdx.x*(long)blockDim.x + threadIdx.x; i < TE; i += (long)gridDim.x*blockDim.x)
    if (Hinc[i] != 0.f){
      int e = (int)(i % E);
      int slot = atomicAdd(&colcnt[e], 1);
      if (slot < CAPE) colidx[(long)e*CAPE + slot] = (u16)(i / E);
    }
}

// ---------- small precomputes ----------
__global__ void k_ctxv(const float* __restrict__ ctx1, const float* __restrict__ W1h,
                       float* __restrict__ v){
  int l = blockIdx.x, k = threadIdx.x;
  float a = 0.f;
  for (int j = 0; j < HD; ++j) a += ctx1[l*HD + j] * W1h[((long)l*HD + j)*HD + k];
  v[l*HD + k] = a;
}

// MqT[l][n][k] = sum_j W2h[l][j][n] * W3[l][j][k]
__global__ void k_mm128(const float* __restrict__ W2h, const float* __restrict__ W3,
                        float* __restrict__ MqT){
  int n = blockIdx.x, l = blockIdx.y, k = threadIdx.x;
  const float* A = W2h + (long)l*HD*HD;
  const float* Bm = W3 + (long)l*HD*HD;
  float s = 0.f;
  for (int j = 0; j < HD; ++j) s += A[(long)j*HD + n] * Bm[(long)j*HD + k];
  MqT[((long)l*HD + n)*HD + k] = s;
}

// ---------- dual GEMM: (z+zbase)==0 -> bf16 out (Wa), else f32 out (Wb) ----------
__global__ __launch_bounds__(256) void k_gemm2b(const float* __restrict__ A,
                       const float* __restrict__ Wa, const float* __restrict__ Wb,
                       u16* __restrict__ Cb16, float* __restrict__ Cf32, int M, int zbase){
  int isB = ((blockIdx.z + zbase) == 0) ? 1 : 0;
  const float* W = isB ? Wa : Wb;
  __shared__ float As[64][33];
  __shared__ float Ws[32][132];
  int b = blockIdx.y;
  const float* Ab = A + (long)b*M*HD;
  int row0 = blockIdx.x * 64;
  int tid = threadIdx.x;
  int tx = tid & 15, ty = tid >> 4;
  float acc[4][8];
  #pragma unroll
  for (int r = 0; r < 4; ++r)
    #pragma unroll
    for (int c = 0; c < 8; ++c) acc[r][c] = 0.f;

  for (int kk = 0; kk < HD; kk += 32){
    #pragma unroll
    for (int i = tid; i < 64*32; i += 256){
      int m = i >> 5, k = i & 31;
      int gr = row0 + m;
      As[m][k] = (gr < M) ? Ab[(long)gr*HD + kk + k] : 0.f;
    }
    #pragma unroll
    for (int i = tid; i < 128*32; i += 256){
      int n = i >> 5, k = i & 31;
      Ws[k][n] = W[(long)n*HD + kk + k];
    }
    __syncthreads();
    #pragma unroll
    for (int k = 0; k < 32; ++k){
      float a0 = As[ty*4+0][k], a1 = As[ty*4+1][k], a2 = As[ty*4+2][k], a3 = As[ty*4+3][k];
      float4 b0 = *(const float4*)&Ws[k][tx*8];
      float4 b1 = *(const float4*)&Ws[k][tx*8+4];
      float bb[8] = {b0.x,b0.y,b0.z,b0.w,b1.x,b1.y,b1.z,b1.w};
      #pragma unroll
      for (int c = 0; c < 8; ++c){
        acc[0][c] += a0*bb[c]; acc[1][c] += a1*bb[c];
        acc[2][c] += a2*bb[c]; acc[3][c] += a3*bb[c];
      }
    }
    __syncthreads();
  }
  #pragma unroll
  for (int r = 0; r < 4; ++r){
    int gr = row0 + ty*4 + r;
    if (gr >= M) continue;
    if (isB){
      u16* Cb = Cb16 + (long)b*M*HD;
      uint4 pk;
      pk.x = (unsigned)f2b(acc[r][0]) | ((unsigned)f2b(acc[r][1]) << 16);
      pk.y = (unsigned)f2b(acc[r][2]) | ((unsigned)f2b(acc[r][3]) << 16);
      pk.z = (unsigned)f2b(acc[r][4]) | ((unsigned)f2b(acc[r][5]) << 16);
      pk.w = (unsigned)f2b(acc[r][6]) | ((unsigned)f2b(acc[r][7]) << 16);
      *(uint4*)&Cb[(long)gr*HD + tx*8] = pk;
    } else {
      float* Cb = Cf32 + (long)b*M*HD;
      *(float4*)&Cb[(long)gr*HD + tx*8]   = make_float4(acc[r][0],acc[r][1],acc[r][2],acc[r][3]);
      *(float4*)&Cb[(long)gr*HD + tx*8+4] = make_float4(acc[r][4],acc[r][5],acc[r][6],acc[r][7]);
    }
  }
}

// ---------- stage 1: per-edge masked softmax + weighted sum of proj1 (bf16 gather) ----------
__global__ __launch_bounds__(128) void k_edge(int swz, const float* __restrict__ raw,
                      const u16* __restrict__ proj1b,
                      const int* __restrict__ colcnt, const u16* __restrict__ colidx,
                      float* __restrict__ hyper, int T, int E){
  int bi = blockIdx.x;
  int b, e;
  if (swz){ int x = bi & 7; b = x >> 1; e = ((bi >> 3) << 1) | (x & 1); }
  else    { b = bi / E; e = bi - b*E; }
  int j = threadIdx.x;
  __shared__ float red[2];
  __shared__ float wls[ECH];
  __shared__ int   tls[ECH];
  int c = colcnt[e]; if (c > CAPE) c = CAPE;
  const u16* ci = colidx + (long)e*CAPE;
  const float* rawb = raw + (long)b*T;
  long orow = ((long)b*E + e)*HD + j;
  if (c <= 0){ hyper[orow] = 0.f; return; }
  float lm = -1e30f;
  for (int i = j; i < c; i += 128) lm = fmaxf(lm, rawb[ci[i]]);
  float m = blockMax128(lm, red);
  float lz = 0.f;
  for (int i = j; i < c; i += 128) lz += __expf(rawb[ci[i]] - m);
  float Z = blockSum128(lz, red);
  float invZ = 1.f / Z;
  const u16* pb = proj1b + (long)b*T*HD + j;
  float accv = 0.f;
  for (int base = 0; base < c; base += ECH){
    int n = c - base; if (n > ECH) n = ECH;
    __syncthreads();
    for (int i = j; i < n; i += 128){
      int t = ci[base + i];
      tls[i] = t;
      wls[i] = __expf(rawb[t] - m);
    }
    __syncthreads();
    float a0=0.f,a1=0.f,a2=0.f,a3=0.f;
    int i = 0;
    for (; i + 4 <= n; i += 4){
      a0 += wls[i]   * b2f(pb[(long)tls[i]  *HD]);
      a1 += wls[i+1] * b2f(pb[(long)tls[i+1]*HD]);
      a2 += wls[i+2] * b2f(pb[(long)tls[i+2]*HD]);
      a3 += wls[i+3] * b2f(pb[(long)tls[i+3]*HD]);
    }
    for (; i < n; ++i) a0 += wls[i] * b2f(pb[(long)tls[i]*HD]);
    accv += (a0+a1)+(a2+a3);
  }
  hyper[orow] = accv * invZ;
}

// ---------- stage 2: scores qt·hyper(f32), PV vs hw2(f32), residual + LN (+ fused next raw) ----------
__global__ __launch_bounds__(128) void k_node(int swz,
      const int* __restrict__ rowcnt, const u16* __restrict__ rowidx,
      const float* __restrict__ qt, const float* __restrict__ hyper, const float* __restrict__ hw2f,
      const float* __restrict__ lng, const float* __restrict__ lnb,
      const float* __restrict__ vnext, float* __restrict__ rawnext, int writeRaw,
      float* __restrict__ h_aug, float* __restrict__ out,
      int T, int E, int N, int writeOut, float scale){
  int bi = blockIdx.x;
  int b, t;
  if (swz){ int x = bi & 7; b = x >> 1; t = ((bi >> 3) << 1) | (x & 1); }
  else    { b = bi / T; t = bi - b*T; }
  int j = threadIdx.x;
  __shared__ __align__(16) float qs[HD];
  __shared__ int   mem[MAXM];
  __shared__ float sv[MAXM];
  __shared__ float red[2];
  long rowb = (long)b*T + t;
  qs[j] = qt[rowb*HD + j];
  int c = rowcnt[t]; if (c > MAXM) c = MAXM;
  const u16* ri = rowidx + (long)t*MAXM;
  for (int i = j; i < c; i += 128) mem[i] = ri[i];
  __syncthreads();

  float o = 0.f;
  if (c > 0){
    const float* hyE = hyper + (long)b*E*HD;
    int sub = j & 3, grp = j >> 2;
    const float4* qv = (const float4*)qs;
    // scores: 4 lanes per edge; lane sub reads chunks u*4+sub (contiguous 64B per group-step)
    for (int i0 = 0; i0 < c; i0 += 32){
      int e = i0 + grp;
      float s = 0.f;
      if (e < c){
        const float4* hr = (const float4*)(hyE + (long)mem[e]*HD);
        #pragma unroll
        for (int u = 0; u < 8; ++u){
          float4 hv = hr[u*4 + sub];
          float4 qa = qv[u*4 + sub];
          s += hv.x*qa.x + hv.y*qa.y + hv.z*qa.z + hv.w*qa.w;
        }
      }
      s += __shfl_xor(s, 1);
      s += __shfl_xor(s, 2);
      if (sub == 0 && e < c) sv[e] = s * scale;
    }
    __syncthreads();
    float lm = -1e30f;
    for (int i = j; i < c; i += 128) lm = fmaxf(lm, sv[i]);
    float m = blockMax128(lm, red);
    float lz = 0.f;
    for (int i = j; i < c; i += 128){ float w = __expf(sv[i] - m); sv[i] = w; lz += w; }
    float Z = blockSum128(lz, red);
    float invZ = 1.f / Z;
    const float* hb = hw2f + (long)b*E*HD + j;
    float o0=0.f,o1=0.f,o2=0.f,o3=0.f;
    int i = 0;
    for (; i + 4 <= c; i += 4){
      o0 += sv[i]   * hb[(long)mem[i]  *HD];
      o1 += sv[i+1] * hb[(long)mem[i+1]*HD];
      o2 += sv[i+2] * hb[(long)mem[i+2]*HD];
      o3 += sv[i+3] * hb[(long)mem[i+3]*HD];
    }
    for (; i < c; ++i) o0 += sv[i] * hb[(long)mem[i]*HD];
    o = ((o0+o1)+(o2+o3)) * invZ;
  }
  float x = o + h_aug[rowb*HD + j];
  float mean = blockSum128(x, red) * (1.f/HD);
  float d = x - mean;
  float var = blockSum128(d*d, red) * (1.f/HD);
  float y = d * rsqrtf(var + 1e-5f) * lng[j] + lnb[j];
  if (writeOut){
    if (t < N) out[((long)b*N + t)*HD + j] = y;
  } else {
    h_aug[rowb*HD + j] = y;
  }
  if (writeRaw){
    float s = blockSum128(y * vnext[j], red);
    if (j == 0) rawnext[rowb] = s * scale;
  }
}

extern "C" void kernel_launch(void* const* d_in, const int* in_sizes, int n_in,
                              void* d_out, int out_size, void* d_ws, size_t ws_size,
                              hipStream_t stream) {
  const float* node_emb = (const float*)d_in[0];
  const float* Hinc     = (const float*)d_in[1];
  const int*   memb     = (const int*)d_in[2];
  const float* W1       = (const float*)d_in[3];
  const float* W1h      = (const float*)d_in[4];
  const float* ctx1     = (const float*)d_in[5];
  const float* W2       = (const float*)d_in[6];
  const float* W2h      = (const float*)d_in[7];
  const float* W3       = (const float*)d_in[8];
  const float* lng      = (const float*)d_in[9];
  const float* lnb      = (const float*)d_in[10];
  const float* rinit    = (const float*)d_in[11];
  float* out = (float*)d_out;

  const int N  = in_sizes[2];
  const int Hd = in_sizes[3] / in_sizes[5];
  const int L  = in_sizes[5] / Hd;
  const int R  = in_sizes[11] / Hd;
  const int B  = in_sizes[0] / (N * Hd);
  const int T  = N + R;
  const int E  = in_sizes[1] / T;
  const float scale = 1.0f / sqrtf((float)Hd);

  char* p = (char*)d_ws;
  auto carve = [&](size_t bytes){ char* r = p; p += (bytes + 255) & ~(size_t)255; return (void*)r; };
  float* h_aug  = (float*)carve((size_t)B*T*Hd*4);
  u16*   proj1b = (u16*)  carve((size_t)B*T*Hd*2);        // hw2f (B*E*Hd*4) aliases this
  float* qt     = (float*)carve((size_t)B*T*Hd*4);        // partials alias this
  float* hyper  = (float*)carve((size_t)B*E*Hd*4);
  float* MqT    = (float*)carve((size_t)L*Hd*Hd*4);
  float* rawb   = (float*)carve((size_t)B*T*4);
  float* vbuf   = (float*)carve((size_t)L*Hd*4);
  int* counts   = (int*)carve((size_t)R*4);
  int* col_cnt  = (int*)carve((size_t)E*4);
  int* row_cnt  = (int*)carve((size_t)T*4);
  u16* row_idx  = (u16*)carve((size_t)T*MAXM*2);
  u16* col_idx  = (u16*)carve((size_t)E*CAPE*2);

  float* hw2f = (float*)proj1b;       // alias: proj1b dead after k_edge each layer
  float* partials = qt;               // alias: qt dead until first k_gemm2b

  hipMemsetAsync(counts, 0, (size_t)R*4, stream);
  hipMemsetAsync(col_cnt, 0, (size_t)E*4, stream);

  k_count<<<32, 256, 0, stream>>>(memb, N, counts);

  int redN;
  if (R <= MAXR){
    k_regsum_fast<<<dim3(NB_RS, B), 128, 0, stream>>>(node_emb, memb, N, R, partials);
    redN = NB_RS;
  } else {
    hipMemsetAsync(partials, 0, (size_t)B*R*Hd*4, stream);
    k_regsum_lds<<<dim3(16, B), Hd, (size_t)R*Hd*4, stream>>>(node_emb, memb, N, R, partials, NB_RS);
    redN = 1;
  }
  int tot = B*R*Hd;
  k_regfin<<<(tot+255)/256, 256, 0, stream>>>(partials, NB_RS, redN, counts, rinit, h_aug, N, R, T, B);

  // index builds (once per launch)
  long TE = (long)T*E;
  k_rowbuild<<<T, 128, 0, stream>>>(Hinc, E, row_idx, row_cnt);
  k_colbuild<<<2048, 256, 0, stream>>>(Hinc, TE, E, col_cnt, col_idx);

  k_ctxv<<<L, Hd, 0, stream>>>(ctx1, W1h, vbuf);
  k_mm128<<<dim3(Hd, L), Hd, 0, stream>>>(W2h, W3, MqT);
  // fused copy + first raw (after regfin so region rows exist)
  k_copyraw<<<dim3(T, B), 128, 0, stream>>>(node_emb, vbuf, h_aug, rawb, N, T, scale);

  int gT = (T + 63)/64, gE = (E + 63)/64;
  int swzE = (B == 4 && (E & 1) == 0) ? 1 : 0;
  int swzN = (B == 4 && (T & 1) == 0) ? 1 : 0;
  for (int l = 0; l < L; ++l){
    size_t wo = (size_t)l*Hd*Hd;
    // proj1 (bf16) = h@W1^T ; qt (f32) = h@MqT^T
    k_gemm2b<<<dim3(gT, B, 2), 256, 0, stream>>>(h_aug, W1 + wo, MqT + wo, proj1b, qt, T, 0);
    k_edge<<<B*E, 128, 0, stream>>>(swzE, rawb, proj1b, col_cnt, col_idx, hyper, T, E);
    // hw2 (f32) = hyper@W2^T   (zbase=1 -> f32 path)
    k_gemm2b<<<dim3(gE, B, 1), 256, 0, stream>>>(hyper, nullptr, W2 + wo, nullptr, hw2f, E, 1);
    int writeRaw = (l < L-1) ? 1 : 0;
    const float* vnext = vbuf + (size_t)((l+1 < L) ? (l+1) : l)*Hd;
    k_node<<<B*T, 128, 0, stream>>>(swzN, row_cnt, row_idx, qt, hyper, hw2f,
                                    lng + wo/Hd, lnb + wo/Hd,
                                    vnext, rawb, writeRaw,
                                    h_aug, out, T, E, N, (l == L-1) ? 1 : 0, scale);
  }
}

// Round 6
// 613.334 us; speedup vs baseline: 1.6190x; 1.2352x over previous
//
#include <hip/hip_runtime.h>

#define HD 128
#define MAXM 256
#define CAPE 768
#define MAXR 16
#define NB_RS 128

typedef unsigned short u16;
typedef __attribute__((ext_vector_type(8))) short bf16x8;
typedef __attribute__((ext_vector_type(4))) float f32x4;

__device__ inline float b2f(unsigned u){ return __uint_as_float(u << 16); }
__device__ inline u16 f2b(float x){
  unsigned u = __float_as_uint(x);
  return (u16)((u + 0x7fffu + ((u >> 16) & 1u)) >> 16);
}

// ---------- reduction helpers (block = 128 threads = 2 waves) ----------
__device__ inline float waveSum(float v){ for(int o=32;o;o>>=1) v += __shfl_down(v,o); return v; }
__device__ inline float waveMax(float v){ for(int o=32;o;o>>=1) v = fmaxf(v,__shfl_down(v,o)); return v; }

__device__ inline float blockSum128(float v, float* red){
  int j = threadIdx.x;
  float s = waveSum(v);
  __syncthreads();
  if ((j & 63) == 0) red[j >> 6] = s;
  __syncthreads();
  return red[0] + red[1];
}
__device__ inline float blockMax128(float v, float* red){
  int j = threadIdx.x;
  float s = waveMax(v);
  __syncthreads();
  if ((j & 63) == 0) red[j >> 6] = s;
  __syncthreads();
  return fmaxf(red[0], red[1]);
}

// ---------- region aggregation ----------
__global__ void k_count(const int* __restrict__ memb, int N, int* __restrict__ counts){
  __shared__ int h[64];
  int tid = threadIdx.x;
  if (tid < 64) h[tid] = 0;
  __syncthreads();
  for (int t = blockIdx.x*blockDim.x + tid; t < N; t += gridDim.x*blockDim.x)
    atomicAdd(&h[memb[t]], 1);
  __syncthreads();
  if (tid < 64){ int v = h[tid]; if (v) atomicAdd(&counts[tid], v); }
}

__global__ __launch_bounds__(128) void k_regsum_fast(const float* __restrict__ node,
                        const int* __restrict__ memb, int N, int R,
                        float* __restrict__ partials){
  int b = blockIdx.y, j = threadIdx.x, blk = blockIdx.x;
  int nb = gridDim.x;
  int per = (N + nb - 1) / nb;
  int t0 = blk * per;
  int t1 = t0 + per; if (t1 > N) t1 = N;
  float acc[MAXR];
  #pragma unroll
  for (int i = 0; i < MAXR; ++i) acc[i] = 0.f;
  const float* base = node + (long)b*N*HD + j;
  for (int t = t0; t < t1; ++t){
    float v = base[(long)t*HD];
    int r = memb[t];
    #pragma unroll
    for (int i = 0; i < MAXR; ++i) acc[i] += (i == r) ? v : 0.f;
  }
  float* dst = partials + ((long)(b*nb + blk)*R)*HD + j;
  #pragma unroll
  for (int i = 0; i < MAXR; ++i)
    if (i < R) dst[(long)i*HD] = acc[i];
}

__global__ void k_regsum_lds(const float* __restrict__ node, const int* __restrict__ memb,
                             int N, int R, float* __restrict__ partials, int nb){
  extern __shared__ float acc[];
  int b = blockIdx.y, j = threadIdx.x;
  for (int r = 0; r < R; ++r) acc[r*HD + j] = 0.f;
  int per = (N + gridDim.x - 1) / gridDim.x;
  int t0 = blockIdx.x * per;
  int t1 = t0 + per; if (t1 > N) t1 = N;
  for (int t = t0; t < t1; ++t){
    int r = memb[t];
    acc[r*HD + j] += node[((long)b*N + t)*HD + j];
  }
  for (int r = 0; r < R; ++r)
    atomicAdd(&partials[((long)(b*nb)*R + r)*HD + j], acc[r*HD + j]);
}

__global__ void k_regfin(const float* __restrict__ partials, int nb, int redN,
                         const int* __restrict__ counts,
                         const float* __restrict__ rinit, float* __restrict__ h_aug,
                         int N, int R, int T, int B){
  int i = blockIdx.x*blockDim.x + threadIdx.x;
  if (i >= B*R*HD) return;
  int j = i % HD; int r = (i/HD) % R; int b = i/(HD*R);
  float s = 0.f;
  for (int blk = 0; blk < redN; ++blk)
    s += partials[((long)(b*nb + blk)*R + r)*HD + j];
  int c = counts[r];
  float v = (c > 0) ? s / (float)c : 0.f;
  v += rinit[r*HD + j];
  h_aug[((long)b*T + N + r)*HD + j] = v;
}

// copy node rows into h_aug AND compute raw = (h·v)*scale (fused)
__global__ __launch_bounds__(128) void k_copyraw(const float* __restrict__ node,
                      const float* __restrict__ v, float* __restrict__ h_aug,
                      float* __restrict__ raw, int N, int T, float scale){
  int t = blockIdx.x, b = blockIdx.y, j = threadIdx.x;
  __shared__ float red[2];
  long rowb = (long)b*T + t;
  float x;
  if (t < N){ x = node[((long)b*N + t)*HD + j]; h_aug[rowb*HD + j] = x; }
  else      { x = h_aug[rowb*HD + j]; }
  float s = blockSum128(x * v[j], red);
  if (j == 0) raw[rowb] = s * scale;
}

// ---------- padded index builders (H_inc static: build once per launch) ----------
__global__ __launch_bounds__(128) void k_rowbuild(const float* __restrict__ Hinc, int E,
                          u16* __restrict__ rowidx, int* __restrict__ rowcnt){
  int t = blockIdx.x, j = threadIdx.x;
  int lane = j & 63, wid = j >> 6;
  __shared__ int wsum[2];
  const float* hrow = Hinc + (long)t*E;
  int c = 0;
  for (int base = 0; base < E; base += 128){
    bool f = (base + j < E) && (hrow[base + j] != 0.f);
    unsigned long long mk = __ballot(f);
    if (lane == 0) wsum[wid] = __popcll(mk);
    __syncthreads();
    int w0 = wsum[0], w1 = wsum[1];
    if (f){
      int pos = c + (wid ? w0 : 0) + (int)__popcll(mk & ((1ull << lane) - 1ull));
      if (pos < MAXM) rowidx[(long)t*MAXM + pos] = (u16)(base + j);
    }
    c += w0 + w1;
    __syncthreads();
  }
  if (j == 0) rowcnt[t] = (c < MAXM) ? c : MAXM;
}

__global__ void k_colbuild(const float* __restrict__ Hinc, long TE, int E,
                           int* __restrict__ colcnt, u16* __restrict__ colidx){
  for (long i = blockIdx.x*(long)blockDim.x + threadIdx.x; i < TE; i += (long)gridDim.x*blockDim.x)
    if (Hinc[i] != 0.f){
      int e = (int)(i % E);
      int slot = atomicAdd(&colcnt[e], 1);
      if (slot < CAPE) colidx[(long)e*CAPE + slot] = (u16)(i / E);
    }
}

// ---------- small precomputes ----------
__global__ void k_ctxv(const float* __restrict__ ctx1, const float* __restrict__ W1h,
                       float* __restrict__ v){
  int l = blockIdx.x, k = threadIdx.x;
  float a = 0.f;
  for (int j = 0; j < HD; ++j) a += ctx1[l*HD + j] * W1h[((long)l*HD + j)*HD + k];
  v[l*HD + k] = a;
}

// MqT[l][n][k] = sum_j W2h[l][j][n] * W3[l][j][k]
__global__ void k_mm128(const float* __restrict__ W2h, const float* __restrict__ W3,
                        float* __restrict__ MqT){
  int n = blockIdx.x, l = blockIdx.y, k = threadIdx.x;
  const float* A = W2h + (long)l*HD*HD;
  const float* Bm = W3 + (long)l*HD*HD;
  float s = 0.f;
  for (int j = 0; j < HD; ++j) s += A[(long)j*HD + n] * Bm[(long)j*HD + k];
  MqT[((long)l*HD + n)*HD + k] = s;
}

// ---------- MFMA bf16 GEMM: C = A @ W^T ----------
// A: (M,128) f32 row-major (batch-merged rows). W: (128,128) f32 row-major.
// z = blockIdx.y + zbase: 0 -> Wa, bf16 out (Cb16); 1 -> Wb, f32 out (Cf32).
// 256 threads = 4 waves; tile 64 rows x 128 cols; stage-converts f32->bf16 into LDS.
#define LWS 136   // u16 row stride (128 + 8 pad): 16B-aligned rows, ~2-way banks
__global__ __launch_bounds__(256) void k_gemmM(const float* __restrict__ A,
                       const float* __restrict__ Wa, const float* __restrict__ Wb,
                       u16* __restrict__ Cb16, float* __restrict__ Cf32, int M, int zbase){
  int isB = ((blockIdx.y + zbase) == 0) ? 1 : 0;
  const float* W = isB ? Wa : Wb;
  __shared__ __align__(16) u16 Ws[128][LWS];
  __shared__ __align__(16) u16 As[64][LWS];
  int tid = threadIdx.x;
  int row0 = blockIdx.x * 64;
  // stage W (128x128) and A-tile (64x128), converting to bf16
  for (int i = tid; i < 128*128; i += 256){
    int r = i >> 7, c = i & 127;
    Ws[r][c] = f2b(W[(long)r*HD + c]);
  }
  for (int i = tid; i < 64*128; i += 256){
    int r = i >> 7, c = i & 127;
    int gr = row0 + r;
    As[r][c] = (gr < M) ? f2b(A[(long)gr*HD + c]) : (u16)0;
  }
  __syncthreads();

  int wave = tid >> 6, lane = tid & 63;
  int wr0 = wave * 16;
  int frow = lane & 15;
  int koff = (lane >> 4) * 8;
  f32x4 acc[8];
  #pragma unroll
  for (int f = 0; f < 8; ++f) acc[f] = (f32x4){0.f,0.f,0.f,0.f};

  #pragma unroll
  for (int ks = 0; ks < 4; ++ks){
    int kc = ks*32 + koff;
    bf16x8 av = *(const bf16x8*)&As[wr0 + frow][kc];
    #pragma unroll
    for (int f = 0; f < 8; ++f){
      bf16x8 bv = *(const bf16x8*)&Ws[f*16 + frow][kc];
      acc[f] = __builtin_amdgcn_mfma_f32_16x16x32_bf16(av, bv, acc[f], 0, 0, 0);
    }
  }

  int orow = wr0 + (lane >> 4) * 4;
  #pragma unroll
  for (int f = 0; f < 8; ++f){
    int col = f*16 + frow;
    #pragma unroll
    for (int i = 0; i < 4; ++i){
      int gr = row0 + orow + i;
      if (gr < M){
        if (isB) Cb16[(long)gr*HD + col] = f2b(acc[f][i]);
        else     Cf32[(long)gr*HD + col] = acc[f][i];
      }
    }
  }
}

// ---------- stage 1: per-edge masked softmax + weighted sum of proj1 (bf16 gather) ----------
__global__ __launch_bounds__(128) void k_edge(int swz, const float* __restrict__ raw,
                      const u16* __restrict__ proj1b,
                      const int* __restrict__ colcnt, const u16* __restrict__ colidx,
                      float* __restrict__ hyper, int T, int E){
  int bi = blockIdx.x;
  int b, e;
  if (swz){ int x = bi & 7; b = x >> 1; e = ((bi >> 3) << 1) | (x & 1); }
  else    { b = bi / E; e = bi - b*E; }
  int j = threadIdx.x;
  __shared__ float red[2];
  __shared__ float wls[CAPE];
  __shared__ int   tls[CAPE];
  int c = colcnt[e]; if (c > CAPE) c = CAPE;
  const u16* ci = colidx + (long)e*CAPE;
  const float* rawb = raw + (long)b*T;
  long orow = ((long)b*E + e)*HD + j;
  if (c <= 0){ hyper[orow] = 0.f; return; }
  // single gather pass: stage indices + raw values in LDS
  float lm = -1e30f;
  for (int i = j; i < c; i += 128){
    int t = ci[i];
    float v = rawb[t];
    tls[i] = t;
    wls[i] = v;
    lm = fmaxf(lm, v);
  }
  float m = blockMax128(lm, red);
  float lz = 0.f;
  for (int i = j; i < c; i += 128){
    float w = __expf(wls[i] - m);
    wls[i] = w;
    lz += w;
  }
  float Z = blockSum128(lz, red);   // also publishes wls
  float invZ = 1.f / Z;
  const u16* pb = proj1b + (long)b*T*HD + j;
  float a0=0.f,a1=0.f,a2=0.f,a3=0.f;
  int i = 0;
  for (; i + 4 <= c; i += 4){
    a0 += wls[i]   * b2f(pb[(long)tls[i]  *HD]);
    a1 += wls[i+1] * b2f(pb[(long)tls[i+1]*HD]);
    a2 += wls[i+2] * b2f(pb[(long)tls[i+2]*HD]);
    a3 += wls[i+3] * b2f(pb[(long)tls[i+3]*HD]);
  }
  for (; i < c; ++i) a0 += wls[i] * b2f(pb[(long)tls[i]*HD]);
  hyper[orow] = ((a0+a1)+(a2+a3)) * invZ;
}

// ---------- stage 2: scores qt·hyper(f32), PV vs hw2(f32), residual + LN (+ fused next raw) ----------
__global__ __launch_bounds__(128) void k_node(int swz,
      const int* __restrict__ rowcnt, const u16* __restrict__ rowidx,
      const float* __restrict__ qt, const float* __restrict__ hyper, const float* __restrict__ hw2f,
      const float* __restrict__ lng, const float* __restrict__ lnb,
      const float* __restrict__ vnext, float* __restrict__ rawnext, int writeRaw,
      float* __restrict__ h_aug, float* __restrict__ out,
      int T, int E, int N, int writeOut, float scale){
  int bi = blockIdx.x;
  int b, t;
  if (swz){ int x = bi & 7; b = x >> 1; t = ((bi >> 3) << 1) | (x & 1); }
  else    { b = bi / T; t = bi - b*T; }
  int j = threadIdx.x;
  __shared__ __align__(16) float qs[HD];
  __shared__ int   mem[MAXM];
  __shared__ float sv[MAXM];
  __shared__ float red[2];
  long rowb = (long)b*T + t;
  qs[j] = qt[rowb*HD + j];
  int c = rowcnt[t]; if (c > MAXM) c = MAXM;
  const u16* ri = rowidx + (long)t*MAXM;
  for (int i = j; i < c; i += 128) mem[i] = ri[i];
  __syncthreads();

  float o = 0.f;
  if (c > 0){
    const float* hyE = hyper + (long)b*E*HD;
    int sub = j & 3, grp = j >> 2;
    const float4* qv = (const float4*)qs;
    for (int i0 = 0; i0 < c; i0 += 32){
      int e = i0 + grp;
      float s = 0.f;
      if (e < c){
        const float4* hr = (const float4*)(hyE + (long)mem[e]*HD);
        #pragma unroll
        for (int u = 0; u < 8; ++u){
          float4 hv = hr[u*4 + sub];
          float4 qa = qv[u*4 + sub];
          s += hv.x*qa.x + hv.y*qa.y + hv.z*qa.z + hv.w*qa.w;
        }
      }
      s += __shfl_xor(s, 1);
      s += __shfl_xor(s, 2);
      if (sub == 0 && e < c) sv[e] = s * scale;
    }
    __syncthreads();
    float lm = -1e30f;
    for (int i = j; i < c; i += 128) lm = fmaxf(lm, sv[i]);
    float m = blockMax128(lm, red);
    float lz = 0.f;
    for (int i = j; i < c; i += 128){ float w = __expf(sv[i] - m); sv[i] = w; lz += w; }
    float Z = blockSum128(lz, red);
    float invZ = 1.f / Z;
    const float* hb = hw2f + (long)b*E*HD + j;
    float o0=0.f,o1=0.f,o2=0.f,o3=0.f;
    int i = 0;
    for (; i + 4 <= c; i += 4){
      o0 += sv[i]   * hb[(long)mem[i]  *HD];
      o1 += sv[i+1] * hb[(long)mem[i+1]*HD];
      o2 += sv[i+2] * hb[(long)mem[i+2]*HD];
      o3 += sv[i+3] * hb[(long)mem[i+3]*HD];
    }
    for (; i < c; ++i) o0 += sv[i] * hb[(long)mem[i]*HD];
    o = ((o0+o1)+(o2+o3)) * invZ;
  }
  float x = o + h_aug[rowb*HD + j];
  float mean = blockSum128(x, red) * (1.f/HD);
  float d = x - mean;
  float var = blockSum128(d*d, red) * (1.f/HD);
  float y = d * rsqrtf(var + 1e-5f) * lng[j] + lnb[j];
  if (writeOut){
    if (t < N) out[((long)b*N + t)*HD + j] = y;
  } else {
    h_aug[rowb*HD + j] = y;
  }
  if (writeRaw){
    float s = blockSum128(y * vnext[j], red);
    if (j == 0) rawnext[rowb] = s * scale;
  }
}

extern "C" void kernel_launch(void* const* d_in, const int* in_sizes, int n_in,
                              void* d_out, int out_size, void* d_ws, size_t ws_size,
                              hipStream_t stream) {
  const float* node_emb = (const float*)d_in[0];
  const float* Hinc     = (const float*)d_in[1];
  const int*   memb     = (const int*)d_in[2];
  const float* W1       = (const float*)d_in[3];
  const float* W1h      = (const float*)d_in[4];
  const float* ctx1     = (const float*)d_in[5];
  const float* W2       = (const float*)d_in[6];
  const float* W2h      = (const float*)d_in[7];
  const float* W3       = (const float*)d_in[8];
  const float* lng      = (const float*)d_in[9];
  const float* lnb      = (const float*)d_in[10];
  const float* rinit    = (const float*)d_in[11];
  float* out = (float*)d_out;

  const int N  = in_sizes[2];
  const int Hd = in_sizes[3] / in_sizes[5];
  const int L  = in_sizes[5] / Hd;
  const int R  = in_sizes[11] / Hd;
  const int B  = in_sizes[0] / (N * Hd);
  const int T  = N + R;
  const int E  = in_sizes[1] / T;
  const float scale = 1.0f / sqrtf((float)Hd);

  char* p = (char*)d_ws;
  auto carve = [&](size_t bytes){ char* r = p; p += (bytes + 255) & ~(size_t)255; return (void*)r; };
  float* h_aug  = (float*)carve((size_t)B*T*Hd*4);
  u16*   proj1b = (u16*)  carve((size_t)B*T*Hd*2);        // hw2f (B*E*Hd*4) aliases this
  float* qt     = (float*)carve((size_t)B*T*Hd*4);        // partials alias this
  float* hyper  = (float*)carve((size_t)B*E*Hd*4);
  float* MqT    = (float*)carve((size_t)L*Hd*Hd*4);
  float* rawb   = (float*)carve((size_t)B*T*4);
  float* vbuf   = (float*)carve((size_t)L*Hd*4);
  int* counts   = (int*)carve((size_t)R*4);
  int* col_cnt  = (int*)carve((size_t)E*4);
  int* row_cnt  = (int*)carve((size_t)T*4);
  u16* row_idx  = (u16*)carve((size_t)T*MAXM*2);
  u16* col_idx  = (u16*)carve((size_t)E*CAPE*2);

  float* hw2f = (float*)proj1b;       // alias: proj1b dead after k_edge each layer
  float* partials = qt;               // alias: qt dead until first k_gemmM

  hipMemsetAsync(counts, 0, (size_t)R*4, stream);
  hipMemsetAsync(col_cnt, 0, (size_t)E*4, stream);

  k_count<<<32, 256, 0, stream>>>(memb, N, counts);

  int redN;
  if (R <= MAXR){
    k_regsum_fast<<<dim3(NB_RS, B), 128, 0, stream>>>(node_emb, memb, N, R, partials);
    redN = NB_RS;
  } else {
    hipMemsetAsync(partials, 0, (size_t)B*R*Hd*4, stream);
    k_regsum_lds<<<dim3(16, B), Hd, (size_t)R*Hd*4, stream>>>(node_emb, memb, N, R, partials, NB_RS);
    redN = 1;
  }
  int tot = B*R*Hd;
  k_regfin<<<(tot+255)/256, 256, 0, stream>>>(partials, NB_RS, redN, counts, rinit, h_aug, N, R, T, B);

  // index builds (once per launch)
  long TE = (long)T*E;
  k_rowbuild<<<T, 128, 0, stream>>>(Hinc, E, row_idx, row_cnt);
  k_colbuild<<<2048, 256, 0, stream>>>(Hinc, TE, E, col_cnt, col_idx);

  k_ctxv<<<L, Hd, 0, stream>>>(ctx1, W1h, vbuf);
  k_mm128<<<dim3(Hd, L), Hd, 0, stream>>>(W2h, W3, MqT);
  k_copyraw<<<dim3(T, B), 128, 0, stream>>>(node_emb, vbuf, h_aug, rawb, N, T, scale);

  int MT = B*T, ME = B*E;
  int gTm = (MT + 63)/64, gEm = (ME + 63)/64;
  int swzE = (B == 4 && (E & 1) == 0) ? 1 : 0;
  int swzN = (B == 4 && (T & 1) == 0) ? 1 : 0;
  for (int l = 0; l < L; ++l){
    size_t wo = (size_t)l*Hd*Hd;
    // proj1 (bf16) = h@W1^T ; qt (f32) = h@MqT^T   [MFMA, batch-merged M]
    k_gemmM<<<dim3(gTm, 2), 256, 0, stream>>>(h_aug, W1 + wo, MqT + wo, proj1b, qt, MT, 0);
    k_edge<<<B*E, 128, 0, stream>>>(swzE, rawb, proj1b, col_cnt, col_idx, hyper, T, E);
    // hw2 (f32) = hyper@W2^T   [MFMA]
    k_gemmM<<<dim3(gEm, 1), 256, 0, stream>>>(hyper, nullptr, W2 + wo, nullptr, hw2f, ME, 1);
    int writeRaw = (l < L-1) ? 1 : 0;
    const float* vnext = vbuf + (size_t)((l+1 < L) ? (l+1) : l)*Hd;
    k_node<<<B*T, 128, 0, stream>>>(swzN, row_cnt, row_idx, qt, hyper, hw2f,
                                    lng + wo/Hd, lnb + wo/Hd,
                                    vnext, rawb, writeRaw,
                                    h_aug, out, T, E, N, (l == L-1) ? 1 : 0, scale);
  }
}

// Round 7
// 514.187 us; speedup vs baseline: 1.9312x; 1.1928x over previous
//
#include <hip/hip_runtime.h>

#define HD 128
#define CAPE 768
#define MAXR 16
#define NB_RS 128
#define KSTR 136   // K/LDS row stride in u16 (16B-aligned, 2-way banks)
#define VSTR 72    // V tile row stride in u16
#define PSTR 72    // P tile row stride in u16

typedef unsigned short u16;
typedef unsigned long long u64;
typedef __attribute__((ext_vector_type(8))) short bf16x8;
typedef __attribute__((ext_vector_type(4))) float f32x4;

__device__ inline float b2f(unsigned u){ return __uint_as_float(u << 16); }
__device__ inline u16 f2b(float x){
  unsigned u = __float_as_uint(x);
  return (u16)((u + 0x7fffu + ((u >> 16) & 1u)) >> 16);
}

// ---------- reduction helpers (block = 128 threads = 2 waves) ----------
__device__ inline float waveSum(float v){ for(int o=32;o;o>>=1) v += __shfl_down(v,o); return v; }
__device__ inline float waveMax(float v){ for(int o=32;o;o>>=1) v = fmaxf(v,__shfl_down(v,o)); return v; }

__device__ inline float blockSum128(float v, float* red){
  int j = threadIdx.x;
  float s = waveSum(v);
  __syncthreads();
  if ((j & 63) == 0) red[j >> 6] = s;
  __syncthreads();
  return red[0] + red[1];
}
__device__ inline float blockMax128(float v, float* red){
  int j = threadIdx.x;
  float s = waveMax(v);
  __syncthreads();
  if ((j & 63) == 0) red[j >> 6] = s;
  __syncthreads();
  return fmaxf(red[0], red[1]);
}

// ---------- region aggregation ----------
__global__ void k_count(const int* __restrict__ memb, int N, int* __restrict__ counts){
  __shared__ int h[64];
  int tid = threadIdx.x;
  if (tid < 64) h[tid] = 0;
  __syncthreads();
  for (int t = blockIdx.x*blockDim.x + tid; t < N; t += gridDim.x*blockDim.x)
    atomicAdd(&h[memb[t]], 1);
  __syncthreads();
  if (tid < 64){ int v = h[tid]; if (v) atomicAdd(&counts[tid], v); }
}

__global__ __launch_bounds__(128) void k_regsum_fast(const float* __restrict__ node,
                        const int* __restrict__ memb, int N, int R,
                        float* __restrict__ partials){
  int b = blockIdx.y, j = threadIdx.x, blk = blockIdx.x;
  int nb = gridDim.x;
  int per = (N + nb - 1) / nb;
  int t0 = blk * per;
  int t1 = t0 + per; if (t1 > N) t1 = N;
  float acc[MAXR];
  #pragma unroll
  for (int i = 0; i < MAXR; ++i) acc[i] = 0.f;
  const float* base = node + (long)b*N*HD + j;
  for (int t = t0; t < t1; ++t){
    float v = base[(long)t*HD];
    int r = memb[t];
    #pragma unroll
    for (int i = 0; i < MAXR; ++i) acc[i] += (i == r) ? v : 0.f;
  }
  float* dst = partials + ((long)(b*nb + blk)*R)*HD + j;
  #pragma unroll
  for (int i = 0; i < MAXR; ++i)
    if (i < R) dst[(long)i*HD] = acc[i];
}

__global__ void k_regsum_lds(const float* __restrict__ node, const int* __restrict__ memb,
                             int N, int R, float* __restrict__ partials, int nb){
  extern __shared__ float acc[];
  int b = blockIdx.y, j = threadIdx.x;
  for (int r = 0; r < R; ++r) acc[r*HD + j] = 0.f;
  int per = (N + gridDim.x - 1) / gridDim.x;
  int t0 = blockIdx.x * per;
  int t1 = t0 + per; if (t1 > N) t1 = N;
  for (int t = t0; t < t1; ++t){
    int r = memb[t];
    acc[r*HD + j] += node[((long)b*N + t)*HD + j];
  }
  for (int r = 0; r < R; ++r)
    atomicAdd(&partials[((long)(b*nb)*R + r)*HD + j], acc[r*HD + j]);
}

__global__ void k_regfin(const float* __restrict__ partials, int nb, int redN,
                         const int* __restrict__ counts,
                         const float* __restrict__ rinit, float* __restrict__ h_aug,
                         int N, int R, int T, int B){
  int i = blockIdx.x*blockDim.x + threadIdx.x;
  if (i >= B*R*HD) return;
  int j = i % HD; int r = (i/HD) % R; int b = i/(HD*R);
  float s = 0.f;
  for (int blk = 0; blk < redN; ++blk)
    s += partials[((long)(b*nb + blk)*R + r)*HD + j];
  int c = counts[r];
  float v = (c > 0) ? s / (float)c : 0.f;
  v += rinit[r*HD + j];
  h_aug[((long)b*T + N + r)*HD + j] = v;
}

// copy node rows into h_aug AND compute raw = (h·v)*scale (fused)
__global__ __launch_bounds__(128) void k_copyraw(const float* __restrict__ node,
                      const float* __restrict__ v, float* __restrict__ h_aug,
                      float* __restrict__ raw, int N, int T, float scale){
  int t = blockIdx.x, b = blockIdx.y, j = threadIdx.x;
  __shared__ float red[2];
  long rowb = (long)b*T + t;
  float x;
  if (t < N){ x = node[((long)b*N + t)*HD + j]; h_aug[rowb*HD + j] = x; }
  else      { x = h_aug[rowb*HD + j]; }
  float s = blockSum128(x * v[j], red);
  if (j == 0) raw[rowb] = s * scale;
}

// ---------- incidence bitmask: maskw[t][w] bit j <-> H_inc[t][w*64+j] != 0 ----------
__global__ __launch_bounds__(256) void k_maskbuild(const float* __restrict__ Hinc, int E, int MW,
                        u64* __restrict__ maskw){
  int t = blockIdx.x;
  int wv = threadIdx.x >> 6, lane = threadIdx.x & 63;
  const float* hrow = Hinc + (long)t*E;
  for (int w = wv; w < MW; w += 4){
    int e = w*64 + lane;
    bool f = (e < E) && (hrow[e] != 0.f);
    u64 mk = __ballot(f);
    if (lane == 0) maskw[(long)t*MW + w] = mk;
  }
}

// cols: atomic slot fill (set deterministic; order not — summation tolerance ok)
__global__ void k_colbuild(const float* __restrict__ Hinc, long TE, int E,
                           int* __restrict__ colcnt, u16* __restrict__ colidx){
  for (long i = blockIdx.x*(long)blockDim.x + threadIdx.x; i < TE; i += (long)gridDim.x*blockDim.x)
    if (Hinc[i] != 0.f){
      int e = (int)(i % E);
      int slot = atomicAdd(&colcnt[e], 1);
      if (slot < CAPE) colidx[(long)e*CAPE + slot] = (u16)(i / E);
    }
}

// ---------- small precomputes ----------
__global__ void k_ctxv(const float* __restrict__ ctx1, const float* __restrict__ W1h,
                       float* __restrict__ v){
  int l = blockIdx.x, k = threadIdx.x;
  float a = 0.f;
  for (int j = 0; j < HD; ++j) a += ctx1[l*HD + j] * W1h[((long)l*HD + j)*HD + k];
  v[l*HD + k] = a;
}

// MqT[l][n][k] = sum_j W2h[l][j][n] * W3[l][j][k]
__global__ void k_mm128(const float* __restrict__ W2h, const float* __restrict__ W3,
                        float* __restrict__ MqT){
  int n = blockIdx.x, l = blockIdx.y, k = threadIdx.x;
  const float* A = W2h + (long)l*HD*HD;
  const float* Bm = W3 + (long)l*HD*HD;
  float s = 0.f;
  for (int j = 0; j < HD; ++j) s += A[(long)j*HD + n] * Bm[(long)j*HD + k];
  MqT[((long)l*HD + n)*HD + k] = s;
}

// ---------- MFMA bf16 GEMM: C = A @ W^T (A f32 (M,128); z picks W/output form) ----------
__global__ __launch_bounds__(256) void k_gemmM(const float* __restrict__ A,
                       const float* __restrict__ Wa, const float* __restrict__ Wb,
                       u16* __restrict__ Cb16, float* __restrict__ Cf32, int M, int zbase){
  int isB = ((blockIdx.y + zbase) == 0) ? 1 : 0;
  const float* W = isB ? Wa : Wb;
  __shared__ __align__(16) u16 Ws[128][KSTR];
  __shared__ __align__(16) u16 As[64][KSTR];
  int tid = threadIdx.x;
  int row0 = blockIdx.x * 64;
  for (int i = tid; i < 128*128; i += 256){
    int r = i >> 7, c = i & 127;
    Ws[r][c] = f2b(W[(long)r*HD + c]);
  }
  for (int i = tid; i < 64*128; i += 256){
    int r = i >> 7, c = i & 127;
    int gr = row0 + r;
    As[r][c] = (gr < M) ? f2b(A[(long)gr*HD + c]) : (u16)0;
  }
  __syncthreads();

  int wave = tid >> 6, lane = tid & 63;
  int wr0 = wave * 16;
  int frow = lane & 15;
  int koff = (lane >> 4) * 8;
  f32x4 acc[8];
  #pragma unroll
  for (int f = 0; f < 8; ++f) acc[f] = (f32x4){0.f,0.f,0.f,0.f};

  #pragma unroll
  for (int ks = 0; ks < 4; ++ks){
    int kc = ks*32 + koff;
    bf16x8 av = *(const bf16x8*)&As[wr0 + frow][kc];
    #pragma unroll
    for (int f = 0; f < 8; ++f){
      bf16x8 bv = *(const bf16x8*)&Ws[f*16 + frow][kc];
      acc[f] = __builtin_amdgcn_mfma_f32_16x16x32_bf16(av, bv, acc[f], 0, 0, 0);
    }
  }

  int orow = wr0 + (lane >> 4) * 4;
  #pragma unroll
  for (int f = 0; f < 8; ++f){
    int col = f*16 + frow;
    #pragma unroll
    for (int i = 0; i < 4; ++i){
      int gr = row0 + orow + i;
      if (gr < M){
        if (isB) Cb16[(long)gr*HD + col] = f2b(acc[f][i]);
        else     Cf32[(long)gr*HD + col] = acc[f][i];
      }
    }
  }
}

// ---------- hw2t[b][h][e] = sum_d W2[h][d] * hyper[b][e][d]  (bf16 out, e-major) ----------
__global__ __launch_bounds__(256) void k_gemmW2T(const float* __restrict__ W2,
                       const u16* __restrict__ hyb, u16* __restrict__ hw2t, int E){
  int b = blockIdx.y;
  int e0 = blockIdx.x * 64;
  __shared__ __align__(16) u16 As[128][KSTR];
  __shared__ __align__(16) u16 Bs[64][KSTR];
  int tid = threadIdx.x;
  for (int i = tid; i < 128*128; i += 256){
    int r = i >> 7, c = i & 127;
    As[r][c] = f2b(W2[(long)r*HD + c]);
  }
  {
    int er = tid >> 2, q = (tid & 3)*32;
    if (e0 + er < E){
      const uint4* src = (const uint4*)(hyb + ((long)b*E + e0 + er)*HD + q);
      uint4 w0 = src[0], w1 = src[1], w2 = src[2], w3 = src[3];
      *(uint4*)&Bs[er][q]    = w0;
      *(uint4*)&Bs[er][q+8]  = w1;
      *(uint4*)&Bs[er][q+16] = w2;
      *(uint4*)&Bs[er][q+24] = w3;
    } else {
      uint4 z = {0,0,0,0};
      *(uint4*)&Bs[er][q] = z; *(uint4*)&Bs[er][q+8] = z;
      *(uint4*)&Bs[er][q+16] = z; *(uint4*)&Bs[er][q+24] = z;
    }
  }
  __syncthreads();
  int wv = tid >> 6, lane = tid & 63;
  int lc = lane & 15, lg = lane >> 4;
  f32x4 acc[2][4];
  #pragma unroll
  for (int mt=0;mt<2;++mt)
    #pragma unroll
    for (int nf=0;nf<4;++nf) acc[mt][nf] = (f32x4){0.f,0.f,0.f,0.f};
  #pragma unroll
  for (int mt=0;mt<2;++mt){
    int hr = wv*32 + mt*16 + lc;
    #pragma unroll
    for (int ks=0;ks<4;++ks){
      bf16x8 av = *(const bf16x8*)&As[hr][ks*32 + lg*8];
      #pragma unroll
      for (int nf=0;nf<4;++nf){
        bf16x8 bv = *(const bf16x8*)&Bs[nf*16+lc][ks*32 + lg*8];
        acc[mt][nf] = __builtin_amdgcn_mfma_f32_16x16x32_bf16(av, bv, acc[mt][nf], 0,0,0);
      }
    }
  }
  #pragma unroll
  for (int mt=0;mt<2;++mt){
    #pragma unroll
    for (int nf=0;nf<4;++nf){
      #pragma unroll
      for (int i=0;i<4;++i){
        int h = wv*32 + mt*16 + lg*4 + i;
        int e = e0 + nf*16 + lc;
        if (e < E) hw2t[((long)b*HD + h)*E + e] = f2b(acc[mt][nf][i]);
      }
    }
  }
}

// ---------- stage 1: per-edge masked softmax + weighted sum of proj1 (bf16 out) ----------
__global__ __launch_bounds__(128) void k_edge(int swz, const float* __restrict__ raw,
                      const u16* __restrict__ proj1b,
                      const int* __restrict__ colcnt, const u16* __restrict__ colidx,
                      u16* __restrict__ hyb, int T, int E){
  int bi = blockIdx.x;
  int b, e;
  if (swz){ int x = bi & 7; b = x >> 1; e = ((bi >> 3) << 1) | (x & 1); }
  else    { b = bi / E; e = bi - b*E; }
  int j = threadIdx.x;
  __shared__ float red[2];
  __shared__ float wls[CAPE];
  __shared__ int   tls[CAPE];
  int c = colcnt[e]; if (c > CAPE) c = CAPE;
  const u16* ci = colidx + (long)e*CAPE;
  const float* rawb = raw + (long)b*T;
  long orow = ((long)b*E + e)*HD + j;
  if (c <= 0){ hyb[orow] = 0; return; }
  float lm = -1e30f;
  for (int i = j; i < c; i += 128){
    int t = ci[i];
    float v = rawb[t];
    tls[i] = t;
    wls[i] = v;
    lm = fmaxf(lm, v);
  }
  float m = blockMax128(lm, red);
  float lz = 0.f;
  for (int i = j; i < c; i += 128){
    float w = __expf(wls[i] - m);
    wls[i] = w;
    lz += w;
  }
  float Z = blockSum128(lz, red);
  float invZ = 1.f / Z;
  const u16* pb = proj1b + (long)b*T*HD + j;
  float a0=0.f,a1=0.f,a2=0.f,a3=0.f;
  int i = 0;
  for (; i + 4 <= c; i += 4){
    a0 += wls[i]   * b2f(pb[(long)tls[i]  *HD]);
    a1 += wls[i+1] * b2f(pb[(long)tls[i+1]*HD]);
    a2 += wls[i+2] * b2f(pb[(long)tls[i+2]*HD]);
    a3 += wls[i+3] * b2f(pb[(long)tls[i+3]*HD]);
  }
  for (; i < c; ++i) a0 += wls[i] * b2f(pb[(long)tls[i]*HD]);
  hyb[orow] = f2b(((a0+a1)+(a2+a3)) * invZ);
}

// ---------- stage 2: flash-dense masked attention + residual + LN (+ fused next raw) ----------
// S = qt @ hyper^T * scale (masked); P = softmax_row(S); O = P @ hw2; y = LN(O + h_aug)
__global__ __launch_bounds__(256) void k_flash(
      const float* __restrict__ qt, const u16* __restrict__ hyb, const u16* __restrict__ hw2t,
      const u64* __restrict__ maskw,
      const float* __restrict__ lng, const float* __restrict__ lnb,
      const float* __restrict__ vnext, float* __restrict__ rawnext, int writeRaw,
      float* __restrict__ h_aug, float* __restrict__ out,
      int T, int E, int N, int writeOut, float scale){
  int b = blockIdx.y;
  int t0 = blockIdx.x * 64;
  int tid = threadIdx.x;
  int wv = tid >> 6, lane = tid & 63;
  int lc = lane & 15, lg = lane >> 4;

  __shared__ __align__(16) u16 Ks[64][KSTR];
  __shared__ __align__(16) u16 Vs[128][VSTR];
  __shared__ __align__(16) u16 Ps[4][16][PSTR];

  // Q fragments in registers (bf16)
  int qrow = t0 + wv*16 + lc;
  bf16x8 qf[4];
  if (qrow < T){
    const float* qr = qt + ((long)b*T + qrow)*HD + lg*8;
    #pragma unroll
    for (int ks = 0; ks < 4; ++ks){
      const float4* q4 = (const float4*)(qr + ks*32);
      float4 a = q4[0], cc = q4[1];
      bf16x8 v;
      v[0]=(short)f2b(a.x);  v[1]=(short)f2b(a.y);  v[2]=(short)f2b(a.z);  v[3]=(short)f2b(a.w);
      v[4]=(short)f2b(cc.x); v[5]=(short)f2b(cc.y); v[6]=(short)f2b(cc.z); v[7]=(short)f2b(cc.w);
      qf[ks] = v;
    }
  } else {
    #pragma unroll
    for (int ks = 0; ks < 4; ++ks) qf[ks] = (bf16x8){0,0,0,0,0,0,0,0};
  }

  int mrow[4];
  #pragma unroll
  for (int i=0;i<4;++i) mrow[i] = t0 + wv*16 + lg*4 + i;

  float m_i[4], l_i[4];
  #pragma unroll
  for (int i=0;i<4;++i){ m_i[i] = -1e30f; l_i[i] = 0.f; }
  f32x4 Oa[8];
  #pragma unroll
  for (int f=0;f<8;++f) Oa[f] = (f32x4){0.f,0.f,0.f,0.f};

  const u16* hyB = hyb + (long)b*E*HD;
  const u16* vtB = hw2t + (long)b*HD*E;
  int MW = (E + 63) >> 6;
  int ntile = (E + 63) / 64;

  for (int et = 0; et < ntile; ++et){
    int e0 = et*64;
    { // stage K tile: hyper rows e0..e0+63 (bf16), 32 u16 per thread
      int er = tid >> 2, q = (tid & 3)*32;
      if (e0 + er < E){
        const uint4* src = (const uint4*)(hyB + (long)(e0+er)*HD + q);
        uint4 w0 = src[0], w1 = src[1], w2 = src[2], w3 = src[3];
        *(uint4*)&Ks[er][q]    = w0;
        *(uint4*)&Ks[er][q+8]  = w1;
        *(uint4*)&Ks[er][q+16] = w2;
        *(uint4*)&Ks[er][q+24] = w3;
      } else {
        uint4 z = {0,0,0,0};
        *(uint4*)&Ks[er][q] = z; *(uint4*)&Ks[er][q+8] = z;
        *(uint4*)&Ks[er][q+16] = z; *(uint4*)&Ks[er][q+24] = z;
      }
    }
    { // stage V tile: hw2t[h][e0..e0+63] -> Vs[h][0..63], 32 u16 per thread
      int h = tid >> 1, off = (tid & 1)*32;
      if (e0 + off + 31 < E){
        const uint4* src = (const uint4*)(vtB + (long)h*E + e0 + off);
        uint4 w0 = src[0], w1 = src[1], w2 = src[2], w3 = src[3];
        *(uint4*)&Vs[h][off]    = w0;
        *(uint4*)&Vs[h][off+8]  = w1;
        *(uint4*)&Vs[h][off+16] = w2;
        *(uint4*)&Vs[h][off+24] = w3;
      } else {
        for (int k = 0; k < 32; ++k){
          int e = e0 + off + k;
          Vs[h][off+k] = (e < E) ? vtB[(long)h*E + e] : (u16)0;
        }
      }
    }
    __syncthreads();

    // QK^T: S-tile 16x64 per wave
    f32x4 accS[4];
    #pragma unroll
    for (int ne=0;ne<4;++ne) accS[ne] = (f32x4){0.f,0.f,0.f,0.f};
    #pragma unroll
    for (int ks=0;ks<4;++ks){
      #pragma unroll
      for (int ne=0;ne<4;++ne){
        bf16x8 kv = *(const bf16x8*)&Ks[ne*16+lc][ks*32 + lg*8];
        accS[ne] = __builtin_amdgcn_mfma_f32_16x16x32_bf16(qf[ks], kv, accS[ne], 0,0,0);
      }
    }

    // mask words for this tile (one u64 covers e0..e0+63)
    u64 mw[4];
    #pragma unroll
    for (int i=0;i<4;++i)
      mw[i] = (mrow[i] < T) ? maskw[(long)mrow[i]*MW + et] : 0ull;

    // online softmax (per row i; 16-lane xor reduces)
    float p[4][4];
    #pragma unroll
    for (int i=0;i<4;++i){
      float sv[4];
      float mx = -1e30f;
      #pragma unroll
      for (int ne=0;ne<4;++ne){
        int bit = (int)((mw[i] >> (ne*16 + lc)) & 1ull);
        float s = bit ? accS[ne][i]*scale : -1e30f;
        sv[ne] = s;
        mx = fmaxf(mx, s);
      }
      mx = fmaxf(mx, __shfl_xor(mx,1));
      mx = fmaxf(mx, __shfl_xor(mx,2));
      mx = fmaxf(mx, __shfl_xor(mx,4));
      mx = fmaxf(mx, __shfl_xor(mx,8));
      float mn = fmaxf(m_i[i], mx);
      float corr = __expf(m_i[i] - mn);
      m_i[i] = mn;
      float ls = 0.f;
      #pragma unroll
      for (int ne=0;ne<4;++ne){
        float pv = (sv[ne] > -1e29f) ? __expf(sv[ne] - mn) : 0.f;
        p[ne][i] = pv;
        ls += pv;
      }
      ls += __shfl_xor(ls,1);
      ls += __shfl_xor(ls,2);
      ls += __shfl_xor(ls,4);
      ls += __shfl_xor(ls,8);
      l_i[i] = l_i[i]*corr + ls;
      #pragma unroll
      for (int f=0;f<8;++f) Oa[f][i] *= corr;
    }

    // P -> wave-private LDS (bf16), then PV MFMA
    #pragma unroll
    for (int i=0;i<4;++i){
      #pragma unroll
      for (int ne=0;ne<4;++ne)
        Ps[wv][lg*4+i][ne*16+lc] = f2b(p[ne][i]);
    }
    #pragma unroll
    for (int ks2=0;ks2<2;++ks2){
      bf16x8 pa = *(const bf16x8*)&Ps[wv][lc][ks2*32 + lg*8];
      #pragma unroll
      for (int f=0;f<8;++f){
        bf16x8 vb = *(const bf16x8*)&Vs[f*16+lc][ks2*32 + lg*8];
        Oa[f] = __builtin_amdgcn_mfma_f32_16x16x32_bf16(pa, vb, Oa[f], 0,0,0);
      }
    }
    __syncthreads();
  }

  // epilogue: o = Oa/l, + residual, LN, store, fused next-raw
  #pragma unroll
  for (int i=0;i<4;++i){
    int t = mrow[i];
    if (t >= T) continue;             // whole 16-lane group shares t -> shfl-safe
    long rowb = (long)b*T + t;
    float inv = (l_i[i] > 0.f) ? 1.f/l_i[i] : 0.f;
    float xv[8];
    float sm = 0.f;
    #pragma unroll
    for (int f=0;f<8;++f){
      float o = Oa[f][i]*inv;
      float h = h_aug[rowb*HD + f*16+lc];
      xv[f] = o + h;
      sm += xv[f];
    }
    sm += __shfl_xor(sm,1); sm += __shfl_xor(sm,2);
    sm += __shfl_xor(sm,4); sm += __shfl_xor(sm,8);
    float mean = sm * (1.f/HD);
    float vr = 0.f;
    #pragma unroll
    for (int f=0;f<8;++f){ float d = xv[f]-mean; vr += d*d; }
    vr += __shfl_xor(vr,1); vr += __shfl_xor(vr,2);
    vr += __shfl_xor(vr,4); vr += __shfl_xor(vr,8);
    float rstd = rsqrtf(vr*(1.f/HD) + 1e-5f);
    float rsum = 0.f;
    #pragma unroll
    for (int f=0;f<8;++f){
      int col = f*16+lc;
      float y = (xv[f]-mean)*rstd*lng[col] + lnb[col];
      if (writeOut){ if (t < N) out[((long)b*N + t)*HD + col] = y; }
      else h_aug[rowb*HD + col] = y;
      rsum += y * vnext[col];
    }
    rsum += __shfl_xor(rsum,1); rsum += __shfl_xor(rsum,2);
    rsum += __shfl_xor(rsum,4); rsum += __shfl_xor(rsum,8);
    if (writeRaw && lc == 0) rawnext[rowb] = rsum * scale;
  }
}

extern "C" void kernel_launch(void* const* d_in, const int* in_sizes, int n_in,
                              void* d_out, int out_size, void* d_ws, size_t ws_size,
                              hipStream_t stream) {
  const float* node_emb = (const float*)d_in[0];
  const float* Hinc     = (const float*)d_in[1];
  const int*   memb     = (const int*)d_in[2];
  const float* W1       = (const float*)d_in[3];
  const float* W1h      = (const float*)d_in[4];
  const float* ctx1     = (const float*)d_in[5];
  const float* W2       = (const float*)d_in[6];
  const float* W2h      = (const float*)d_in[7];
  const float* W3       = (const float*)d_in[8];
  const float* lng      = (const float*)d_in[9];
  const float* lnb      = (const float*)d_in[10];
  const float* rinit    = (const float*)d_in[11];
  float* out = (float*)d_out;

  const int N  = in_sizes[2];
  const int Hd = in_sizes[3] / in_sizes[5];
  const int L  = in_sizes[5] / Hd;
  const int R  = in_sizes[11] / Hd;
  const int B  = in_sizes[0] / (N * Hd);
  const int T  = N + R;
  const int E  = in_sizes[1] / T;
  const int MW = (E + 63) / 64;
  const float scale = 1.0f / sqrtf((float)Hd);

  char* p = (char*)d_ws;
  auto carve = [&](size_t bytes){ char* r = p; p += (bytes + 255) & ~(size_t)255; return (void*)r; };
  float* h_aug  = (float*)carve((size_t)B*T*Hd*4);
  u16*   proj1b = (u16*)  carve((size_t)B*T*Hd*2);
  float* qt     = (float*)carve((size_t)B*T*Hd*4);        // partials alias this
  u16*   hyb    = (u16*)  carve((size_t)B*E*Hd*2);
  u16*   hw2t   = (u16*)  carve((size_t)B*Hd*E*2);
  float* MqT    = (float*)carve((size_t)L*Hd*Hd*4);
  float* rawb   = (float*)carve((size_t)B*T*4);
  float* vbuf   = (float*)carve((size_t)L*Hd*4);
  u64*   maskw  = (u64*)  carve((size_t)T*MW*8);
  int* counts   = (int*)carve((size_t)R*4);
  int* col_cnt  = (int*)carve((size_t)E*4);
  u16* col_idx  = (u16*)carve((size_t)E*CAPE*2);

  float* partials = qt;               // alias: qt dead until first k_gemmM

  hipMemsetAsync(counts, 0, (size_t)R*4, stream);
  hipMemsetAsync(col_cnt, 0, (size_t)E*4, stream);

  k_count<<<32, 256, 0, stream>>>(memb, N, counts);

  int redN;
  if (R <= MAXR){
    k_regsum_fast<<<dim3(NB_RS, B), 128, 0, stream>>>(node_emb, memb, N, R, partials);
    redN = NB_RS;
  } else {
    hipMemsetAsync(partials, 0, (size_t)B*R*Hd*4, stream);
    k_regsum_lds<<<dim3(16, B), Hd, (size_t)R*Hd*4, stream>>>(node_emb, memb, N, R, partials, NB_RS);
    redN = 1;
  }
  int tot = B*R*Hd;
  k_regfin<<<(tot+255)/256, 256, 0, stream>>>(partials, NB_RS, redN, counts, rinit, h_aug, N, R, T, B);

  // static-structure builds (once per launch)
  long TE = (long)T*E;
  k_maskbuild<<<T, 256, 0, stream>>>(Hinc, E, MW, maskw);
  k_colbuild<<<2048, 256, 0, stream>>>(Hinc, TE, E, col_cnt, col_idx);

  k_ctxv<<<L, Hd, 0, stream>>>(ctx1, W1h, vbuf);
  k_mm128<<<dim3(Hd, L), Hd, 0, stream>>>(W2h, W3, MqT);
  k_copyraw<<<dim3(T, B), 128, 0, stream>>>(node_emb, vbuf, h_aug, rawb, N, T, scale);

  int MT = B*T;
  int gTm = (MT + 63)/64;
  int gTf = (T + 63)/64;
  int gEt = (E + 63)/64;
  int swzE = (B == 4 && (E & 1) == 0) ? 1 : 0;
  for (int l = 0; l < L; ++l){
    size_t wo = (size_t)l*Hd*Hd;
    // proj1 (bf16) = h@W1^T ; qt (f32) = h@MqT^T   [MFMA, batch-merged M]
    k_gemmM<<<dim3(gTm, 2), 256, 0, stream>>>(h_aug, W1 + wo, MqT + wo, proj1b, qt, MT, 0);
    k_edge<<<B*E, 128, 0, stream>>>(swzE, rawb, proj1b, col_cnt, col_idx, hyb, T, E);
    // hw2t (bf16, [b][h][e]) = W2 @ hyper^T   [MFMA]
    k_gemmW2T<<<dim3(gEt, B), 256, 0, stream>>>(W2 + wo, hyb, hw2t, E);
    int writeRaw = (l < L-1) ? 1 : 0;
    const float* vnext = vbuf + (size_t)((l+1 < L) ? (l+1) : l)*Hd;
    k_flash<<<dim3(gTf, B), 256, 0, stream>>>(qt, hyb, hw2t, maskw,
                                    lng + wo/Hd, lnb + wo/Hd,
                                    vnext, rawb, writeRaw,
                                    h_aug, out, T, E, N, (l == L-1) ? 1 : 0, scale);
  }
}

// Round 8
// 434.035 us; speedup vs baseline: 2.2878x; 1.1847x over previous
//
#include <hip/hip_runtime.h>

#define HD 128
#define CAPE 768
#define MAXR 16
#define NB_RS 128
#define KSTR 136   // K/LDS row stride in u16 (16B-aligned, 2-way banks)
#define VSTR 72    // V tile row stride in u16
#define PSTR 72    // P tile row stride in u16

typedef unsigned short u16;
typedef unsigned long long u64;
typedef __attribute__((ext_vector_type(8))) short bf16x8;
typedef __attribute__((ext_vector_type(4))) float f32x4;

__device__ inline float b2f(unsigned u){ return __uint_as_float(u << 16); }
__device__ inline u16 f2b(float x){
  unsigned u = __float_as_uint(x);
  return (u16)((u + 0x7fffu + ((u >> 16) & 1u)) >> 16);
}

// ---------- reduction helpers (block = 128 threads = 2 waves) ----------
__device__ inline float waveSum(float v){ for(int o=32;o;o>>=1) v += __shfl_down(v,o); return v; }
__device__ inline float waveMax(float v){ for(int o=32;o;o>>=1) v = fmaxf(v,__shfl_down(v,o)); return v; }

__device__ inline float blockSum128(float v, float* red){
  int j = threadIdx.x;
  float s = waveSum(v);
  __syncthreads();
  if ((j & 63) == 0) red[j >> 6] = s;
  __syncthreads();
  return red[0] + red[1];
}
__device__ inline float blockMax128(float v, float* red){
  int j = threadIdx.x;
  float s = waveMax(v);
  __syncthreads();
  if ((j & 63) == 0) red[j >> 6] = s;
  __syncthreads();
  return fmaxf(red[0], red[1]);
}

// ---------- region aggregation ----------
__global__ void k_count(const int* __restrict__ memb, int N, int* __restrict__ counts){
  __shared__ int h[64];
  int tid = threadIdx.x;
  if (tid < 64) h[tid] = 0;
  __syncthreads();
  for (int t = blockIdx.x*blockDim.x + tid; t < N; t += gridDim.x*blockDim.x)
    atomicAdd(&h[memb[t]], 1);
  __syncthreads();
  if (tid < 64){ int v = h[tid]; if (v) atomicAdd(&counts[tid], v); }
}

__global__ __launch_bounds__(128) void k_regsum_fast(const float* __restrict__ node,
                        const int* __restrict__ memb, int N, int R,
                        float* __restrict__ partials){
  int b = blockIdx.y, j = threadIdx.x, blk = blockIdx.x;
  int nb = gridDim.x;
  int per = (N + nb - 1) / nb;
  int t0 = blk * per;
  int t1 = t0 + per; if (t1 > N) t1 = N;
  float acc[MAXR];
  #pragma unroll
  for (int i = 0; i < MAXR; ++i) acc[i] = 0.f;
  const float* base = node + (long)b*N*HD + j;
  for (int t = t0; t < t1; ++t){
    float v = base[(long)t*HD];
    int r = memb[t];
    #pragma unroll
    for (int i = 0; i < MAXR; ++i) acc[i] += (i == r) ? v : 0.f;
  }
  float* dst = partials + ((long)(b*nb + blk)*R)*HD + j;
  #pragma unroll
  for (int i = 0; i < MAXR; ++i)
    if (i < R) dst[(long)i*HD] = acc[i];
}

__global__ void k_regsum_lds(const float* __restrict__ node, const int* __restrict__ memb,
                             int N, int R, float* __restrict__ partials, int nb){
  extern __shared__ float acc[];
  int b = blockIdx.y, j = threadIdx.x;
  for (int r = 0; r < R; ++r) acc[r*HD + j] = 0.f;
  int per = (N + gridDim.x - 1) / gridDim.x;
  int t0 = blockIdx.x * per;
  int t1 = t0 + per; if (t1 > N) t1 = N;
  for (int t = t0; t < t1; ++t){
    int r = memb[t];
    acc[r*HD + j] += node[((long)b*N + t)*HD + j];
  }
  for (int r = 0; r < R; ++r)
    atomicAdd(&partials[((long)(b*nb)*R + r)*HD + j], acc[r*HD + j]);
}

__global__ void k_regfin(const float* __restrict__ partials, int nb, int redN,
                         const int* __restrict__ counts,
                         const float* __restrict__ rinit, float* __restrict__ h_aug,
                         int N, int R, int T, int B){
  int i = blockIdx.x*blockDim.x + threadIdx.x;
  if (i >= B*R*HD) return;
  int j = i % HD; int r = (i/HD) % R; int b = i/(HD*R);
  float s = 0.f;
  for (int blk = 0; blk < redN; ++blk)
    s += partials[((long)(b*nb + blk)*R + r)*HD + j];
  int c = counts[r];
  float v = (c > 0) ? s / (float)c : 0.f;
  v += rinit[r*HD + j];
  h_aug[((long)b*T + N + r)*HD + j] = v;
}

// copy node rows into h_aug AND compute raw = (h·v)*scale (fused)
__global__ __launch_bounds__(128) void k_copyraw(const float* __restrict__ node,
                      const float* __restrict__ v, float* __restrict__ h_aug,
                      float* __restrict__ raw, int N, int T, float scale){
  int t = blockIdx.x, b = blockIdx.y, j = threadIdx.x;
  __shared__ float red[2];
  long rowb = (long)b*T + t;
  float x;
  if (t < N){ x = node[((long)b*N + t)*HD + j]; h_aug[rowb*HD + j] = x; }
  else      { x = h_aug[rowb*HD + j]; }
  float s = blockSum128(x * v[j], red);
  if (j == 0) raw[rowb] = s * scale;
}

// ---------- incidence bitmask: maskw[t][w] bit j <-> H_inc[t][w*64+j] != 0 ----------
__global__ __launch_bounds__(256) void k_maskbuild(const float* __restrict__ Hinc, int E, int MW,
                        u64* __restrict__ maskw){
  int t = blockIdx.x;
  int wv = threadIdx.x >> 6, lane = threadIdx.x & 63;
  const float* hrow = Hinc + (long)t*E;
  for (int w = wv; w < MW; w += 4){
    int e = w*64 + lane;
    bool f = (e < E) && (hrow[e] != 0.f);
    u64 mk = __ballot(f);
    if (lane == 0) maskw[(long)t*MW + w] = mk;
  }
}

// ---------- cols from bitmask: ballot-compaction, deterministic, atomic-free ----------
__global__ __launch_bounds__(256) void k_colbuild2(const u64* __restrict__ maskw, int T, int MW,
                           u16* __restrict__ colidx, int* __restrict__ colcnt){
  int e = blockIdx.x;
  int w = e >> 6, bit = e & 63;
  int j = threadIdx.x;
  int lane = j & 63, wv = j >> 6;
  __shared__ int wsum[4];
  int c = 0;
  for (int base = 0; base < T; base += 256){
    int t = base + j;
    bool f = (t < T) && ((maskw[(long)t*MW + w] >> bit) & 1ull);
    u64 mk = __ballot(f);
    if (lane == 0) wsum[wv] = __popcll(mk);
    __syncthreads();
    int pre = 0;
    #pragma unroll
    for (int k = 0; k < 4; ++k) pre += (k < wv) ? wsum[k] : 0;
    int tot = wsum[0] + wsum[1] + wsum[2] + wsum[3];
    if (f){
      int pos = c + pre + (int)__popcll(mk & ((1ull << lane) - 1ull));
      if (pos < CAPE) colidx[(long)e*CAPE + pos] = (u16)t;
    }
    c += tot;
    __syncthreads();
  }
  if (j == 0) colcnt[e] = (c < CAPE) ? c : CAPE;
}

// ---------- small precomputes ----------
__global__ void k_ctxv(const float* __restrict__ ctx1, const float* __restrict__ W1h,
                       float* __restrict__ v){
  int l = blockIdx.x, k = threadIdx.x;
  float a = 0.f;
  for (int j = 0; j < HD; ++j) a += ctx1[l*HD + j] * W1h[((long)l*HD + j)*HD + k];
  v[l*HD + k] = a;
}

// MqT[l][n][k] = sum_j W2h[l][j][n] * W3[l][j][k]
__global__ void k_mm128(const float* __restrict__ W2h, const float* __restrict__ W3,
                        float* __restrict__ MqT){
  int n = blockIdx.x, l = blockIdx.y, k = threadIdx.x;
  const float* A = W2h + (long)l*HD*HD;
  const float* Bm = W3 + (long)l*HD*HD;
  float s = 0.f;
  for (int j = 0; j < HD; ++j) s += A[(long)j*HD + n] * Bm[(long)j*HD + k];
  MqT[((long)l*HD + n)*HD + k] = s;
}

// ---------- MFMA bf16 GEMM: C = A @ W^T (A f32 (M,128); z picks W/output form) ----------
__global__ __launch_bounds__(256) void k_gemmM(const float* __restrict__ A,
                       const float* __restrict__ Wa, const float* __restrict__ Wb,
                       u16* __restrict__ Cb16, float* __restrict__ Cf32, int M, int zbase){
  int isB = ((blockIdx.y + zbase) == 0) ? 1 : 0;
  const float* W = isB ? Wa : Wb;
  __shared__ __align__(16) u16 Ws[128][KSTR];
  __shared__ __align__(16) u16 As[64][KSTR];
  int tid = threadIdx.x;
  int row0 = blockIdx.x * 64;
  for (int i = tid; i < 128*128; i += 256){
    int r = i >> 7, c = i & 127;
    Ws[r][c] = f2b(W[(long)r*HD + c]);
  }
  for (int i = tid; i < 64*128; i += 256){
    int r = i >> 7, c = i & 127;
    int gr = row0 + r;
    As[r][c] = (gr < M) ? f2b(A[(long)gr*HD + c]) : (u16)0;
  }
  __syncthreads();

  int wave = tid >> 6, lane = tid & 63;
  int wr0 = wave * 16;
  int frow = lane & 15;
  int koff = (lane >> 4) * 8;
  f32x4 acc[8];
  #pragma unroll
  for (int f = 0; f < 8; ++f) acc[f] = (f32x4){0.f,0.f,0.f,0.f};

  #pragma unroll
  for (int ks = 0; ks < 4; ++ks){
    int kc = ks*32 + koff;
    bf16x8 av = *(const bf16x8*)&As[wr0 + frow][kc];
    #pragma unroll
    for (int f = 0; f < 8; ++f){
      bf16x8 bv = *(const bf16x8*)&Ws[f*16 + frow][kc];
      acc[f] = __builtin_amdgcn_mfma_f32_16x16x32_bf16(av, bv, acc[f], 0, 0, 0);
    }
  }

  int orow = wr0 + (lane >> 4) * 4;
  #pragma unroll
  for (int f = 0; f < 8; ++f){
    int col = f*16 + frow;
    #pragma unroll
    for (int i = 0; i < 4; ++i){
      int gr = row0 + orow + i;
      if (gr < M){
        if (isB) Cb16[(long)gr*HD + col] = f2b(acc[f][i]);
        else     Cf32[(long)gr*HD + col] = acc[f][i];
      }
    }
  }
}

// ---------- hw2t[b][h][e] = sum_d W2[h][d] * hyper[b][e][d]  (bf16 out, e-major) ----------
__global__ __launch_bounds__(256) void k_gemmW2T(const float* __restrict__ W2,
                       const u16* __restrict__ hyb, u16* __restrict__ hw2t, int E){
  int b = blockIdx.y;
  int e0 = blockIdx.x * 64;
  __shared__ __align__(16) u16 As[128][KSTR];
  __shared__ __align__(16) u16 Bs[64][KSTR];
  int tid = threadIdx.x;
  for (int i = tid; i < 128*128; i += 256){
    int r = i >> 7, c = i & 127;
    As[r][c] = f2b(W2[(long)r*HD + c]);
  }
  {
    int er = tid >> 2, q = (tid & 3)*32;
    if (e0 + er < E){
      const uint4* src = (const uint4*)(hyb + ((long)b*E + e0 + er)*HD + q);
      uint4 w0 = src[0], w1 = src[1], w2 = src[2], w3 = src[3];
      *(uint4*)&Bs[er][q]    = w0;
      *(uint4*)&Bs[er][q+8]  = w1;
      *(uint4*)&Bs[er][q+16] = w2;
      *(uint4*)&Bs[er][q+24] = w3;
    } else {
      uint4 z = {0,0,0,0};
      *(uint4*)&Bs[er][q] = z; *(uint4*)&Bs[er][q+8] = z;
      *(uint4*)&Bs[er][q+16] = z; *(uint4*)&Bs[er][q+24] = z;
    }
  }
  __syncthreads();
  int wv = tid >> 6, lane = tid & 63;
  int lc = lane & 15, lg = lane >> 4;
  f32x4 acc[2][4];
  #pragma unroll
  for (int mt=0;mt<2;++mt)
    #pragma unroll
    for (int nf=0;nf<4;++nf) acc[mt][nf] = (f32x4){0.f,0.f,0.f,0.f};
  #pragma unroll
  for (int mt=0;mt<2;++mt){
    int hr = wv*32 + mt*16 + lc;
    #pragma unroll
    for (int ks=0;ks<4;++ks){
      bf16x8 av = *(const bf16x8*)&As[hr][ks*32 + lg*8];
      #pragma unroll
      for (int nf=0;nf<4;++nf){
        bf16x8 bv = *(const bf16x8*)&Bs[nf*16+lc][ks*32 + lg*8];
        acc[mt][nf] = __builtin_amdgcn_mfma_f32_16x16x32_bf16(av, bv, acc[mt][nf], 0,0,0);
      }
    }
  }
  #pragma unroll
  for (int mt=0;mt<2;++mt){
    #pragma unroll
    for (int nf=0;nf<4;++nf){
      #pragma unroll
      for (int i=0;i<4;++i){
        int h = wv*32 + mt*16 + lg*4 + i;
        int e = e0 + nf*16 + lc;
        if (e < E) hw2t[((long)b*HD + h)*E + e] = f2b(acc[mt][nf][i]);
      }
    }
  }
}

// ---------- stage 1: per-edge masked softmax + weighted sum of proj1 (bf16 out) ----------
__global__ __launch_bounds__(128) void k_edge(int swz, const float* __restrict__ raw,
                      const u16* __restrict__ proj1b,
                      const int* __restrict__ colcnt, const u16* __restrict__ colidx,
                      u16* __restrict__ hyb, int T, int E){
  int bi = blockIdx.x;
  int b, e;
  if (swz){ int x = bi & 7; b = x >> 1; e = ((bi >> 3) << 1) | (x & 1); }
  else    { b = bi / E; e = bi - b*E; }
  int j = threadIdx.x;
  __shared__ float red[2];
  __shared__ float wls[CAPE];
  __shared__ int   tls[CAPE];
  int c = colcnt[e]; if (c > CAPE) c = CAPE;
  const u16* ci = colidx + (long)e*CAPE;
  const float* rawb = raw + (long)b*T;
  long orow = ((long)b*E + e)*HD + j;
  if (c <= 0){ hyb[orow] = 0; return; }
  float lm = -1e30f;
  for (int i = j; i < c; i += 128){
    int t = ci[i];
    float v = rawb[t];
    tls[i] = t;
    wls[i] = v;
    lm = fmaxf(lm, v);
  }
  float m = blockMax128(lm, red);
  float lz = 0.f;
  for (int i = j; i < c; i += 128){
    float w = __expf(wls[i] - m);
    wls[i] = w;
    lz += w;
  }
  float Z = blockSum128(lz, red);
  float invZ = 1.f / Z;
  const u16* pb = proj1b + (long)b*T*HD + j;
  float a0=0.f,a1=0.f,a2=0.f,a3=0.f;
  int i = 0;
  for (; i + 4 <= c; i += 4){
    a0 += wls[i]   * b2f(pb[(long)tls[i]  *HD]);
    a1 += wls[i+1] * b2f(pb[(long)tls[i+1]*HD]);
    a2 += wls[i+2] * b2f(pb[(long)tls[i+2]*HD]);
    a3 += wls[i+3] * b2f(pb[(long)tls[i+3]*HD]);
  }
  for (; i < c; ++i) a0 += wls[i] * b2f(pb[(long)tls[i]*HD]);
  hyb[orow] = f2b(((a0+a1)+(a2+a3)) * invZ);
}

// ---------- stage 2: flash-dense masked attention + residual + LN (+ fused next raw) ----------
__global__ __launch_bounds__(256) void k_flash(
      const float* __restrict__ qt, const u16* __restrict__ hyb, const u16* __restrict__ hw2t,
      const u64* __restrict__ maskw,
      const float* __restrict__ lng, const float* __restrict__ lnb,
      const float* __restrict__ vnext, float* __restrict__ rawnext, int writeRaw,
      float* __restrict__ h_aug, float* __restrict__ out,
      int T, int E, int N, int writeOut, float scale){
  int b = blockIdx.y;
  int t0 = blockIdx.x * 64;
  int tid = threadIdx.x;
  int wv = tid >> 6, lane = tid & 63;
  int lc = lane & 15, lg = lane >> 4;

  __shared__ __align__(16) u16 Ks[64][KSTR];
  __shared__ __align__(16) u16 Vs[128][VSTR];
  __shared__ __align__(16) u16 Ps[4][16][PSTR];

  int qrow = t0 + wv*16 + lc;
  bf16x8 qf[4];
  if (qrow < T){
    const float* qr = qt + ((long)b*T + qrow)*HD + lg*8;
    #pragma unroll
    for (int ks = 0; ks < 4; ++ks){
      const float4* q4 = (const float4*)(qr + ks*32);
      float4 a = q4[0], cc = q4[1];
      bf16x8 v;
      v[0]=(short)f2b(a.x);  v[1]=(short)f2b(a.y);  v[2]=(short)f2b(a.z);  v[3]=(short)f2b(a.w);
      v[4]=(short)f2b(cc.x); v[5]=(short)f2b(cc.y); v[6]=(short)f2b(cc.z); v[7]=(short)f2b(cc.w);
      qf[ks] = v;
    }
  } else {
    #pragma unroll
    for (int ks = 0; ks < 4; ++ks) qf[ks] = (bf16x8){0,0,0,0,0,0,0,0};
  }

  int mrow[4];
  #pragma unroll
  for (int i=0;i<4;++i) mrow[i] = t0 + wv*16 + lg*4 + i;

  float m_i[4], l_i[4];
  #pragma unroll
  for (int i=0;i<4;++i){ m_i[i] = -1e30f; l_i[i] = 0.f; }
  f32x4 Oa[8];
  #pragma unroll
  for (int f=0;f<8;++f) Oa[f] = (f32x4){0.f,0.f,0.f,0.f};

  const u16* hyB = hyb + (long)b*E*HD;
  const u16* vtB = hw2t + (long)b*HD*E;
  int MW = (E + 63) >> 6;
  int ntile = (E + 63) / 64;

  for (int et = 0; et < ntile; ++et){
    int e0 = et*64;
    {
      int er = tid >> 2, q = (tid & 3)*32;
      if (e0 + er < E){
        const uint4* src = (const uint4*)(hyB + (long)(e0+er)*HD + q);
        uint4 w0 = src[0], w1 = src[1], w2 = src[2], w3 = src[3];
        *(uint4*)&Ks[er][q]    = w0;
        *(uint4*)&Ks[er][q+8]  = w1;
        *(uint4*)&Ks[er][q+16] = w2;
        *(uint4*)&Ks[er][q+24] = w3;
      } else {
        uint4 z = {0,0,0,0};
        *(uint4*)&Ks[er][q] = z; *(uint4*)&Ks[er][q+8] = z;
        *(uint4*)&Ks[er][q+16] = z; *(uint4*)&Ks[er][q+24] = z;
      }
    }
    {
      int h = tid >> 1, off = (tid & 1)*32;
      if (e0 + off + 31 < E){
        const uint4* src = (const uint4*)(vtB + (long)h*E + e0 + off);
        uint4 w0 = src[0], w1 = src[1], w2 = src[2], w3 = src[3];
        *(uint4*)&Vs[h][off]    = w0;
        *(uint4*)&Vs[h][off+8]  = w1;
        *(uint4*)&Vs[h][off+16] = w2;
        *(uint4*)&Vs[h][off+24] = w3;
      } else {
        for (int k = 0; k < 32; ++k){
          int e = e0 + off + k;
          Vs[h][off+k] = (e < E) ? vtB[(long)h*E + e] : (u16)0;
        }
      }
    }
    __syncthreads();

    f32x4 accS[4];
    #pragma unroll
    for (int ne=0;ne<4;++ne) accS[ne] = (f32x4){0.f,0.f,0.f,0.f};
    #pragma unroll
    for (int ks=0;ks<4;++ks){
      #pragma unroll
      for (int ne=0;ne<4;++ne){
        bf16x8 kv = *(const bf16x8*)&Ks[ne*16+lc][ks*32 + lg*8];
        accS[ne] = __builtin_amdgcn_mfma_f32_16x16x32_bf16(qf[ks], kv, accS[ne], 0,0,0);
      }
    }

    u64 mw[4];
    #pragma unroll
    for (int i=0;i<4;++i)
      mw[i] = (mrow[i] < T) ? maskw[(long)mrow[i]*MW + et] : 0ull;

    float p[4][4];
    #pragma unroll
    for (int i=0;i<4;++i){
      float sv[4];
      float mx = -1e30f;
      #pragma unroll
      for (int ne=0;ne<4;++ne){
        int bit = (int)((mw[i] >> (ne*16 + lc)) & 1ull);
        float s = bit ? accS[ne][i]*scale : -1e30f;
        sv[ne] = s;
        mx = fmaxf(mx, s);
      }
      mx = fmaxf(mx, __shfl_xor(mx,1));
      mx = fmaxf(mx, __shfl_xor(mx,2));
      mx = fmaxf(mx, __shfl_xor(mx,4));
      mx = fmaxf(mx, __shfl_xor(mx,8));
      float mn = fmaxf(m_i[i], mx);
      float corr = __expf(m_i[i] - mn);
      m_i[i] = mn;
      float ls = 0.f;
      #pragma unroll
      for (int ne=0;ne<4;++ne){
        float pv = (sv[ne] > -1e29f) ? __expf(sv[ne] - mn) : 0.f;
        p[ne][i] = pv;
        ls += pv;
      }
      ls += __shfl_xor(ls,1);
      ls += __shfl_xor(ls,2);
      ls += __shfl_xor(ls,4);
      ls += __shfl_xor(ls,8);
      l_i[i] = l_i[i]*corr + ls;
      #pragma unroll
      for (int f=0;f<8;++f) Oa[f][i] *= corr;
    }

    #pragma unroll
    for (int i=0;i<4;++i){
      #pragma unroll
      for (int ne=0;ne<4;++ne)
        Ps[wv][lg*4+i][ne*16+lc] = f2b(p[ne][i]);
    }
    #pragma unroll
    for (int ks2=0;ks2<2;++ks2){
      bf16x8 pa = *(const bf16x8*)&Ps[wv][lc][ks2*32 + lg*8];
      #pragma unroll
      for (int f=0;f<8;++f){
        bf16x8 vb = *(const bf16x8*)&Vs[f*16+lc][ks2*32 + lg*8];
        Oa[f] = __builtin_amdgcn_mfma_f32_16x16x32_bf16(pa, vb, Oa[f], 0,0,0);
      }
    }
    __syncthreads();
  }

  #pragma unroll
  for (int i=0;i<4;++i){
    int t = mrow[i];
    if (t >= T) continue;
    long rowb = (long)b*T + t;
    float inv = (l_i[i] > 0.f) ? 1.f/l_i[i] : 0.f;
    float xv[8];
    float sm = 0.f;
    #pragma unroll
    for (int f=0;f<8;++f){
      float o = Oa[f][i]*inv;
      float h = h_aug[rowb*HD + f*16+lc];
      xv[f] = o + h;
      sm += xv[f];
    }
    sm += __shfl_xor(sm,1); sm += __shfl_xor(sm,2);
    sm += __shfl_xor(sm,4); sm += __shfl_xor(sm,8);
    float mean = sm * (1.f/HD);
    float vr = 0.f;
    #pragma unroll
    for (int f=0;f<8;++f){ float d = xv[f]-mean; vr += d*d; }
    vr += __shfl_xor(vr,1); vr += __shfl_xor(vr,2);
    vr += __shfl_xor(vr,4); vr += __shfl_xor(vr,8);
    float rstd = rsqrtf(vr*(1.f/HD) + 1e-5f);
    float rsum = 0.f;
    #pragma unroll
    for (int f=0;f<8;++f){
      int col = f*16+lc;
      float y = (xv[f]-mean)*rstd*lng[col] + lnb[col];
      if (writeOut){ if (t < N) out[((long)b*N + t)*HD + col] = y; }
      else h_aug[rowb*HD + col] = y;
      rsum += y * vnext[col];
    }
    rsum += __shfl_xor(rsum,1); rsum += __shfl_xor(rsum,2);
    rsum += __shfl_xor(rsum,4); rsum += __shfl_xor(rsum,8);
    if (writeRaw && lc == 0) rawnext[rowb] = rsum * scale;
  }
}

extern "C" void kernel_launch(void* const* d_in, const int* in_sizes, int n_in,
                              void* d_out, int out_size, void* d_ws, size_t ws_size,
                              hipStream_t stream) {
  const float* node_emb = (const float*)d_in[0];
  const float* Hinc     = (const float*)d_in[1];
  const int*   memb     = (const int*)d_in[2];
  const float* W1       = (const float*)d_in[3];
  const float* W1h      = (const float*)d_in[4];
  const float* ctx1     = (const float*)d_in[5];
  const float* W2       = (const float*)d_in[6];
  const float* W2h      = (const float*)d_in[7];
  const float* W3       = (const float*)d_in[8];
  const float* lng      = (const float*)d_in[9];
  const float* lnb      = (const float*)d_in[10];
  const float* rinit    = (const float*)d_in[11];
  float* out = (float*)d_out;

  const int N  = in_sizes[2];
  const int Hd = in_sizes[3] / in_sizes[5];
  const int L  = in_sizes[5] / Hd;
  const int R  = in_sizes[11] / Hd;
  const int B  = in_sizes[0] / (N * Hd);
  const int T  = N + R;
  const int E  = in_sizes[1] / T;
  const int MW = (E + 63) / 64;
  const float scale = 1.0f / sqrtf((float)Hd);

  char* p = (char*)d_ws;
  auto carve = [&](size_t bytes){ char* r = p; p += (bytes + 255) & ~(size_t)255; return (void*)r; };
  float* h_aug  = (float*)carve((size_t)B*T*Hd*4);
  u16*   proj1b = (u16*)  carve((size_t)B*T*Hd*2);
  float* qt     = (float*)carve((size_t)B*T*Hd*4);        // partials alias this
  u16*   hyb    = (u16*)  carve((size_t)B*E*Hd*2);
  u16*   hw2t   = (u16*)  carve((size_t)B*Hd*E*2);
  float* MqT    = (float*)carve((size_t)L*Hd*Hd*4);
  float* rawb   = (float*)carve((size_t)B*T*4);
  float* vbuf   = (float*)carve((size_t)L*Hd*4);
  u64*   maskw  = (u64*)  carve((size_t)T*MW*8);
  int* counts   = (int*)carve((size_t)R*4);
  int* col_cnt  = (int*)carve((size_t)E*4);
  u16* col_idx  = (u16*)carve((size_t)E*CAPE*2);

  float* partials = qt;               // alias: qt dead until first k_gemmM

  hipMemsetAsync(counts, 0, (size_t)R*4, stream);

  k_count<<<32, 256, 0, stream>>>(memb, N, counts);

  int redN;
  if (R <= MAXR){
    k_regsum_fast<<<dim3(NB_RS, B), 128, 0, stream>>>(node_emb, memb, N, R, partials);
    redN = NB_RS;
  } else {
    hipMemsetAsync(partials, 0, (size_t)B*R*Hd*4, stream);
    k_regsum_lds<<<dim3(16, B), Hd, (size_t)R*Hd*4, stream>>>(node_emb, memb, N, R, partials, NB_RS);
    redN = 1;
  }
  int tot = B*R*Hd;
  k_regfin<<<(tot+255)/256, 256, 0, stream>>>(partials, NB_RS, redN, counts, rinit, h_aug, N, R, T, B);

  // static-structure builds (once per launch): bitmask, then cols from bitmask
  k_maskbuild<<<T, 256, 0, stream>>>(Hinc, E, MW, maskw);
  k_colbuild2<<<E, 256, 0, stream>>>(maskw, T, MW, col_idx, col_cnt);

  k_ctxv<<<L, Hd, 0, stream>>>(ctx1, W1h, vbuf);
  k_mm128<<<dim3(Hd, L), Hd, 0, stream>>>(W2h, W3, MqT);
  k_copyraw<<<dim3(T, B), 128, 0, stream>>>(node_emb, vbuf, h_aug, rawb, N, T, scale);

  int MT = B*T;
  int gTm = (MT + 63)/64;
  int gTf = (T + 63)/64;
  int gEt = (E + 63)/64;
  int swzE = (B == 4 && (E & 1) == 0) ? 1 : 0;
  for (int l = 0; l < L; ++l){
    size_t wo = (size_t)l*Hd*Hd;
    k_gemmM<<<dim3(gTm, 2), 256, 0, stream>>>(h_aug, W1 + wo, MqT + wo, proj1b, qt, MT, 0);
    k_edge<<<B*E, 128, 0, stream>>>(swzE, rawb, proj1b, col_cnt, col_idx, hyb, T, E);
    k_gemmW2T<<<dim3(gEt, B), 256, 0, stream>>>(W2 + wo, hyb, hw2t, E);
    int writeRaw = (l < L-1) ? 1 : 0;
    const float* vnext = vbuf + (size_t)((l+1 < L) ? (l+1) : l)*Hd;
    k_flash<<<dim3(gTf, B), 256, 0, stream>>>(qt, hyb, hw2t, maskw,
                                    lng + wo/Hd, lnb + wo/Hd,
                                    vnext, rawb, writeRaw,
                                    h_aug, out, T, E, N, (l == L-1) ? 1 : 0, scale);
  }
}

// Round 9
// 405.839 us; speedup vs baseline: 2.4468x; 1.0695x over previous
//
#include <hip/hip_runtime.h>

#define HD 128
#define CAPE 768
#define MAXR 16
#define NB_RS 128
#define KSTR 136   // K LDS row stride in u16 (16B-aligned rows, 2-way banks)
#define VSTR 72    // V tile row stride in u16

typedef unsigned short u16;
typedef unsigned long long u64;
typedef __attribute__((ext_vector_type(8))) short bf16x8;
typedef __attribute__((ext_vector_type(4))) float f32x4;
typedef __attribute__((ext_vector_type(4))) unsigned u32x4;

__device__ inline float b2f(unsigned u){ return __uint_as_float(u << 16); }
__device__ inline u16 f2b(float x){
  unsigned u = __float_as_uint(x);
  return (u16)((u + 0x7fffu + ((u >> 16) & 1u)) >> 16);
}

// ---------- reduction helpers (block = 128 threads = 2 waves) ----------
__device__ inline float waveSum(float v){ for(int o=32;o;o>>=1) v += __shfl_down(v,o); return v; }
__device__ inline float waveMax(float v){ for(int o=32;o;o>>=1) v = fmaxf(v,__shfl_down(v,o)); return v; }

__device__ inline float blockSum128(float v, float* red){
  int j = threadIdx.x;
  float s = waveSum(v);
  __syncthreads();
  if ((j & 63) == 0) red[j >> 6] = s;
  __syncthreads();
  return red[0] + red[1];
}
__device__ inline float blockMax128(float v, float* red){
  int j = threadIdx.x;
  float s = waveMax(v);
  __syncthreads();
  if ((j & 63) == 0) red[j >> 6] = s;
  __syncthreads();
  return fmaxf(red[0], red[1]);
}

// ---------- region aggregation ----------
__global__ void k_count(const int* __restrict__ memb, int N, int* __restrict__ counts){
  __shared__ int h[64];
  int tid = threadIdx.x;
  if (tid < 64) h[tid] = 0;
  __syncthreads();
  for (int t = blockIdx.x*blockDim.x + tid; t < N; t += gridDim.x*blockDim.x)
    atomicAdd(&h[memb[t]], 1);
  __syncthreads();
  if (tid < 64){ int v = h[tid]; if (v) atomicAdd(&counts[tid], v); }
}

__global__ __launch_bounds__(128) void k_regsum_fast(const float* __restrict__ node,
                        const int* __restrict__ memb, int N, int R,
                        float* __restrict__ partials){
  int b = blockIdx.y, j = threadIdx.x, blk = blockIdx.x;
  int nb = gridDim.x;
  int per = (N + nb - 1) / nb;
  int t0 = blk * per;
  int t1 = t0 + per; if (t1 > N) t1 = N;
  float acc[MAXR];
  #pragma unroll
  for (int i = 0; i < MAXR; ++i) acc[i] = 0.f;
  const float* base = node + (long)b*N*HD + j;
  for (int t = t0; t < t1; ++t){
    float v = base[(long)t*HD];
    int r = memb[t];
    #pragma unroll
    for (int i = 0; i < MAXR; ++i) acc[i] += (i == r) ? v : 0.f;
  }
  float* dst = partials + ((long)(b*nb + blk)*R)*HD + j;
  #pragma unroll
  for (int i = 0; i < MAXR; ++i)
    if (i < R) dst[(long)i*HD] = acc[i];
}

__global__ void k_regsum_lds(const float* __restrict__ node, const int* __restrict__ memb,
                             int N, int R, float* __restrict__ partials, int nb){
  extern __shared__ float acc[];
  int b = blockIdx.y, j = threadIdx.x;
  for (int r = 0; r < R; ++r) acc[r*HD + j] = 0.f;
  int per = (N + gridDim.x - 1) / gridDim.x;
  int t0 = blockIdx.x * per;
  int t1 = t0 + per; if (t1 > N) t1 = N;
  for (int t = t0; t < t1; ++t){
    int r = memb[t];
    acc[r*HD + j] += node[((long)b*N + t)*HD + j];
  }
  for (int r = 0; r < R; ++r)
    atomicAdd(&partials[((long)(b*nb)*R + r)*HD + j], acc[r*HD + j]);
}

__global__ void k_regfin(const float* __restrict__ partials, int nb, int redN,
                         const int* __restrict__ counts,
                         const float* __restrict__ rinit, float* __restrict__ h_aug,
                         int N, int R, int T, int B){
  int i = blockIdx.x*blockDim.x + threadIdx.x;
  if (i >= B*R*HD) return;
  int j = i % HD; int r = (i/HD) % R; int b = i/(HD*R);
  float s = 0.f;
  for (int blk = 0; blk < redN; ++blk)
    s += partials[((long)(b*nb + blk)*R + r)*HD + j];
  int c = counts[r];
  float v = (c > 0) ? s / (float)c : 0.f;
  v += rinit[r*HD + j];
  h_aug[((long)b*T + N + r)*HD + j] = v;
}

// copy node rows into h_aug AND compute raw = (h·v)*scale (fused)
__global__ __launch_bounds__(128) void k_copyraw(const float* __restrict__ node,
                      const float* __restrict__ v, float* __restrict__ h_aug,
                      float* __restrict__ raw, int N, int T, float scale){
  int t = blockIdx.x, b = blockIdx.y, j = threadIdx.x;
  __shared__ float red[2];
  long rowb = (long)b*T + t;
  float x;
  if (t < N){ x = node[((long)b*N + t)*HD + j]; h_aug[rowb*HD + j] = x; }
  else      { x = h_aug[rowb*HD + j]; }
  float s = blockSum128(x * v[j], red);
  if (j == 0) raw[rowb] = s * scale;
}

// ---------- incidence bitmask ----------
__global__ __launch_bounds__(256) void k_maskbuild(const float* __restrict__ Hinc, int E, int MW,
                        u64* __restrict__ maskw){
  int t = blockIdx.x;
  int wv = threadIdx.x >> 6, lane = threadIdx.x & 63;
  const float* hrow = Hinc + (long)t*E;
  for (int w = wv; w < MW; w += 4){
    int e = w*64 + lane;
    bool f = (e < E) && (hrow[e] != 0.f);
    u64 mk = __ballot(f);
    if (lane == 0) maskw[(long)t*MW + w] = mk;
  }
}

// ---------- cols from bitmask: ballot-compaction, deterministic, atomic-free ----------
__global__ __launch_bounds__(256) void k_colbuild2(const u64* __restrict__ maskw, int T, int MW,
                           u16* __restrict__ colidx, int* __restrict__ colcnt){
  int e = blockIdx.x;
  int w = e >> 6, bit = e & 63;
  int j = threadIdx.x;
  int lane = j & 63, wv = j >> 6;
  __shared__ int wsum[4];
  int c = 0;
  for (int base = 0; base < T; base += 256){
    int t = base + j;
    bool f = (t < T) && ((maskw[(long)t*MW + w] >> bit) & 1ull);
    u64 mk = __ballot(f);
    if (lane == 0) wsum[wv] = __popcll(mk);
    __syncthreads();
    int pre = 0;
    #pragma unroll
    for (int k = 0; k < 4; ++k) pre += (k < wv) ? wsum[k] : 0;
    int tot = wsum[0] + wsum[1] + wsum[2] + wsum[3];
    if (f){
      int pos = c + pre + (int)__popcll(mk & ((1ull << lane) - 1ull));
      if (pos < CAPE) colidx[(long)e*CAPE + pos] = (u16)t;
    }
    c += tot;
    __syncthreads();
  }
  if (j == 0) colcnt[e] = (c < CAPE) ? c : CAPE;
}

// ---------- small precomputes ----------
__global__ void k_ctxv(const float* __restrict__ ctx1, const float* __restrict__ W1h,
                       float* __restrict__ v){
  int l = blockIdx.x, k = threadIdx.x;
  float a = 0.f;
  for (int j = 0; j < HD; ++j) a += ctx1[l*HD + j] * W1h[((long)l*HD + j)*HD + k];
  v[l*HD + k] = a;
}

__global__ void k_mm128(const float* __restrict__ W2h, const float* __restrict__ W3,
                        float* __restrict__ MqT){
  int n = blockIdx.x, l = blockIdx.y, k = threadIdx.x;
  const float* A = W2h + (long)l*HD*HD;
  const float* Bm = W3 + (long)l*HD*HD;
  float s = 0.f;
  for (int j = 0; j < HD; ++j) s += A[(long)j*HD + n] * Bm[(long)j*HD + k];
  MqT[((long)l*HD + n)*HD + k] = s;
}

// ---------- MFMA bf16 GEMM: C = A @ W^T ----------
__global__ __launch_bounds__(256) void k_gemmM(const float* __restrict__ A,
                       const float* __restrict__ Wa, const float* __restrict__ Wb,
                       u16* __restrict__ Cb16, float* __restrict__ Cf32, int M, int zbase){
  int isB = ((blockIdx.y + zbase) == 0) ? 1 : 0;
  const float* W = isB ? Wa : Wb;
  __shared__ __align__(16) u16 Ws[128][KSTR];
  __shared__ __align__(16) u16 As[64][KSTR];
  int tid = threadIdx.x;
  int row0 = blockIdx.x * 64;
  for (int i = tid; i < 128*128; i += 256){
    int r = i >> 7, c = i & 127;
    Ws[r][c] = f2b(W[(long)r*HD + c]);
  }
  for (int i = tid; i < 64*128; i += 256){
    int r = i >> 7, c = i & 127;
    int gr = row0 + r;
    As[r][c] = (gr < M) ? f2b(A[(long)gr*HD + c]) : (u16)0;
  }
  __syncthreads();

  int wave = tid >> 6, lane = tid & 63;
  int wr0 = wave * 16;
  int frow = lane & 15;
  int koff = (lane >> 4) * 8;
  f32x4 acc[8];
  #pragma unroll
  for (int f = 0; f < 8; ++f) acc[f] = (f32x4){0.f,0.f,0.f,0.f};

  #pragma unroll
  for (int ks = 0; ks < 4; ++ks){
    int kc = ks*32 + koff;
    bf16x8 av = *(const bf16x8*)&As[wr0 + frow][kc];
    #pragma unroll
    for (int f = 0; f < 8; ++f){
      bf16x8 bv = *(const bf16x8*)&Ws[f*16 + frow][kc];
      acc[f] = __builtin_amdgcn_mfma_f32_16x16x32_bf16(av, bv, acc[f], 0, 0, 0);
    }
  }

  int orow = wr0 + (lane >> 4) * 4;
  #pragma unroll
  for (int f = 0; f < 8; ++f){
    int col = f*16 + frow;
    #pragma unroll
    for (int i = 0; i < 4; ++i){
      int gr = row0 + orow + i;
      if (gr < M){
        if (isB) Cb16[(long)gr*HD + col] = f2b(acc[f][i]);
        else     Cf32[(long)gr*HD + col] = acc[f][i];
      }
    }
  }
}

// ---------- hw2t[b][h][e] = sum_d W2[h][d] * hyper[b][e][d]  (bf16 out, e-major) ----------
__global__ __launch_bounds__(256) void k_gemmW2T(const float* __restrict__ W2,
                       const u16* __restrict__ hyb, u16* __restrict__ hw2t, int E){
  int b = blockIdx.y;
  int e0 = blockIdx.x * 64;
  __shared__ __align__(16) u16 As[128][KSTR];
  __shared__ __align__(16) u16 Bs[64][KSTR];
  int tid = threadIdx.x;
  for (int i = tid; i < 128*128; i += 256){
    int r = i >> 7, c = i & 127;
    As[r][c] = f2b(W2[(long)r*HD + c]);
  }
  {
    int er = tid >> 2, q = (tid & 3)*32;
    if (e0 + er < E){
      const uint4* src = (const uint4*)(hyb + ((long)b*E + e0 + er)*HD + q);
      uint4 w0 = src[0], w1 = src[1], w2 = src[2], w3 = src[3];
      *(uint4*)&Bs[er][q]    = w0;
      *(uint4*)&Bs[er][q+8]  = w1;
      *(uint4*)&Bs[er][q+16] = w2;
      *(uint4*)&Bs[er][q+24] = w3;
    } else {
      uint4 z = {0,0,0,0};
      *(uint4*)&Bs[er][q] = z; *(uint4*)&Bs[er][q+8] = z;
      *(uint4*)&Bs[er][q+16] = z; *(uint4*)&Bs[er][q+24] = z;
    }
  }
  __syncthreads();
  int wv = tid >> 6, lane = tid & 63;
  int lc = lane & 15, lg = lane >> 4;
  f32x4 acc[2][4];
  #pragma unroll
  for (int mt=0;mt<2;++mt)
    #pragma unroll
    for (int nf=0;nf<4;++nf) acc[mt][nf] = (f32x4){0.f,0.f,0.f,0.f};
  #pragma unroll
  for (int mt=0;mt<2;++mt){
    int hr = wv*32 + mt*16 + lc;
    #pragma unroll
    for (int ks=0;ks<4;++ks){
      bf16x8 av = *(const bf16x8*)&As[hr][ks*32 + lg*8];
      #pragma unroll
      for (int nf=0;nf<4;++nf){
        bf16x8 bv = *(const bf16x8*)&Bs[nf*16+lc][ks*32 + lg*8];
        acc[mt][nf] = __builtin_amdgcn_mfma_f32_16x16x32_bf16(av, bv, acc[mt][nf], 0,0,0);
      }
    }
  }
  #pragma unroll
  for (int mt=0;mt<2;++mt){
    #pragma unroll
    for (int nf=0;nf<4;++nf){
      #pragma unroll
      for (int i=0;i<4;++i){
        int h = wv*32 + mt*16 + lg*4 + i;
        int e = e0 + nf*16 + lc;
        if (e < E) hw2t[((long)b*HD + h)*E + e] = f2b(acc[mt][nf][i]);
      }
    }
  }
}

// ---------- stage 1: per-edge masked softmax + weighted sum of proj1 (bf16 out) ----------
__global__ __launch_bounds__(128) void k_edge(int swz, const float* __restrict__ raw,
                      const u16* __restrict__ proj1b,
                      const int* __restrict__ colcnt, const u16* __restrict__ colidx,
                      u16* __restrict__ hyb, int T, int E){
  int bi = blockIdx.x;
  int b, e;
  if (swz){ int x = bi & 7; b = x >> 1; e = ((bi >> 3) << 1) | (x & 1); }
  else    { b = bi / E; e = bi - b*E; }
  int j = threadIdx.x;
  __shared__ float red[2];
  __shared__ float wls[CAPE];
  __shared__ int   tls[CAPE];
  int c = colcnt[e]; if (c > CAPE) c = CAPE;
  const u16* ci = colidx + (long)e*CAPE;
  const float* rawb = raw + (long)b*T;
  long orow = ((long)b*E + e)*HD + j;
  if (c <= 0){ hyb[orow] = 0; return; }
  float lm = -1e30f;
  for (int i = j; i < c; i += 128){
    int t = ci[i];
    float v = rawb[t];
    tls[i] = t;
    wls[i] = v;
    lm = fmaxf(lm, v);
  }
  float m = blockMax128(lm, red);
  float lz = 0.f;
  for (int i = j; i < c; i += 128){
    float w = __expf(wls[i] - m);
    wls[i] = w;
    lz += w;
  }
  float Z = blockSum128(lz, red);
  float invZ = 1.f / Z;
  const u16* pb = proj1b + (long)b*T*HD + j;
  float a0=0.f,a1=0.f,a2=0.f,a3=0.f;
  int i = 0;
  for (; i + 4 <= c; i += 4){
    a0 += wls[i]   * b2f(pb[(long)tls[i]  *HD]);
    a1 += wls[i+1] * b2f(pb[(long)tls[i+1]*HD]);
    a2 += wls[i+2] * b2f(pb[(long)tls[i+2]*HD]);
    a3 += wls[i+3] * b2f(pb[(long)tls[i+3]*HD]);
  }
  for (; i < c; ++i) a0 += wls[i] * b2f(pb[(long)tls[i]*HD]);
  hyb[orow] = f2b(((a0+a1)+(a2+a3)) * invZ);
}

// ---------- stage 2: flash-dense masked attention, swapped-QK layout ----------
__global__ __launch_bounds__(256) void k_flash(
      const float* __restrict__ qt, const u16* __restrict__ hyb, const u16* __restrict__ hw2t,
      const u64* __restrict__ maskw,
      const float* __restrict__ lng, const float* __restrict__ lnb,
      const float* __restrict__ vnext, float* __restrict__ rawnext, int writeRaw,
      float* __restrict__ h_aug, float* __restrict__ out,
      int T, int E, int N, int writeOut, float scale){
  int b = blockIdx.y;
  int t0 = blockIdx.x * 64;
  int tid = threadIdx.x;
  int wv = tid >> 6, lane = tid & 63;
  int lc = lane & 15, lg = lane >> 4;

  __shared__ __align__(16) u16 Ks[64][KSTR];
  __shared__ __align__(16) u16 Vs[128][VSTR];

  int qrow = t0 + wv*16 + lc;
  bf16x8 qf[4];
  if (qrow < T){
    const float* qr = qt + ((long)b*T + qrow)*HD + lg*8;
    #pragma unroll
    for (int ks = 0; ks < 4; ++ks){
      const float4* q4 = (const float4*)(qr + ks*32);
      float4 a = q4[0], cc = q4[1];
      bf16x8 v;
      v[0]=(short)f2b(a.x);  v[1]=(short)f2b(a.y);  v[2]=(short)f2b(a.z);  v[3]=(short)f2b(a.w);
      v[4]=(short)f2b(cc.x); v[5]=(short)f2b(cc.y); v[6]=(short)f2b(cc.z); v[7]=(short)f2b(cc.w);
      qf[ks] = v;
    }
  } else {
    #pragma unroll
    for (int ks = 0; ks < 4; ++ks) qf[ks] = (bf16x8){0,0,0,0,0,0,0,0};
  }

  float m_s = -1e30f, l_s = 0.f;
  f32x4 Oa[8];
  #pragma unroll
  for (int f=0;f<8;++f) Oa[f] = (f32x4){0.f,0.f,0.f,0.f};

  const u16* hyB = hyb + (long)b*E*HD;
  const u16* vtB = hw2t + (long)b*HD*E;
  int MW = (E + 63) >> 6;
  int ntile = (E + 63) / 64;

  int kr = tid >> 2, kq = (tid & 3)*32;
  int vh = tid >> 1, vo = (tid & 1)*32;

  uint4 kreg0, kreg1, kreg2, kreg3, vreg0, vreg1, vreg2, vreg3;
  const uint4 zz = make_uint4(0u,0u,0u,0u);

  // prologue load (tile 0)
  {
    int e0 = 0;
    if (e0 + kr < E){
      const uint4* s = (const uint4*)(hyB + (long)(e0+kr)*HD + kq);
      kreg0=s[0]; kreg1=s[1]; kreg2=s[2]; kreg3=s[3];
    } else { kreg0=zz; kreg1=zz; kreg2=zz; kreg3=zz; }
    if (e0 + vo + 31 < E){
      const uint4* s = (const uint4*)(vtB + (long)vh*E + e0 + vo);
      vreg0=s[0]; vreg1=s[1]; vreg2=s[2]; vreg3=s[3];
    } else {
      union { uint4 v[4]; u16 s[32]; } u;
      #pragma unroll
      for (int k=0;k<32;++k){ int e=e0+vo+k; u.s[k] = (e<E)? vtB[(long)vh*E+e] : (u16)0; }
      vreg0=u.v[0]; vreg1=u.v[1]; vreg2=u.v[2]; vreg3=u.v[3];
    }
  }

  // permuted V store offsets (compile-time per chunk given vo at runtime)
  for (int et = 0; et < ntile; ++et){
    // store staged regs -> LDS
    *(uint4*)&Ks[kr][kq]    = kreg0;
    *(uint4*)&Ks[kr][kq+8]  = kreg1;
    *(uint4*)&Ks[kr][kq+16] = kreg2;
    *(uint4*)&Ks[kr][kq+24] = kreg3;
    {
      // chunk c: natural e = vo + c*8 .. +7 ; split into two 4-runs at permuted slots
      int eb0 = vo;        int ne0 = eb0>>4; int ka0 = (ne0>>1)*32 + ((eb0>>2)&3)*8 + (ne0&1)*4;
      int eb1 = vo + 8;    int ne1 = eb1>>4; int ka1 = (ne1>>1)*32 + ((eb1>>2)&3)*8 + (ne1&1)*4;
      int eb2 = vo + 16;   int ne2 = eb2>>4; int ka2 = (ne2>>1)*32 + ((eb2>>2)&3)*8 + (ne2&1)*4;
      int eb3 = vo + 24;   int ne3 = eb3>>4; int ka3 = (ne3>>1)*32 + ((eb3>>2)&3)*8 + (ne3&1)*4;
      *(uint2*)&Vs[vh][ka0]   = make_uint2(vreg0.x, vreg0.y);
      *(uint2*)&Vs[vh][ka0+8] = make_uint2(vreg0.z, vreg0.w);
      *(uint2*)&Vs[vh][ka1]   = make_uint2(vreg1.x, vreg1.y);
      *(uint2*)&Vs[vh][ka1+8] = make_uint2(vreg1.z, vreg1.w);
      *(uint2*)&Vs[vh][ka2]   = make_uint2(vreg2.x, vreg2.y);
      *(uint2*)&Vs[vh][ka2+8] = make_uint2(vreg2.z, vreg2.w);
      *(uint2*)&Vs[vh][ka3]   = make_uint2(vreg3.x, vreg3.y);
      *(uint2*)&Vs[vh][ka3+8] = make_uint2(vreg3.z, vreg3.w);
    }
    __syncthreads();
    if (et + 1 < ntile){
      int e0 = (et+1)*64;
      if (e0 + kr < E){
        const uint4* s = (const uint4*)(hyB + (long)(e0+kr)*HD + kq);
        kreg0=s[0]; kreg1=s[1]; kreg2=s[2]; kreg3=s[3];
      } else { kreg0=zz; kreg1=zz; kreg2=zz; kreg3=zz; }
      if (e0 + vo + 31 < E){
        const uint4* s = (const uint4*)(vtB + (long)vh*E + e0 + vo);
        vreg0=s[0]; vreg1=s[1]; vreg2=s[2]; vreg3=s[3];
      } else {
        union { uint4 v[4]; u16 s[32]; } u;
        #pragma unroll
        for (int k=0;k<32;++k){ int e=e0+vo+k; u.s[k] = (e<E)? vtB[(long)vh*E+e] : (u16)0; }
        vreg0=u.v[0]; vreg1=u.v[1]; vreg2=u.v[2]; vreg3=u.v[3];
      }
    }

    u64 mw = (qrow < T) ? maskw[(long)qrow*MW + et] : 0ull;

    f32x4 accS[4];
    #pragma unroll
    for (int ne=0;ne<4;++ne) accS[ne] = (f32x4){0.f,0.f,0.f,0.f};
    __builtin_amdgcn_s_setprio(1);
    #pragma unroll
    for (int ks=0;ks<4;++ks){
      #pragma unroll
      for (int ne=0;ne<4;++ne){
        bf16x8 kv = *(const bf16x8*)&Ks[ne*16+lc][ks*32 + lg*8];
        accS[ne] = __builtin_amdgcn_mfma_f32_16x16x32_bf16(kv, qf[ks], accS[ne], 0,0,0);
      }
    }
    __builtin_amdgcn_s_setprio(0);

    unsigned lo = (unsigned)mw, hi = (unsigned)(mw >> 32);
    unsigned nib[4];
    nib[0] = (lo >> (lg*4)) & 0xFu;
    nib[1] = (lo >> (16 + lg*4)) & 0xFu;
    nib[2] = (hi >> (lg*4)) & 0xFu;
    nib[3] = (hi >> (16 + lg*4)) & 0xFu;

    float p[4][4];
    float mx = -1e30f;
    #pragma unroll
    for (int ne=0;ne<4;++ne){
      #pragma unroll
      for (int r=0;r<4;++r){
        float s = ((nib[ne] >> r) & 1u) ? accS[ne][r]*scale : -1e30f;
        p[ne][r] = s;
        mx = fmaxf(mx, s);
      }
    }
    mx = fmaxf(mx, __shfl_xor(mx, 16));
    mx = fmaxf(mx, __shfl_xor(mx, 32));
    float mn = fmaxf(m_s, mx);
    float corr = __expf(m_s - mn);
    m_s = mn;
    float ls = 0.f;
    #pragma unroll
    for (int ne=0;ne<4;++ne){
      #pragma unroll
      for (int r=0;r<4;++r){
        float pv = __expf(p[ne][r] - mn);
        p[ne][r] = pv;
        ls += pv;
      }
    }
    ls += __shfl_xor(ls, 16);
    ls += __shfl_xor(ls, 32);
    l_s = l_s*corr + ls;

    float corrO[4];
    #pragma unroll
    for (int i=0;i<4;++i) corrO[i] = __shfl(corr, lg*4 + i, 16);
    #pragma unroll
    for (int f=0;f<8;++f){
      #pragma unroll
      for (int i=0;i<4;++i) Oa[f][i] *= corrO[i];
    }

    unsigned pk00, pk01, pk10, pk11, pk20, pk21, pk30, pk31;
    asm("v_cvt_pk_bf16_f32 %0, %1, %2" : "=v"(pk00) : "v"(p[0][0]), "v"(p[0][1]));
    asm("v_cvt_pk_bf16_f32 %0, %1, %2" : "=v"(pk01) : "v"(p[0][2]), "v"(p[0][3]));
    asm("v_cvt_pk_bf16_f32 %0, %1, %2" : "=v"(pk10) : "v"(p[1][0]), "v"(p[1][1]));
    asm("v_cvt_pk_bf16_f32 %0, %1, %2" : "=v"(pk11) : "v"(p[1][2]), "v"(p[1][3]));
    asm("v_cvt_pk_bf16_f32 %0, %1, %2" : "=v"(pk20) : "v"(p[2][0]), "v"(p[2][1]));
    asm("v_cvt_pk_bf16_f32 %0, %1, %2" : "=v"(pk21) : "v"(p[2][2]), "v"(p[2][3]));
    asm("v_cvt_pk_bf16_f32 %0, %1, %2" : "=v"(pk30) : "v"(p[3][0]), "v"(p[3][1]));
    asm("v_cvt_pk_bf16_f32 %0, %1, %2" : "=v"(pk31) : "v"(p[3][2]), "v"(p[3][3]));

    __builtin_amdgcn_s_setprio(1);
    {
      u32x4 w0v = { pk00, pk01, pk10, pk11 };
      bf16x8 pa0 = __builtin_bit_cast(bf16x8, w0v);
      #pragma unroll
      for (int f=0;f<8;++f){
        bf16x8 vb = *(const bf16x8*)&Vs[f*16+lc][lg*8];
        Oa[f] = __builtin_amdgcn_mfma_f32_16x16x32_bf16(pa0, vb, Oa[f], 0,0,0);
      }
      u32x4 w1v = { pk20, pk21, pk30, pk31 };
      bf16x8 pa1 = __builtin_bit_cast(bf16x8, w1v);
      #pragma unroll
      for (int f=0;f<8;++f){
        bf16x8 vb = *(const bf16x8*)&Vs[f*16+lc][32 + lg*8];
        Oa[f] = __builtin_amdgcn_mfma_f32_16x16x32_bf16(pa1, vb, Oa[f], 0,0,0);
      }
    }
    __builtin_amdgcn_s_setprio(0);
    __syncthreads();
  }

  float invl = (l_s > 0.f) ? 1.f/l_s : 0.f;
  #pragma unroll
  for (int i=0;i<4;++i){
    int t = t0 + wv*16 + lg*4 + i;
    if (t >= T) continue;
    long rowb = (long)b*T + t;
    float inv = __shfl(invl, lg*4 + i, 16);
    float xv[8];
    float sm = 0.f;
    #pragma unroll
    for (int f=0;f<8;++f){
      float o = Oa[f][i]*inv;
      float h = h_aug[rowb*HD + f*16+lc];
      xv[f] = o + h;
      sm += xv[f];
    }
    sm += __shfl_xor(sm,1); sm += __shfl_xor(sm,2);
    sm += __shfl_xor(sm,4); sm += __shfl_xor(sm,8);
    float mean = sm * (1.f/HD);
    float vr = 0.f;
    #pragma unroll
    for (int f=0;f<8;++f){ float d = xv[f]-mean; vr += d*d; }
    vr += __shfl_xor(vr,1); vr += __shfl_xor(vr,2);
    vr += __shfl_xor(vr,4); vr += __shfl_xor(vr,8);
    float rstd = rsqrtf(vr*(1.f/HD) + 1e-5f);
    float rsum = 0.f;
    #pragma unroll
    for (int f=0;f<8;++f){
      int col = f*16+lc;
      float y = (xv[f]-mean)*rstd*lng[col] + lnb[col];
      if (writeOut){ if (t < N) out[((long)b*N + t)*HD + col] = y; }
      else h_aug[rowb*HD + col] = y;
      rsum += y * vnext[col];
    }
    rsum += __shfl_xor(rsum,1); rsum += __shfl_xor(rsum,2);
    rsum += __shfl_xor(rsum,4); rsum += __shfl_xor(rsum,8);
    if (writeRaw && lc == 0) rawnext[rowb] = rsum * scale;
  }
}

extern "C" void kernel_launch(void* const* d_in, const int* in_sizes, int n_in,
                              void* d_out, int out_size, void* d_ws, size_t ws_size,
                              hipStream_t stream) {
  const float* node_emb = (const float*)d_in[0];
  const float* Hinc     = (const float*)d_in[1];
  const int*   memb     = (const int*)d_in[2];
  const float* W1       = (const float*)d_in[3];
  const float* W1h      = (const float*)d_in[4];
  const float* ctx1     = (const float*)d_in[5];
  const float* W2       = (const float*)d_in[6];
  const float* W2h      = (const float*)d_in[7];
  const float* W3       = (const float*)d_in[8];
  const float* lng      = (const float*)d_in[9];
  const float* lnb      = (const float*)d_in[10];
  const float* rinit    = (const float*)d_in[11];
  float* out = (float*)d_out;

  const int N  = in_sizes[2];
  const int Hd = in_sizes[3] / in_sizes[5];
  const int L  = in_sizes[5] / Hd;
  const int R  = in_sizes[11] / Hd;
  const int B  = in_sizes[0] / (N * Hd);
  const int T  = N + R;
  const int E  = in_sizes[1] / T;
  const int MW = (E + 63) / 64;
  const float scale = 1.0f / sqrtf((float)Hd);

  char* p = (char*)d_ws;
  auto carve = [&](size_t bytes){ char* r = p; p += (bytes + 255) & ~(size_t)255; return (void*)r; };
  float* h_aug  = (float*)carve((size_t)B*T*Hd*4);
  u16*   proj1b = (u16*)  carve((size_t)B*T*Hd*2);
  float* qt     = (float*)carve((size_t)B*T*Hd*4);
  u16*   hyb    = (u16*)  carve((size_t)B*E*Hd*2);
  u16*   hw2t   = (u16*)  carve((size_t)B*Hd*E*2);
  float* MqT    = (float*)carve((size_t)L*Hd*Hd*4);
  float* rawb   = (float*)carve((size_t)B*T*4);
  float* vbuf   = (float*)carve((size_t)L*Hd*4);
  u64*   maskw  = (u64*)  carve((size_t)T*MW*8);
  int* counts   = (int*)carve((size_t)R*4);
  int* col_cnt  = (int*)carve((size_t)E*4);
  u16* col_idx  = (u16*)carve((size_t)E*CAPE*2);

  float* partials = qt;

  hipMemsetAsync(counts, 0, (size_t)R*4, stream);

  k_count<<<32, 256, 0, stream>>>(memb, N, counts);

  int redN;
  if (R <= MAXR){
    k_regsum_fast<<<dim3(NB_RS, B), 128, 0, stream>>>(node_emb, memb, N, R, partials);
    redN = NB_RS;
  } else {
    hipMemsetAsync(partials, 0, (size_t)B*R*Hd*4, stream);
    k_regsum_lds<<<dim3(16, B), Hd, (size_t)R*Hd*4, stream>>>(node_emb, memb, N, R, partials, NB_RS);
    redN = 1;
  }
  int tot = B*R*Hd;
  k_regfin<<<(tot+255)/256, 256, 0, stream>>>(partials, NB_RS, redN, counts, rinit, h_aug, N, R, T, B);

  k_maskbuild<<<T, 256, 0, stream>>>(Hinc, E, MW, maskw);
  k_colbuild2<<<E, 256, 0, stream>>>(maskw, T, MW, col_idx, col_cnt);

  k_ctxv<<<L, Hd, 0, stream>>>(ctx1, W1h, vbuf);
  k_mm128<<<dim3(Hd, L), Hd, 0, stream>>>(W2h, W3, MqT);
  k_copyraw<<<dim3(T, B), 128, 0, stream>>>(node_emb, vbuf, h_aug, rawb, N, T, scale);

  int MT = B*T;
  int gTm = (MT + 63)/64;
  int gTf = (T + 63)/64;
  int gEt = (E + 63)/64;
  int swzE = (B == 4 && (E & 1) == 0) ? 1 : 0;
  for (int l = 0; l < L; ++l){
    size_t wo = (size_t)l*Hd*Hd;
    k_gemmM<<<dim3(gTm, 2), 256, 0, stream>>>(h_aug, W1 + wo, MqT + wo, proj1b, qt, MT, 0);
    k_edge<<<B*E, 128, 0, stream>>>(swzE, rawb, proj1b, col_cnt, col_idx, hyb, T, E);
    k_gemmW2T<<<dim3(gEt, B), 256, 0, stream>>>(W2 + wo, hyb, hw2t, E);
    int writeRaw = (l < L-1) ? 1 : 0;
    const float* vnext = vbuf + (size_t)((l+1 < L) ? (l+1) : l)*Hd;
    k_flash<<<dim3(gTf, B), 256, 0, stream>>>(qt, hyb, hw2t, maskw,
                                    lng + wo/Hd, lnb + wo/Hd,
                                    vnext, rawb, writeRaw,
                                    h_aug, out, T, E, N, (l == L-1) ? 1 : 0, scale);
  }
}